// Round 2
// baseline (15985.521 us; speedup 1.0000x reference)
//
#include <hip/hip_runtime.h>
#include <hip/hip_bf16.h>

#define B_ 4
#define N_ 4096
#define H_ 1024
#define NH_ 16
#define HD_ 64
#define M_ 256

__device__ __forceinline__ float gelu_f(float x) {
  const float c = 0.7978845608028654f;
  float t = tanhf(c * (x + 0.044715f * x * x * x));
  return 0.5f * x * (1.0f + t);
}

// Generic fp32 tiled GEMM.
//   C[M,N] = act(A @ W + bias)
// A: [M,K] row-major, leading dim lda. W: [K,N] row-major, leading dim ldw.
// Batched over blockIdx.z with per-z element offsets (bb=z>>4, hh=z&15).
// ACT: 0 = bias; 1 = bias+gelu;
//      2 = performer-feature epilogue: P=(1/16)(exp(acc - dacc/16 - rowmax)+1e-4),
//          dacc=sum_k a^2; optional atomic ksum accumulation (per-z rows of 256);
//      3 = divide by denom, denom[row]=sum_k a[row,k]*ksum[z*K+k].
template<int BM, int BN, int TM, int TN, int ACT>
__launch_bounds__(256)
__global__ void gemm_k(const float* __restrict__ A, int lda, long long sAb, long long sAh,
                       const float* __restrict__ W, int ldw, long long sWb, long long sWh,
                       const float* __restrict__ bias,
                       float* __restrict__ ksum,
                       float* __restrict__ C, int ldc, long long sCb, long long sCh,
                       int K) {
  constexpr int BK = 8;
  constexpr int NTX = BN / TN;
  constexpr int NTY = BM / TM;
  static_assert(NTX * NTY == 256, "block must be 256 threads");
  __shared__ float As[BK][BM];
  __shared__ float Ws[BK][BN];
  __shared__ float Ks[BK];
  const int z = blockIdx.z, bb = z >> 4, hh = z & 15;
  A += bb * sAb + hh * sAh;
  W += bb * sWb + hh * sWh;
  C += bb * sCb + hh * sCh;
  const float* ksp = (ACT == 3) ? (ksum + (long long)z * K) : nullptr;
  const int tid = threadIdx.x;
  const int row0 = blockIdx.y * BM;
  const int col0 = blockIdx.x * BN;
  const int tx = tid % NTX, ty = tid / NTX;

  float acc[TM][TN];
#pragma unroll
  for (int i = 0; i < TM; ++i)
#pragma unroll
    for (int j = 0; j < TN; ++j) acc[i][j] = 0.0f;
  float dacc[TM];
#pragma unroll
  for (int i = 0; i < TM; ++i) dacc[i] = 0.0f;

  for (int k0 = 0; k0 < K; k0 += BK) {
    {
      constexpr int n4 = BM * BK / 4;
      for (int i = tid; i < n4; i += 256) {
        int r = i / (BK / 4);
        int kk = (i % (BK / 4)) * 4;
        float4 v = *(const float4*)&A[(long long)(row0 + r) * lda + k0 + kk];
        As[kk + 0][r] = v.x; As[kk + 1][r] = v.y; As[kk + 2][r] = v.z; As[kk + 3][r] = v.w;
      }
    }
    {
      constexpr int n4 = BN * BK / 4;
      for (int i = tid; i < n4; i += 256) {
        int kk = i / (BN / 4);
        int c4 = (i % (BN / 4)) * 4;
        *(float4*)&Ws[kk][c4] = *(const float4*)&W[(long long)(k0 + kk) * ldw + col0 + c4];
      }
    }
    if (ACT == 3) { if (tid < BK) Ks[tid] = ksp[k0 + tid]; }
    __syncthreads();
#pragma unroll
    for (int kk = 0; kk < BK; ++kk) {
      float a[TM], w[TN];
#pragma unroll
      for (int i = 0; i < TM; ++i) {
        int r = (TM == 8) ? ((i < 4) ? ty * 4 + i : BM / 2 + ty * 4 + (i - 4)) : ty * TM + i;
        a[i] = As[kk][r];
      }
#pragma unroll
      for (int j = 0; j < TN; ++j) {
        int c = (TN == 8) ? ((j < 4) ? tx * 4 + j : BN / 2 + tx * 4 + (j - 4)) : tx * TN + j;
        w[j] = Ws[kk][c];
      }
      if (ACT == 2) {
#pragma unroll
        for (int i = 0; i < TM; ++i) dacc[i] += a[i] * a[i];
      }
      if (ACT == 3) {
#pragma unroll
        for (int i = 0; i < TM; ++i) dacc[i] += a[i] * Ks[kk];
      }
#pragma unroll
      for (int i = 0; i < TM; ++i)
#pragma unroll
        for (int j = 0; j < TN; ++j) acc[i][j] += a[i] * w[j];
    }
    __syncthreads();
  }

  float cs[TN];
#pragma unroll
  for (int j = 0; j < TN; ++j) cs[j] = 0.0f;

#pragma unroll
  for (int i = 0; i < TM; ++i) {
    int ri = (TM == 8) ? ((i < 4) ? ty * 4 + i : BM / 2 + ty * 4 + (i - 4)) : ty * TM + i;
    long long crow = (long long)(row0 + ri) * ldc;
    float base = 0.0f;
    if (ACT == 2) {
      float rm = acc[i][0];
#pragma unroll
      for (int j = 1; j < TN; ++j) rm = fmaxf(rm, acc[i][j]);
#pragma unroll
      for (int mls = 1; mls < 32; mls <<= 1) rm = fmaxf(rm, __shfl_xor(rm, mls, 32));
      base = 0.0625f * dacc[i] + rm;
    }
#pragma unroll
    for (int j = 0; j < TN; ++j) {
      int cj = (TN == 8) ? ((j < 4) ? tx * 4 + j : BN / 2 + tx * 4 + (j - 4)) : tx * TN + j;
      float v = acc[i][j];
      if (ACT == 2) {
        v = 0.0625f * (expf(v - base) + 1e-4f);
        cs[j] += v;
      } else if (ACT == 3) {
        v /= dacc[i];
      } else {
        if (bias) v += bias[col0 + cj];
        if (ACT == 1) v = gelu_f(v);
      }
      C[crow + col0 + cj] = v;
    }
  }
  if (ACT == 2 && ksum) {
#pragma unroll
    for (int j = 0; j < TN; ++j) {
      int cj = (TN == 8) ? ((j < 4) ? tx * 4 + j : BN / 2 + tx * 4 + (j - 4)) : tx * TN + j;
      atomicAdd(&ksum[(long long)z * BN + col0 + cj], cs[j]);
    }
  }
}

// ctx[hh][m][d] += sum_{n in split} Kp[hh][n][m] * V[n][(g*4+hh)*64 + d]
// grid: (m-tile 4, n-split 16, hh 4); block 256.
__launch_bounds__(256)
__global__ void ctx_k(const float* __restrict__ Kp, const float* __restrict__ V,
                      float* __restrict__ ctx, int g) {
  constexpr int BK = 16;
  __shared__ float As[BK][64];
  __shared__ float Ws[BK][64];
  const int hh = blockIdx.z;
  const int m0 = blockIdx.x * 64;
  const int n0 = blockIdx.y * 256;
  const float* Kph = Kp + (long long)hh * N_ * M_;
  const float* Vh = V + (g * 4 + hh) * 64;
  const int tid = threadIdx.x;
  const int tx = tid % 16, ty = tid / 16;
  const int lr = tid / 16, lc = (tid % 16) * 4;
  float acc[4][4];
#pragma unroll
  for (int i = 0; i < 4; ++i)
#pragma unroll
    for (int j = 0; j < 4; ++j) acc[i][j] = 0.0f;

  for (int k0 = n0; k0 < n0 + 256; k0 += BK) {
    *(float4*)&As[lr][lc] = *(const float4*)&Kph[(long long)(k0 + lr) * M_ + m0 + lc];
    *(float4*)&Ws[lr][lc] = *(const float4*)&Vh[(long long)(k0 + lr) * H_ + lc];
    __syncthreads();
#pragma unroll
    for (int kk = 0; kk < BK; ++kk) {
      float a[4], w[4];
#pragma unroll
      for (int i = 0; i < 4; ++i) a[i] = As[kk][ty * 4 + i];
#pragma unroll
      for (int j = 0; j < 4; ++j) w[j] = Ws[kk][tx * 4 + j];
#pragma unroll
      for (int i = 0; i < 4; ++i)
#pragma unroll
        for (int j = 0; j < 4; ++j) acc[i][j] += a[i] * w[j];
    }
    __syncthreads();
  }
#pragma unroll
  for (int i = 0; i < 4; ++i)
#pragma unroll
    for (int j = 0; j < 4; ++j)
      atomicAdd(&ctx[((long long)hh * M_ + m0 + ty * 4 + i) * 64 + tx * 4 + j], acc[i][j]);
}

// projT[d][m] = dn * proj[m][d], dn = HD^-0.25
__launch_bounds__(256)
__global__ void transp_proj(const float* __restrict__ proj, float* __restrict__ projT) {
  int i = blockIdx.x * 256 + threadIdx.x;  // 0..16383
  int m = i >> 6, d = i & 63;
  projT[d * M_ + m] = 0.35355339059327373f * proj[i];
}

// out = LN(a + b) * g + beta, rows of 1024
__launch_bounds__(256)
__global__ void ln_res(const float* __restrict__ A, const float* __restrict__ Bi,
                       const float* __restrict__ g, const float* __restrict__ be,
                       float* __restrict__ out) {
  long long row = blockIdx.x;
  int t = threadIdx.x;
  const float4 va = ((const float4*)(A + row * H_))[t];
  const float4 vb = ((const float4*)(Bi + row * H_))[t];
  float x0 = va.x + vb.x, x1 = va.y + vb.y, x2 = va.z + vb.z, x3 = va.w + vb.w;
  float s = x0 + x1 + x2 + x3;
  float q = x0 * x0 + x1 * x1 + x2 * x2 + x3 * x3;
#pragma unroll
  for (int m = 1; m < 64; m <<= 1) { s += __shfl_xor(s, m, 64); q += __shfl_xor(q, m, 64); }
  __shared__ float ssum[4], ssq[4];
  int w = t >> 6, lane = t & 63;
  if (lane == 0) { ssum[w] = s; ssq[w] = q; }
  __syncthreads();
  s = ssum[0] + ssum[1] + ssum[2] + ssum[3];
  q = ssq[0] + ssq[1] + ssq[2] + ssq[3];
  float mean = s * (1.0f / H_);
  float var = q * (1.0f / H_) - mean * mean;
  float rstd = rsqrtf(var + 1e-5f);
  float4 vg = ((const float4*)g)[t];
  float4 vbe = ((const float4*)be)[t];
  float4 o;
  o.x = (x0 - mean) * rstd * vg.x + vbe.x;
  o.y = (x1 - mean) * rstd * vg.y + vbe.y;
  o.z = (x2 - mean) * rstd * vg.z + vbe.z;
  o.w = (x3 - mean) * rstd * vg.w + vbe.w;
  ((float4*)(out + row * H_))[t] = o;
}

extern "C" void kernel_launch(void* const* d_in, const int* in_sizes, int n_in,
                              void* d_out, int out_size, void* d_ws, size_t ws_size,
                              hipStream_t stream) {
  (void)in_sizes; (void)n_in; (void)out_size; (void)ws_size;
  const float* x      = (const float*)d_in[0];
  const float* enc    = (const float*)d_in[1];
  const float* sa_wq  = (const float*)d_in[2];
  const float* sa_bq  = (const float*)d_in[3];
  const float* sa_wk  = (const float*)d_in[4];
  const float* sa_bk  = (const float*)d_in[5];
  const float* sa_wv  = (const float*)d_in[6];
  const float* sa_bv  = (const float*)d_in[7];
  const float* sa_wo  = (const float*)d_in[8];
  const float* sa_bo  = (const float*)d_in[9];
  const float* sa_pj  = (const float*)d_in[10];
  const float* ca_wq  = (const float*)d_in[11];
  const float* ca_bq  = (const float*)d_in[12];
  const float* ca_wk  = (const float*)d_in[13];
  const float* ca_bk  = (const float*)d_in[14];
  const float* ca_wv  = (const float*)d_in[15];
  const float* ca_bv  = (const float*)d_in[16];
  const float* ca_wo  = (const float*)d_in[17];
  const float* ca_bo  = (const float*)d_in[18];
  const float* ca_pj  = (const float*)d_in[19];
  const float* ff_w1  = (const float*)d_in[20];
  const float* ff_b1  = (const float*)d_in[21];
  const float* ff_w2  = (const float*)d_in[22];
  const float* ff_b2  = (const float*)d_in[23];
  const float* ln1_g  = (const float*)d_in[24];
  const float* ln1_b  = (const float*)d_in[25];
  const float* ln2_g  = (const float*)d_in[26];
  const float* ln2_b  = (const float*)d_in[27];
  const float* ln3_g  = (const float*)d_in[28];
  const float* ln3_b  = (const float*)d_in[29];

  float* ws = (float*)d_ws;
  // Workspace layout (floats). Peak: 58,803,200 floats = 235.2 MB.
  float* H1    = ws;                   // 16,777,216  h1 / ff_out
  float* H2    = ws + 16777216LL;      // 16,777,216  h2
  float* AOb   = ws + 33554432LL;      //  4,194,304  per-b attn out [16][4096][64]
  float* S0    = ws + 37748736LL;      //  4,194,304  per-b Q   (also proj-out Pb, also FFN-mid base)
  float* S1    = ws + 41943040LL;      //  4,194,304  per-b K
  float* S2    = ws + 46137344LL;      //  4,194,304  per-b V
  float* Pq    = ws + 50331648LL;      //  4,194,304  per-(b,g) Qp [4][4096][256]
  float* Pk    = ws + 54525952LL;      //  4,194,304  per-(b,g) Kp
  float* ctx   = ws + 58720256LL;      //     65,536  [4][256][64]
  float* ksmB  = ws + 58785792LL;      //      1,024  [4][256]
  float* projT = ws + 58786816LL;      //     16,384  [64][256]
  float* Pb    = S0;                   // proj-out per b (S0 dead by then)
  float* FFMID = S0;                   // 16,777,216 spans S0..Pq (all dead during FFN)

  dim3 blk(256, 1, 1);
  const long long sB = (long long)N_ * H_;
  const long long sP = (long long)N_ * M_;
  const long long sAO = (long long)N_ * HD_;

  auto attn = [&](const float* qin, const float* kvin,
                  const float* wq, const float* bq, const float* wk, const float* bk,
                  const float* wv, const float* bv, const float* proj,
                  const float* wo, const float* bo,
                  const float* res, const float* lg, const float* lb, float* hout) {
    transp_proj<<<dim3(64), blk, 0, stream>>>(proj, projT);
    for (int b = 0; b < B_; ++b) {
      const float* qb = qin + b * sB;
      const float* kb = kvin + b * sB;
      gemm_k<128,128,8,8,0><<<dim3(8,32,1), blk, 0, stream>>>(
          qb, H_, 0, 0, wq, H_, 0, 0, bq, nullptr, S0, H_, 0, 0, H_);
      gemm_k<128,128,8,8,0><<<dim3(8,32,1), blk, 0, stream>>>(
          kb, H_, 0, 0, wk, H_, 0, 0, bk, nullptr, S1, H_, 0, 0, H_);
      gemm_k<128,128,8,8,0><<<dim3(8,32,1), blk, 0, stream>>>(
          kb, H_, 0, 0, wv, H_, 0, 0, bv, nullptr, S2, H_, 0, 0, H_);
      for (int g = 0; g < 4; ++g) {
        // Qp features (fused FAVOR+ epilogue), z = local head 0..3
        gemm_k<64,256,8,8,2><<<dim3(1,64,4), blk, 0, stream>>>(
            S0 + g * 256, H_, 0, 64, projT, M_, 0, 0, nullptr, nullptr,
            Pq, M_, 0, sP, HD_);
        hipMemsetAsync(ksmB, 0, 4 * 256 * sizeof(float), stream);
        gemm_k<64,256,8,8,2><<<dim3(1,64,4), blk, 0, stream>>>(
            S1 + g * 256, H_, 0, 64, projT, M_, 0, 0, nullptr, ksmB,
            Pk, M_, 0, sP, HD_);
        hipMemsetAsync(ctx, 0, 4 * M_ * HD_ * sizeof(float), stream);
        ctx_k<<<dim3(4,16,4), blk, 0, stream>>>(Pk, S2, ctx, g);
        // attn_out = (Qp @ ctx) / denom
        gemm_k<128,64,8,4,3><<<dim3(1,32,4), blk, 0, stream>>>(
            Pq, M_, 0, sP, ctx, HD_, 0, (long long)M_ * HD_, nullptr, ksmB,
            AOb + (long long)g * 4 * sAO, HD_, 0, sAO, M_);
      }
      // out-proj over per-b [4096,1024]
      gemm_k<128,128,8,8,0><<<dim3(8,32,1), blk, 0, stream>>>(
          AOb, H_, 0, 0, wo, H_, 0, 0, bo, nullptr, Pb, H_, 0, 0, H_);
      ln_res<<<dim3(4096), blk, 0, stream>>>(res + b * sB, Pb, lg, lb, hout + b * sB);
    }
  };

  attn(x, x, sa_wq, sa_bq, sa_wk, sa_bk, sa_wv, sa_bv, sa_pj, sa_wo, sa_bo,
       x, ln1_g, ln1_b, H1);
  attn(H1, enc, ca_wq, ca_bq, ca_wk, ca_bk, ca_wv, ca_bv, ca_pj, ca_wo, ca_bo,
       H1, ln2_g, ln2_b, H2);

  // FFN: 4 chunks of 4096 rows. mid = gelu(h2 @ W1 + b1); ff_out = mid @ W2 + b2 -> H1
  for (int c = 0; c < 4; ++c) {
    gemm_k<128,128,8,8,1><<<dim3(32,32,1), blk, 0, stream>>>(
        H2 + (long long)c * 4096 * H_, H_, 0, 0, ff_w1, 4096, 0, 0, ff_b1, nullptr,
        FFMID, 4096, 0, 0, H_);
    gemm_k<128,128,8,8,0><<<dim3(8,32,1), blk, 0, stream>>>(
        FFMID, 4096, 0, 0, ff_w2, H_, 0, 0, ff_b2, nullptr,
        H1 + (long long)c * 4096 * H_, H_, 0, 0, 4096);
  }

  ln_res<<<dim3(16384), blk, 0, stream>>>(H2, H1, ln3_g, ln3_b, (float*)d_out);
}

// Round 4
// 5944.613 us; speedup vs baseline: 2.6891x; 2.6891x over previous
//
#include <hip/hip_runtime.h>
#include <hip/hip_bf16.h>

#define B_ 4
#define N_ 4096
#define H_ 1024
#define NH_ 16
#define HD_ 64
#define M_ 256

typedef __attribute__((ext_vector_type(8))) __bf16 bf16x8;
typedef __attribute__((ext_vector_type(4))) float f32x4;

__device__ __forceinline__ float bf2f(unsigned short u) {
  union { unsigned int i; float f; } x; x.i = ((unsigned int)u) << 16; return x.f;
}
__device__ __forceinline__ unsigned short f2b(float f) {
  __hip_bfloat16 h = __float2bfloat16(f);
  return *(unsigned short*)&h;
}
__device__ __forceinline__ float gelu_f(float x) {
  const float c = 0.7978845608028654f;
  float t = tanhf(c * (x + 0.044715f * x * x * x));
  return 0.5f * x * (1.0f + t);
}

// ---------------------------------------------------------------------------
// Dense bf16 MFMA GEMM: C[M,N] = act(A @ BT^T + bias); C bf16.
// A: [M,K] bf16 row-major (lda). BT: [N,K] bf16 row-major.
// Tile 128x128, BK=64, 4 waves, wave-tile 64x64 (4x4 frags of 16x16x32).
// LDS XOR-swizzled (byte ^= (row&7)<<4).
// ---------------------------------------------------------------------------
template<int ACT>
__launch_bounds__(256)
__global__ void gemm_mfma(const unsigned short* __restrict__ A, int lda,
                          const unsigned short* __restrict__ BT,
                          const float* __restrict__ bias,
                          unsigned short* __restrict__ C, int ldc, int K) {
  __shared__ unsigned short As[128 * 64];
  __shared__ unsigned short Bs[128 * 64];
  char* AsB = (char*)As;
  char* BsB = (char*)Bs;

  const int tid = threadIdx.x;
  const int row0 = blockIdx.y * 128;
  const int col0 = blockIdx.x * 128;
  const int w = tid >> 6, lane = tid & 63;
  const int wm = w >> 1, wn = w & 1;
  const int ln = lane & 15, hi = lane >> 4;
  const int rswz = (ln & 7) << 4;

  const int rowA = tid >> 3;
  const int colA = (tid & 7) * 8;
  const int wcol = ((tid & 7) * 16) ^ (((tid >> 3) & 7) << 4);

  f32x4 acc[4][4];
#pragma unroll
  for (int i = 0; i < 4; ++i)
#pragma unroll
    for (int j = 0; j < 4; ++j) acc[i][j] = (f32x4){0.f, 0.f, 0.f, 0.f};

  uint4 ra[4], rb[4];
  const unsigned short* Ab = A + (long long)(row0 + rowA) * lda + colA;
  const unsigned short* Bb = BT + (long long)(col0 + rowA) * K + colA;
#pragma unroll
  for (int i = 0; i < 4; ++i) {
    ra[i] = *(const uint4*)(Ab + (long long)i * 32 * lda);
    rb[i] = *(const uint4*)(Bb + (long long)i * 32 * K);
  }

  for (int k0 = 0;;) {
#pragma unroll
    for (int i = 0; i < 4; ++i) {
      *(uint4*)(AsB + (rowA + i * 32) * 128 + wcol) = ra[i];
      *(uint4*)(BsB + (rowA + i * 32) * 128 + wcol) = rb[i];
    }
    __syncthreads();
    k0 += 64;
    const bool more = (k0 < K);
    if (more) {
#pragma unroll
      for (int i = 0; i < 4; ++i) {
        ra[i] = *(const uint4*)(Ab + (long long)i * 32 * lda + k0);
        rb[i] = *(const uint4*)(Bb + (long long)i * 32 * K + k0);
      }
    }
#pragma unroll
    for (int kc = 0; kc < 2; ++kc) {
      const int koff = (kc * 64 + hi * 16) ^ rswz;
      bf16x8 av[4], bv[4];
#pragma unroll
      for (int i = 0; i < 4; ++i)
        av[i] = *(bf16x8*)(AsB + (wm * 64 + i * 16 + ln) * 128 + koff);
#pragma unroll
      for (int j = 0; j < 4; ++j)
        bv[j] = *(bf16x8*)(BsB + (wn * 64 + j * 16 + ln) * 128 + koff);
#pragma unroll
      for (int i = 0; i < 4; ++i)
#pragma unroll
        for (int j = 0; j < 4; ++j)
          acc[i][j] = __builtin_amdgcn_mfma_f32_16x16x32_bf16(av[i], bv[j], acc[i][j], 0, 0, 0);
    }
    __syncthreads();
    if (!more) break;
  }

#pragma unroll
  for (int j = 0; j < 4; ++j) {
    const int gcol = col0 + wn * 64 + j * 16 + ln;
    const float bj = bias ? bias[gcol] : 0.0f;
#pragma unroll
    for (int i = 0; i < 4; ++i) {
      const int grow = row0 + wm * 64 + i * 16 + hi * 4;
#pragma unroll
      for (int r = 0; r < 4; ++r) {
        float v = acc[i][j][r] + bj;
        if (ACT == 1) v = gelu_f(v);
        C[(long long)(grow + r) * ldc + gcol] = f2b(v);
      }
    }
  }
}

// ---------------------------------------------------------------------------
// FAVOR+ feature GEMM (SIMT fp32 math, bf16 in/out), K=64, BM=64, BN=256.
// P = (1/16)*(exp(dd - ssq/16 - rowmax) + 1e-4); optional atomic ksum.
// z = local head 0..7.
// ---------------------------------------------------------------------------
__launch_bounds__(256)
__global__ void feat_gemm(const unsigned short* __restrict__ A, int lda,
                          const unsigned short* __restrict__ W,   // [64][256] bf16
                          float* __restrict__ ksum,
                          unsigned short* __restrict__ C) {
  __shared__ float As[8][64];
  __shared__ float Ws[8][256];
  const int hh = blockIdx.z;
  A += hh * 64;
  C += (long long)hh * (N_ * M_);
  const int tid = threadIdx.x;
  const int row0 = blockIdx.y * 64;
  const int tx = tid & 31, ty = tid >> 5;
  float acc[8][8];
#pragma unroll
  for (int i = 0; i < 8; ++i)
#pragma unroll
    for (int j = 0; j < 8; ++j) acc[i][j] = 0.f;
  float dacc[8];
#pragma unroll
  for (int i = 0; i < 8; ++i) dacc[i] = 0.f;

  for (int k0 = 0; k0 < 64; k0 += 8) {
    if (tid < 128) {
      int r = tid >> 1, kk = (tid & 1) * 4;
      ushort4 v = *(const ushort4*)&A[(long long)(row0 + r) * lda + k0 + kk];
      As[kk + 0][r] = bf2f(v.x); As[kk + 1][r] = bf2f(v.y);
      As[kk + 2][r] = bf2f(v.z); As[kk + 3][r] = bf2f(v.w);
    }
    {
      int kk = tid >> 5, c = (tid & 31) * 8;
      ushort4 v0 = *(const ushort4*)&W[(k0 + kk) * 256 + c];
      ushort4 v1 = *(const ushort4*)&W[(k0 + kk) * 256 + c + 4];
      Ws[kk][c + 0] = bf2f(v0.x); Ws[kk][c + 1] = bf2f(v0.y);
      Ws[kk][c + 2] = bf2f(v0.z); Ws[kk][c + 3] = bf2f(v0.w);
      Ws[kk][c + 4] = bf2f(v1.x); Ws[kk][c + 5] = bf2f(v1.y);
      Ws[kk][c + 6] = bf2f(v1.z); Ws[kk][c + 7] = bf2f(v1.w);
    }
    __syncthreads();
#pragma unroll
    for (int kk = 0; kk < 8; ++kk) {
      float a[8], ww[8];
#pragma unroll
      for (int i = 0; i < 8; ++i) {
        int r = (i < 4) ? ty * 4 + i : 32 + ty * 4 + (i - 4);
        a[i] = As[kk][r];
      }
#pragma unroll
      for (int j = 0; j < 8; ++j) {
        int c = (j < 4) ? tx * 4 + j : 128 + tx * 4 + (j - 4);
        ww[j] = Ws[kk][c];
      }
#pragma unroll
      for (int i = 0; i < 8; ++i) dacc[i] += a[i] * a[i];
#pragma unroll
      for (int i = 0; i < 8; ++i)
#pragma unroll
        for (int j = 0; j < 8; ++j) acc[i][j] += a[i] * ww[j];
    }
    __syncthreads();
  }

  float cs[8];
#pragma unroll
  for (int j = 0; j < 8; ++j) cs[j] = 0.f;
#pragma unroll
  for (int i = 0; i < 8; ++i) {
    int ri = (i < 4) ? ty * 4 + i : 32 + ty * 4 + (i - 4);
    float rm = acc[i][0];
#pragma unroll
    for (int j = 1; j < 8; ++j) rm = fmaxf(rm, acc[i][j]);
#pragma unroll
    for (int mls = 1; mls < 32; mls <<= 1) rm = fmaxf(rm, __shfl_xor(rm, mls, 32));
    float base = 0.0625f * dacc[i] + rm;
    long long crow = (long long)(row0 + ri) * 256;
#pragma unroll
    for (int j = 0; j < 8; ++j) {
      int cj = (j < 4) ? tx * 4 + j : 128 + tx * 4 + (j - 4);
      float v = 0.0625f * (expf(acc[i][j] - base) + 1e-4f);
      cs[j] += v;
      C[crow + cj] = f2b(v);
    }
  }
  if (ksum) {
#pragma unroll
    for (int j = 0; j < 8; ++j) {
      int cj = (j < 4) ? tx * 4 + j : 128 + tx * 4 + (j - 4);
      atomicAdd(&ksum[hh * 256 + cj], cs[j]);
    }
  }
}

// ctx[hh][m][d] += sum_{n in split} Kp[hh][n][m] * V[n][hh*64+d]
__launch_bounds__(256)
__global__ void ctx_k(const unsigned short* __restrict__ Kp, const unsigned short* __restrict__ V,
                      float* __restrict__ ctx) {
  constexpr int BK = 16;
  __shared__ float As[BK][64];
  __shared__ float Ws[BK][64];
  const int hh = blockIdx.z;
  const int m0 = blockIdx.x * 64;
  const int n0 = blockIdx.y * 256;
  const unsigned short* Kph = Kp + (long long)hh * N_ * M_;
  const unsigned short* Vh = V + hh * 64;
  const int tid = threadIdx.x;
  const int tx = tid % 16, ty = tid / 16;
  const int lr = tid / 16, lc = (tid % 16) * 4;
  float acc[4][4];
#pragma unroll
  for (int i = 0; i < 4; ++i)
#pragma unroll
    for (int j = 0; j < 4; ++j) acc[i][j] = 0.f;

  for (int k0 = n0; k0 < n0 + 256; k0 += BK) {
    ushort4 a4 = *(const ushort4*)&Kph[(long long)(k0 + lr) * M_ + m0 + lc];
    ushort4 w4 = *(const ushort4*)&Vh[(long long)(k0 + lr) * H_ + lc];
    As[lr][lc + 0] = bf2f(a4.x); As[lr][lc + 1] = bf2f(a4.y);
    As[lr][lc + 2] = bf2f(a4.z); As[lr][lc + 3] = bf2f(a4.w);
    Ws[lr][lc + 0] = bf2f(w4.x); Ws[lr][lc + 1] = bf2f(w4.y);
    Ws[lr][lc + 2] = bf2f(w4.z); Ws[lr][lc + 3] = bf2f(w4.w);
    __syncthreads();
#pragma unroll
    for (int kk = 0; kk < BK; ++kk) {
      float a[4], w[4];
#pragma unroll
      for (int i = 0; i < 4; ++i) a[i] = As[kk][ty * 4 + i];
#pragma unroll
      for (int j = 0; j < 4; ++j) w[j] = Ws[kk][tx * 4 + j];
#pragma unroll
      for (int i = 0; i < 4; ++i)
#pragma unroll
        for (int j = 0; j < 4; ++j) acc[i][j] += a[i] * w[j];
    }
    __syncthreads();
  }
#pragma unroll
  for (int i = 0; i < 4; ++i)
#pragma unroll
    for (int j = 0; j < 4; ++j)
      atomicAdd(&ctx[((long long)hh * M_ + m0 + ty * 4 + i) * 64 + tx * 4 + j], acc[i][j]);
}

// attn_out[hh][n][d] = (Qp @ ctx) / (Qp . ksum)
__launch_bounds__(256)
__global__ void ao_gemm(const unsigned short* __restrict__ A,
                        const float* __restrict__ Wc, const float* __restrict__ ksum,
                        unsigned short* __restrict__ C) {
  __shared__ float As[8][128];
  __shared__ float Ws[8][64];
  __shared__ float Ks[8];
  const int hh = blockIdx.z;
  A += (long long)hh * (N_ * M_);
  const float* W = Wc + (long long)hh * M_ * HD_;
  const float* ksp = ksum + hh * 256;
  C += (long long)hh * (N_ * HD_);
  const int tid = threadIdx.x;
  const int row0 = blockIdx.y * 128;
  const int tx = tid & 15, ty = tid >> 4;
  float acc[8][4];
#pragma unroll
  for (int i = 0; i < 8; ++i)
#pragma unroll
    for (int j = 0; j < 4; ++j) acc[i][j] = 0.f;
  float dacc[8];
#pragma unroll
  for (int i = 0; i < 8; ++i) dacc[i] = 0.f;

  for (int k0 = 0; k0 < 256; k0 += 8) {
    {
      int r = tid >> 1, kk = (tid & 1) * 4;
      ushort4 v = *(const ushort4*)&A[(long long)(row0 + r) * 256 + k0 + kk];
      As[kk + 0][r] = bf2f(v.x); As[kk + 1][r] = bf2f(v.y);
      As[kk + 2][r] = bf2f(v.z); As[kk + 3][r] = bf2f(v.w);
    }
    if (tid < 128) {
      int kk = tid >> 4, c4 = (tid & 15) * 4;
      *(float4*)&Ws[kk][c4] = *(const float4*)&W[(k0 + kk) * 64 + c4];
    }
    if (tid < 8) Ks[tid] = ksp[k0 + tid];
    __syncthreads();
#pragma unroll
    for (int kk = 0; kk < 8; ++kk) {
      float a[8], w[4];
#pragma unroll
      for (int i = 0; i < 8; ++i) {
        int r = (i < 4) ? ty * 4 + i : 64 + ty * 4 + (i - 4);
        a[i] = As[kk][r];
      }
#pragma unroll
      for (int j = 0; j < 4; ++j) w[j] = Ws[kk][tx * 4 + j];
#pragma unroll
      for (int i = 0; i < 8; ++i) dacc[i] += a[i] * Ks[kk];
#pragma unroll
      for (int i = 0; i < 8; ++i)
#pragma unroll
        for (int j = 0; j < 4; ++j) acc[i][j] += a[i] * w[j];
    }
    __syncthreads();
  }
#pragma unroll
  for (int i = 0; i < 8; ++i) {
    int ri = (i < 4) ? ty * 4 + i : 64 + ty * 4 + (i - 4);
    long long crow = (long long)(row0 + ri) * 64;
    float inv = 1.0f / dacc[i];
#pragma unroll
    for (int j = 0; j < 4; ++j)
      C[crow + tx * 4 + j] = f2b(acc[i][j] * inv);
  }
}

// weight transpose+convert: out[n*K+k] = bf16(in[k*N+n])
__launch_bounds__(256)
__global__ void wt_cvt(const float* __restrict__ in, unsigned short* __restrict__ out,
                       int K, int N) {
  __shared__ float t[32][33];
  int k0 = blockIdx.y * 32, n0 = blockIdx.x * 32;
  int tx = threadIdx.x & 31, ty = threadIdx.x >> 5;
  for (int r = ty; r < 32; r += 8) t[r][tx] = in[(long long)(k0 + r) * N + n0 + tx];
  __syncthreads();
  for (int r = ty; r < 32; r += 8) out[(long long)(n0 + r) * K + k0 + tx] = f2b(t[tx][r]);
}

// projT[k][m] = bf16(dn * proj[m][k])
__launch_bounds__(256)
__global__ void projT_cvt(const float* __restrict__ proj, unsigned short* __restrict__ out) {
  int i = blockIdx.x * 256 + threadIdx.x;
  int m = i >> 6, d = i & 63;
  out[d * 256 + m] = f2b(0.35355339059327373f * proj[i]);
}

__launch_bounds__(256)
__global__ void cvt_bf16(const float* __restrict__ in, unsigned short* __restrict__ out,
                         long long n) {
  long long stride = (long long)gridDim.x * 1024;
  for (long long i = ((long long)blockIdx.x * 256 + threadIdx.x) * 4; i < n; i += stride) {
    float4 v = *(const float4*)&in[i];
    ushort4 o;
    o.x = f2b(v.x); o.y = f2b(v.y); o.z = f2b(v.z); o.w = f2b(v.w);
    *(ushort4*)&out[i] = o;
  }
}

// out = LN(res + po) * g + beta, rows of 1024.
// res: f32 (resf) if non-null else bf16 (resb). po: bf16. Outputs optional.
__launch_bounds__(256)
__global__ void ln_k(const float* __restrict__ resf, const unsigned short* __restrict__ resb,
                     const unsigned short* __restrict__ po,
                     const float* __restrict__ g, const float* __restrict__ be,
                     float* __restrict__ outf, unsigned short* __restrict__ outb) {
  long long row = blockIdx.x;
  int t = threadIdx.x;
  float x0, x1, x2, x3;
  if (resf) {
    float4 va = ((const float4*)(resf + row * H_))[t];
    x0 = va.x; x1 = va.y; x2 = va.z; x3 = va.w;
  } else {
    ushort4 va = ((const ushort4*)(resb + row * H_))[t];
    x0 = bf2f(va.x); x1 = bf2f(va.y); x2 = bf2f(va.z); x3 = bf2f(va.w);
  }
  {
    ushort4 vp = ((const ushort4*)(po + row * H_))[t];
    x0 += bf2f(vp.x); x1 += bf2f(vp.y); x2 += bf2f(vp.z); x3 += bf2f(vp.w);
  }
  float s = x0 + x1 + x2 + x3;
  float q = x0 * x0 + x1 * x1 + x2 * x2 + x3 * x3;
#pragma unroll
  for (int m = 1; m < 64; m <<= 1) { s += __shfl_xor(s, m, 64); q += __shfl_xor(q, m, 64); }
  __shared__ float ssum[4], ssq[4];
  int w = t >> 6, lane = t & 63;
  if (lane == 0) { ssum[w] = s; ssq[w] = q; }
  __syncthreads();
  s = ssum[0] + ssum[1] + ssum[2] + ssum[3];
  q = ssq[0] + ssq[1] + ssq[2] + ssq[3];
  float mean = s * (1.0f / H_);
  float var = q * (1.0f / H_) - mean * mean;
  float rstd = rsqrtf(var + 1e-5f);
  float4 vg = ((const float4*)g)[t];
  float4 vbe = ((const float4*)be)[t];
  float o0 = (x0 - mean) * rstd * vg.x + vbe.x;
  float o1 = (x1 - mean) * rstd * vg.y + vbe.y;
  float o2 = (x2 - mean) * rstd * vg.z + vbe.z;
  float o3 = (x3 - mean) * rstd * vg.w + vbe.w;
  if (outf) {
    float4 o; o.x = o0; o.y = o1; o.z = o2; o.w = o3;
    ((float4*)(outf + row * H_))[t] = o;
  }
  if (outb) {
    ushort4 ob; ob.x = f2b(o0); ob.y = f2b(o1); ob.z = f2b(o2); ob.w = f2b(o3);
    ((ushort4*)(outb + row * H_))[t] = ob;
  }
}

extern "C" void kernel_launch(void* const* d_in, const int* in_sizes, int n_in,
                              void* d_out, int out_size, void* d_ws, size_t ws_size,
                              hipStream_t stream) {
  (void)in_sizes; (void)n_in; (void)out_size; (void)ws_size;
  const float* x      = (const float*)d_in[0];
  const float* enc    = (const float*)d_in[1];
  const float* sa_w[4] = {(const float*)d_in[2], (const float*)d_in[4], (const float*)d_in[6], (const float*)d_in[8]};
  const float* sa_b[4] = {(const float*)d_in[3], (const float*)d_in[5], (const float*)d_in[7], (const float*)d_in[9]};
  const float* sa_pj  = (const float*)d_in[10];
  const float* ca_w[4] = {(const float*)d_in[11], (const float*)d_in[13], (const float*)d_in[15], (const float*)d_in[17]};
  const float* ca_b[4] = {(const float*)d_in[12], (const float*)d_in[14], (const float*)d_in[16], (const float*)d_in[18]};
  const float* ca_pj  = (const float*)d_in[19];
  const float* ff_w1  = (const float*)d_in[20];
  const float* ff_b1  = (const float*)d_in[21];
  const float* ff_w2  = (const float*)d_in[22];
  const float* ff_b2  = (const float*)d_in[23];
  const float* ln1_g  = (const float*)d_in[24];
  const float* ln1_b  = (const float*)d_in[25];
  const float* ln2_g  = (const float*)d_in[26];
  const float* ln2_b  = (const float*)d_in[27];
  const float* ln3_g  = (const float*)d_in[28];
  const float* ln3_b  = (const float*)d_in[29];

  float* ws = (float*)d_ws;
  // All offsets in f32 elements. Peak footprint 54,675,456 f = 218.7 MB.
  unsigned short* XB = (unsigned short*)(ws);                 // x/h1/h2 bf16 [16384][1024]
  unsigned short* EB = (unsigned short*)(ws + 8388608LL);     // enc bf16 / AO / (ff1T+ff2T)
  unsigned short* Qb = (unsigned short*)(ws + 16777216LL);    // [4][4096][1024]
  unsigned short* Kb = (unsigned short*)(ws + 25165824LL);
  unsigned short* Vb = (unsigned short*)(ws + 33554432LL);
  unsigned short* Pq = (unsigned short*)(ws + 41943040LL);    // per-(b,g) [8][4096][256]
  unsigned short* Pk = (unsigned short*)(ws + 46137344LL);
  unsigned short* PO = Pq;                                     // [16384][1024] (spans Pq+Pk)
  unsigned short* MIDB = Pq;                                   // FFN mid chunk [4096][4096]
  unsigned short* FO = (unsigned short*)(ws + 50331648LL);    // FFN out chunk [4096][1024]
  unsigned short* WTph = (unsigned short*)(ws + 52428800LL);  // 4 x [1024][1024] bf16
  unsigned short* pjT = (unsigned short*)(ws + 54525952LL);   // 2 x [64][256] bf16
  float* ctx  = ws + 54542336LL;                               // [8][256][64] f32
  float* ksum = ws + 54673408LL;                               // [8][256] f32

  unsigned short* ff1T = EB;                 // [4096][1024] bf16 (FFN phase)
  unsigned short* ff2T = EB + 4194304LL;     // [1024][4096] bf16
  unsigned short* pjT_sa = pjT, *pjT_ca = pjT + 16384;

  dim3 blk(256, 1, 1);
  const long long sB = (long long)N_ * H_;
  const long long sAO = (long long)N_ * HD_;

  projT_cvt<<<dim3(64), blk, 0, stream>>>(sa_pj, pjT_sa);
  projT_cvt<<<dim3(64), blk, 0, stream>>>(ca_pj, pjT_ca);
  cvt_bf16<<<dim3(2048), blk, 0, stream>>>(x, XB, 16777216LL);

  auto attn = [&](const unsigned short* qA, const unsigned short* kvA,
                  const float* const* wsrc, const float* const* bs,
                  const unsigned short* pj) {
    for (int i = 0; i < 4; ++i)
      wt_cvt<<<dim3(32, 32), blk, 0, stream>>>(wsrc[i], WTph + (long long)i * 1048576, H_, H_);
    gemm_mfma<0><<<dim3(8,128), blk, 0, stream>>>(qA, H_, WTph, bs[0], Qb, H_, H_);
    gemm_mfma<0><<<dim3(8,128), blk, 0, stream>>>(kvA, H_, WTph + 1048576, bs[1], Kb, H_, H_);
    gemm_mfma<0><<<dim3(8,128), blk, 0, stream>>>(kvA, H_, WTph + 2097152, bs[2], Vb, H_, H_);
    for (int b = 0; b < B_; ++b) {
      for (int g = 0; g < 2; ++g) {
        const long long go = (long long)b * sB + g * 512;
        feat_gemm<<<dim3(1,64,8), blk, 0, stream>>>(Qb + go, H_, pj, nullptr, Pq);
        hipMemsetAsync(ksum, 0, 8 * 256 * sizeof(float), stream);
        feat_gemm<<<dim3(1,64,8), blk, 0, stream>>>(Kb + go, H_, pj, ksum, Pk);
        hipMemsetAsync(ctx, 0, 8 * M_ * HD_ * sizeof(float), stream);
        ctx_k<<<dim3(4,16,8), blk, 0, stream>>>(Pk, Vb + go, ctx);
        ao_gemm<<<dim3(1,32,8), blk, 0, stream>>>(Pq, ctx, ksum,
            EB + (long long)b * NH_ * sAO + (long long)g * 8 * sAO);
      }
    }
    gemm_mfma<0><<<dim3(8,128), blk, 0, stream>>>(EB, H_, WTph + 3145728, bs[3], PO, H_, H_);
  };

  // self-attention; ln1 reads pristine f32 x as residual; h1 bf16 -> XB
  attn(XB, XB, sa_w, sa_b, pjT_sa);
  ln_k<<<dim3(16384), blk, 0, stream>>>(x, nullptr, PO, ln1_g, ln1_b, nullptr, XB);

  // cross-attention; residual h1 bf16 (XB); h2 bf16 -> XB in place
  cvt_bf16<<<dim3(2048), blk, 0, stream>>>(enc, EB, 16777216LL);
  attn(XB, EB, ca_w, ca_b, pjT_ca);
  ln_k<<<dim3(16384), blk, 0, stream>>>(nullptr, XB, PO, ln2_g, ln2_b, nullptr, XB);

  // FFN (EB dead -> holds ff1T/ff2T; MIDB/FO chunked; ln3 -> d_out f32)
  wt_cvt<<<dim3(128, 32), blk, 0, stream>>>(ff_w1, ff1T, H_, 4096);
  wt_cvt<<<dim3(32, 128), blk, 0, stream>>>(ff_w2, ff2T, 4096, H_);
  for (int c = 0; c < 4; ++c) {
    const long long co = (long long)c * 4096 * H_;
    gemm_mfma<1><<<dim3(32,32), blk, 0, stream>>>(XB + co, H_, ff1T, ff_b1, MIDB, 4096, H_);
    gemm_mfma<0><<<dim3(8,32), blk, 0, stream>>>(MIDB, 4096, ff2T, ff_b2, FO, H_, 4096);
    ln_k<<<dim3(4096), blk, 0, stream>>>(nullptr, XB + co, FO, ln3_g, ln3_b,
                                         (float*)d_out + co, nullptr);
  }
}

// Round 6
// 5914.189 us; speedup vs baseline: 2.7029x; 1.0051x over previous
//
#include <hip/hip_runtime.h>
#include <hip/hip_bf16.h>

#define B_ 4
#define N_ 4096
#define H_ 1024
#define NH_ 16
#define HD_ 64
#define M_ 256

typedef __attribute__((ext_vector_type(8))) __bf16 bf16x8;
typedef __attribute__((ext_vector_type(4))) float f32x4;

__device__ __forceinline__ float bf2f(unsigned short u) {
  union { unsigned int i; float f; } x; x.i = ((unsigned int)u) << 16; return x.f;
}
__device__ __forceinline__ unsigned short f2b(float f) {
  __hip_bfloat16 h = __float2bfloat16(f);
  return *(unsigned short*)&h;
}
__device__ __forceinline__ float gelu_f(float x) {
  const float c = 0.7978845608028654f;
  float t = tanhf(c * (x + 0.044715f * x * x * x));
  return 0.5f * x * (1.0f + t);
}

// ---------------------------------------------------------------------------
// Dense bf16 MFMA GEMM: C[M,N] = act(A @ BT^T + bias); C bf16.
// Tile 128x128, BK=64, 4 waves. K-loop LDS XOR-swizzled.
// Epilogue: stage C tile in LDS (reusing staging buffer), then fully
// coalesced uint4 stores.
// ---------------------------------------------------------------------------
template<int ACT>
__launch_bounds__(256)
__global__ void gemm_mfma(const unsigned short* __restrict__ A, int lda,
                          const unsigned short* __restrict__ BT,
                          const float* __restrict__ bias,
                          unsigned short* __restrict__ C, int ldc, int K) {
  __shared__ unsigned short S[16384];           // 32 KB: staging A|B, then C tile
  unsigned short* As = S;
  unsigned short* Bs = S + 8192;
  char* AsB = (char*)As;
  char* BsB = (char*)Bs;
  char* SB  = (char*)S;

  const int tid = threadIdx.x;
  const int row0 = blockIdx.y * 128;
  const int col0 = blockIdx.x * 128;
  const int w = tid >> 6, lane = tid & 63;
  const int wm = w >> 1, wn = w & 1;
  const int ln = lane & 15, hi = lane >> 4;
  const int rswz = (ln & 7) << 4;

  const int rowA = tid >> 3;
  const int colA = (tid & 7) * 8;
  const int wcol = ((tid & 7) * 16) ^ (((tid >> 3) & 7) << 4);

  f32x4 acc[4][4];
#pragma unroll
  for (int i = 0; i < 4; ++i)
#pragma unroll
    for (int j = 0; j < 4; ++j) acc[i][j] = (f32x4){0.f, 0.f, 0.f, 0.f};

  uint4 ra[4], rb[4];
  const unsigned short* Ab = A + (long long)(row0 + rowA) * lda + colA;
  const unsigned short* Bb = BT + (long long)(col0 + rowA) * K + colA;
#pragma unroll
  for (int i = 0; i < 4; ++i) {
    ra[i] = *(const uint4*)(Ab + (long long)i * 32 * lda);
    rb[i] = *(const uint4*)(Bb + (long long)i * 32 * K);
  }

  for (int k0 = 0;;) {
#pragma unroll
    for (int i = 0; i < 4; ++i) {
      *(uint4*)(AsB + (rowA + i * 32) * 128 + wcol) = ra[i];
      *(uint4*)(BsB + (rowA + i * 32) * 128 + wcol) = rb[i];
    }
    __syncthreads();
    k0 += 64;
    const bool more = (k0 < K);
    if (more) {
#pragma unroll
      for (int i = 0; i < 4; ++i) {
        ra[i] = *(const uint4*)(Ab + (long long)i * 32 * lda + k0);
        rb[i] = *(const uint4*)(Bb + (long long)i * 32 * K + k0);
      }
    }
#pragma unroll
    for (int kc = 0; kc < 2; ++kc) {
      const int koff = (kc * 64 + hi * 16) ^ rswz;
      bf16x8 av[4], bv[4];
#pragma unroll
      for (int i = 0; i < 4; ++i)
        av[i] = *(bf16x8*)(AsB + (wm * 64 + i * 16 + ln) * 128 + koff);
#pragma unroll
      for (int j = 0; j < 4; ++j)
        bv[j] = *(bf16x8*)(BsB + (wn * 64 + j * 16 + ln) * 128 + koff);
#pragma unroll
      for (int i = 0; i < 4; ++i)
#pragma unroll
        for (int j = 0; j < 4; ++j)
          acc[i][j] = __builtin_amdgcn_mfma_f32_16x16x32_bf16(av[i], bv[j], acc[i][j], 0, 0, 0);
    }
    __syncthreads();
    if (!more) break;
  }

  // ---- coalesced epilogue: stage bf16 C tile in LDS (row-XOR swizzled) ----
#pragma unroll
  for (int j = 0; j < 4; ++j) {
    const int lcol = wn * 64 + j * 16 + ln;
    const float bj = bias ? bias[col0 + lcol] : 0.0f;
#pragma unroll
    for (int i = 0; i < 4; ++i) {
      const int rb_ = wm * 64 + i * 16 + hi * 4;
#pragma unroll
      for (int r = 0; r < 4; ++r) {
        float v = acc[i][j][r] + bj;
        if (ACT == 1) v = gelu_f(v);
        const int row = rb_ + r;
        *(unsigned short*)(SB + ((row * 256 + lcol * 2) ^ ((row & 7) << 4))) = f2b(v);
      }
    }
  }
  __syncthreads();
#pragma unroll
  for (int p = 0; p < 8; ++p) {
    const int idx = p * 256 + tid;
    const int row = idx >> 4, seg = idx & 15;
    uint4 v = *(uint4*)(SB + ((row * 256 + seg * 16) ^ ((row & 7) << 4)));
    *(uint4*)(C + (long long)(row0 + row) * ldc + col0 + seg * 8) = v;
  }
}

// ---------------------------------------------------------------------------
// FAVOR+ feature GEMM (SIMT fp32 math, bf16 in/out), K=64, BM=64, BN=256.
// P = (1/16)*(exp(dd - ssq/16 - rowmax) + 1e-4); optional atomic ksum.
// Output staged in LDS -> coalesced uint4 stores.
// ---------------------------------------------------------------------------
__launch_bounds__(256)
__global__ void feat_gemm(const unsigned short* __restrict__ A, int lda,
                          const unsigned short* __restrict__ W,   // [64][256] bf16
                          float* __restrict__ ksum,
                          unsigned short* __restrict__ C) {
  __shared__ float As[8][64];
  __shared__ float Ws[8][256];
  __shared__ unsigned short Ct[64 * 256];   // 32 KB output tile
  const int hh = blockIdx.z;
  A += hh * 64;
  C += (long long)hh * (N_ * M_);
  const int tid = threadIdx.x;
  const int row0 = blockIdx.y * 64;
  const int tx = tid & 31, ty = tid >> 5;
  float acc[8][8];
#pragma unroll
  for (int i = 0; i < 8; ++i)
#pragma unroll
    for (int j = 0; j < 8; ++j) acc[i][j] = 0.f;
  float dacc[8];
#pragma unroll
  for (int i = 0; i < 8; ++i) dacc[i] = 0.f;

  for (int k0 = 0; k0 < 64; k0 += 8) {
    if (tid < 128) {
      int r = tid >> 1, kk = (tid & 1) * 4;
      ushort4 v = *(const ushort4*)&A[(long long)(row0 + r) * lda + k0 + kk];
      As[kk + 0][r] = bf2f(v.x); As[kk + 1][r] = bf2f(v.y);
      As[kk + 2][r] = bf2f(v.z); As[kk + 3][r] = bf2f(v.w);
    }
    {
      int kk = tid >> 5, c = (tid & 31) * 8;
      ushort4 v0 = *(const ushort4*)&W[(k0 + kk) * 256 + c];
      ushort4 v1 = *(const ushort4*)&W[(k0 + kk) * 256 + c + 4];
      Ws[kk][c + 0] = bf2f(v0.x); Ws[kk][c + 1] = bf2f(v0.y);
      Ws[kk][c + 2] = bf2f(v0.z); Ws[kk][c + 3] = bf2f(v0.w);
      Ws[kk][c + 4] = bf2f(v1.x); Ws[kk][c + 5] = bf2f(v1.y);
      Ws[kk][c + 6] = bf2f(v1.z); Ws[kk][c + 7] = bf2f(v1.w);
    }
    __syncthreads();
#pragma unroll
    for (int kk = 0; kk < 8; ++kk) {
      float a[8], ww[8];
#pragma unroll
      for (int i = 0; i < 8; ++i) {
        int r = (i < 4) ? ty * 4 + i : 32 + ty * 4 + (i - 4);
        a[i] = As[kk][r];
      }
#pragma unroll
      for (int j = 0; j < 8; ++j) {
        int c = (j < 4) ? tx * 4 + j : 128 + tx * 4 + (j - 4);
        ww[j] = Ws[kk][c];
      }
#pragma unroll
      for (int i = 0; i < 8; ++i) dacc[i] += a[i] * a[i];
#pragma unroll
      for (int i = 0; i < 8; ++i)
#pragma unroll
        for (int j = 0; j < 8; ++j) acc[i][j] += a[i] * ww[j];
    }
    __syncthreads();
  }

  float cs[8];
#pragma unroll
  for (int j = 0; j < 8; ++j) cs[j] = 0.f;
#pragma unroll
  for (int i = 0; i < 8; ++i) {
    int ri = (i < 4) ? ty * 4 + i : 32 + ty * 4 + (i - 4);
    float rm = acc[i][0];
#pragma unroll
    for (int j = 1; j < 8; ++j) rm = fmaxf(rm, acc[i][j]);
#pragma unroll
    for (int mls = 1; mls < 32; mls <<= 1) rm = fmaxf(rm, __shfl_xor(rm, mls, 32));
    float base = 0.0625f * dacc[i] + rm;
#pragma unroll
    for (int j = 0; j < 8; ++j) {
      int cj = (j < 4) ? tx * 4 + j : 128 + tx * 4 + (j - 4);
      float v = 0.0625f * (expf(acc[i][j] - base) + 1e-4f);
      cs[j] += v;
      Ct[ri * 256 + cj] = f2b(v);
    }
  }
  __syncthreads();
#pragma unroll
  for (int p = 0; p < 8; ++p) {
    const int idx = p * 256 + tid;
    const int row = idx >> 5, seg = idx & 31;
    uint4 v = *(uint4*)((char*)Ct + row * 512 + seg * 16);
    *(uint4*)(C + (long long)(row0 + row) * 256 + seg * 8) = v;
  }
  if (ksum) {
#pragma unroll
    for (int j = 0; j < 8; ++j) {
      int cj = (j < 4) ? tx * 4 + j : 128 + tx * 4 + (j - 4);
      atomicAdd(&ksum[hh * 256 + cj], cs[j]);
    }
  }
}

// ctx[hh][m][d] += sum_{n in split} Kp[hh][n][m] * V[n][hh*64+d]
__launch_bounds__(256)
__global__ void ctx_k(const unsigned short* __restrict__ Kp, const unsigned short* __restrict__ V,
                      float* __restrict__ ctx) {
  constexpr int BK = 16;
  __shared__ float As[BK][64];
  __shared__ float Ws[BK][64];
  const int hh = blockIdx.z;
  const int m0 = blockIdx.x * 64;
  const int n0 = blockIdx.y * 256;
  const unsigned short* Kph = Kp + (long long)hh * N_ * M_;
  const unsigned short* Vh = V + hh * 64;
  const int tid = threadIdx.x;
  const int tx = tid % 16, ty = tid / 16;
  const int lr = tid / 16, lc = (tid % 16) * 4;
  float acc[4][4];
#pragma unroll
  for (int i = 0; i < 4; ++i)
#pragma unroll
    for (int j = 0; j < 4; ++j) acc[i][j] = 0.f;

  for (int k0 = n0; k0 < n0 + 256; k0 += BK) {
    ushort4 a4 = *(const ushort4*)&Kph[(long long)(k0 + lr) * M_ + m0 + lc];
    ushort4 w4 = *(const ushort4*)&Vh[(long long)(k0 + lr) * H_ + lc];
    As[lr][lc + 0] = bf2f(a4.x); As[lr][lc + 1] = bf2f(a4.y);
    As[lr][lc + 2] = bf2f(a4.z); As[lr][lc + 3] = bf2f(a4.w);
    Ws[lr][lc + 0] = bf2f(w4.x); Ws[lr][lc + 1] = bf2f(w4.y);
    Ws[lr][lc + 2] = bf2f(w4.z); Ws[lr][lc + 3] = bf2f(w4.w);
    __syncthreads();
#pragma unroll
    for (int kk = 0; kk < BK; ++kk) {
      float a[4], w[4];
#pragma unroll
      for (int i = 0; i < 4; ++i) a[i] = As[kk][ty * 4 + i];
#pragma unroll
      for (int j = 0; j < 4; ++j) w[j] = Ws[kk][tx * 4 + j];
#pragma unroll
      for (int i = 0; i < 4; ++i)
#pragma unroll
        for (int j = 0; j < 4; ++j) acc[i][j] += a[i] * w[j];
    }
    __syncthreads();
  }
#pragma unroll
  for (int i = 0; i < 4; ++i)
#pragma unroll
    for (int j = 0; j < 4; ++j)
      atomicAdd(&ctx[((long long)hh * M_ + m0 + ty * 4 + i) * 64 + tx * 4 + j], acc[i][j]);
}

// attn_out[hh][n][d] = (Qp @ ctx) / (Qp . ksum); LDS-staged coalesced output
__launch_bounds__(256)
__global__ void ao_gemm(const unsigned short* __restrict__ A,
                        const float* __restrict__ Wc, const float* __restrict__ ksum,
                        unsigned short* __restrict__ C) {
  __shared__ float As[8][128];
  __shared__ float Ws[8][64];
  __shared__ float Ks[8];
  __shared__ unsigned short Ct[128 * 64];   // 16 KB output tile
  const int hh = blockIdx.z;
  A += (long long)hh * (N_ * M_);
  const float* W = Wc + (long long)hh * M_ * HD_;
  const float* ksp = ksum + hh * 256;
  C += (long long)hh * (N_ * HD_);
  const int tid = threadIdx.x;
  const int row0 = blockIdx.y * 128;
  const int tx = tid & 15, ty = tid >> 4;
  float acc[8][4];
#pragma unroll
  for (int i = 0; i < 8; ++i)
#pragma unroll
    for (int j = 0; j < 4; ++j) acc[i][j] = 0.f;
  float dacc[8];
#pragma unroll
  for (int i = 0; i < 8; ++i) dacc[i] = 0.f;

  for (int k0 = 0; k0 < 256; k0 += 8) {
    {
      int r = tid >> 1, kk = (tid & 1) * 4;
      ushort4 v = *(const ushort4*)&A[(long long)(row0 + r) * 256 + k0 + kk];
      As[kk + 0][r] = bf2f(v.x); As[kk + 1][r] = bf2f(v.y);
      As[kk + 2][r] = bf2f(v.z); As[kk + 3][r] = bf2f(v.w);
    }
    if (tid < 128) {
      int kk = tid >> 4, c4 = (tid & 15) * 4;
      *(float4*)&Ws[kk][c4] = *(const float4*)&W[(k0 + kk) * 64 + c4];
    }
    if (tid < 8) Ks[tid] = ksp[k0 + tid];
    __syncthreads();
#pragma unroll
    for (int kk = 0; kk < 8; ++kk) {
      float a[8], w[4];
#pragma unroll
      for (int i = 0; i < 8; ++i) {
        int r = (i < 4) ? ty * 4 + i : 64 + ty * 4 + (i - 4);
        a[i] = As[kk][r];
      }
#pragma unroll
      for (int j = 0; j < 4; ++j) w[j] = Ws[kk][tx * 4 + j];
#pragma unroll
      for (int i = 0; i < 8; ++i) dacc[i] += a[i] * Ks[kk];
#pragma unroll
      for (int i = 0; i < 8; ++i)
#pragma unroll
        for (int j = 0; j < 4; ++j) acc[i][j] += a[i] * w[j];
    }
    __syncthreads();
  }
#pragma unroll
  for (int i = 0; i < 8; ++i) {
    int ri = (i < 4) ? ty * 4 + i : 64 + ty * 4 + (i - 4);
    float inv = 1.0f / dacc[i];
#pragma unroll
    for (int j = 0; j < 4; ++j)
      Ct[ri * 64 + tx * 4 + j] = f2b(acc[i][j] * inv);
  }
  __syncthreads();
  // 128 rows x 64 cols (bf16) = 128 B/row = 8 segs of 16 B per row
#pragma unroll
  for (int p = 0; p < 4; ++p) {
    const int idx = p * 256 + tid;
    const int row = idx >> 3, seg = idx & 7;
    uint4 v = *(uint4*)((char*)Ct + row * 128 + seg * 16);
    *(uint4*)(C + (long long)(row0 + row) * 64 + seg * 8) = v;
  }
}

// weight transpose+convert: out[n*K+k] = bf16(in[k*N+n])
__launch_bounds__(256)
__global__ void wt_cvt(const float* __restrict__ in, unsigned short* __restrict__ out,
                       int K, int N) {
  __shared__ float t[32][33];
  int k0 = blockIdx.y * 32, n0 = blockIdx.x * 32;
  int tx = threadIdx.x & 31, ty = threadIdx.x >> 5;
  for (int r = ty; r < 32; r += 8) t[r][tx] = in[(long long)(k0 + r) * N + n0 + tx];
  __syncthreads();
  for (int r = ty; r < 32; r += 8) out[(long long)(n0 + r) * K + k0 + tx] = f2b(t[tx][r]);
}

// projT[k][m] = bf16(dn * proj[m][k])
__launch_bounds__(256)
__global__ void projT_cvt(const float* __restrict__ proj, unsigned short* __restrict__ out) {
  int i = blockIdx.x * 256 + threadIdx.x;
  int m = i >> 6, d = i & 63;
  out[d * 256 + m] = f2b(0.35355339059327373f * proj[i]);
}

__launch_bounds__(256)
__global__ void cvt_bf16(const float* __restrict__ in, unsigned short* __restrict__ out,
                         long long n) {
  long long stride = (long long)gridDim.x * 1024;
  for (long long i = ((long long)blockIdx.x * 256 + threadIdx.x) * 4; i < n; i += stride) {
    float4 v = *(const float4*)&in[i];
    ushort4 o;
    o.x = f2b(v.x); o.y = f2b(v.y); o.z = f2b(v.z); o.w = f2b(v.w);
    *(ushort4*)&out[i] = o;
  }
}

// out = LN(res + po) * g + beta, rows of 1024.
__launch_bounds__(256)
__global__ void ln_k(const float* __restrict__ resf, const unsigned short* __restrict__ resb,
                     const unsigned short* __restrict__ po,
                     const float* __restrict__ g, const float* __restrict__ be,
                     float* __restrict__ outf, unsigned short* __restrict__ outb) {
  long long row = blockIdx.x;
  int t = threadIdx.x;
  float x0, x1, x2, x3;
  if (resf) {
    float4 va = ((const float4*)(resf + row * H_))[t];
    x0 = va.x; x1 = va.y; x2 = va.z; x3 = va.w;
  } else {
    ushort4 va = ((const ushort4*)(resb + row * H_))[t];
    x0 = bf2f(va.x); x1 = bf2f(va.y); x2 = bf2f(va.z); x3 = bf2f(va.w);
  }
  {
    ushort4 vp = ((const ushort4*)(po + row * H_))[t];
    x0 += bf2f(vp.x); x1 += bf2f(vp.y); x2 += bf2f(vp.z); x3 += bf2f(vp.w);
  }
  float s = x0 + x1 + x2 + x3;
  float q = x0 * x0 + x1 * x1 + x2 * x2 + x3 * x3;
#pragma unroll
  for (int m = 1; m < 64; m <<= 1) { s += __shfl_xor(s, m, 64); q += __shfl_xor(q, m, 64); }
  __shared__ float ssum[4], ssq[4];
  int w = t >> 6, lane = t & 63;
  if (lane == 0) { ssum[w] = s; ssq[w] = q; }
  __syncthreads();
  s = ssum[0] + ssum[1] + ssum[2] + ssum[3];
  q = ssq[0] + ssq[1] + ssq[2] + ssq[3];
  float mean = s * (1.0f / H_);
  float var = q * (1.0f / H_) - mean * mean;
  float rstd = rsqrtf(var + 1e-5f);
  float4 vg = ((const float4*)g)[t];
  float4 vbe = ((const float4*)be)[t];
  float o0 = (x0 - mean) * rstd * vg.x + vbe.x;
  float o1 = (x1 - mean) * rstd * vg.y + vbe.y;
  float o2 = (x2 - mean) * rstd * vg.z + vbe.z;
  float o3 = (x3 - mean) * rstd * vg.w + vbe.w;
  if (outf) {
    float4 o; o.x = o0; o.y = o1; o.z = o2; o.w = o3;
    ((float4*)(outf + row * H_))[t] = o;
  }
  if (outb) {
    ushort4 ob; ob.x = f2b(o0); ob.y = f2b(o1); ob.z = f2b(o2); ob.w = f2b(o3);
    ((ushort4*)(outb + row * H_))[t] = ob;
  }
}

extern "C" void kernel_launch(void* const* d_in, const int* in_sizes, int n_in,
                              void* d_out, int out_size, void* d_ws, size_t ws_size,
                              hipStream_t stream) {
  (void)in_sizes; (void)n_in; (void)out_size; (void)ws_size;
  const float* x      = (const float*)d_in[0];
  const float* enc    = (const float*)d_in[1];
  const float* sa_w[4] = {(const float*)d_in[2], (const float*)d_in[4], (const float*)d_in[6], (const float*)d_in[8]};
  const float* sa_b[4] = {(const float*)d_in[3], (const float*)d_in[5], (const float*)d_in[7], (const float*)d_in[9]};
  const float* sa_pj  = (const float*)d_in[10];
  const float* ca_w[4] = {(const float*)d_in[11], (const float*)d_in[13], (const float*)d_in[15], (const float*)d_in[17]};
  const float* ca_b[4] = {(const float*)d_in[12], (const float*)d_in[14], (const float*)d_in[16], (const float*)d_in[18]};
  const float* ca_pj  = (const float*)d_in[19];
  const float* ff_w1  = (const float*)d_in[20];
  const float* ff_b1  = (const float*)d_in[21];
  const float* ff_w2  = (const float*)d_in[22];
  const float* ff_b2  = (const float*)d_in[23];
  const float* ln1_g  = (const float*)d_in[24];
  const float* ln1_b  = (const float*)d_in[25];
  const float* ln2_g  = (const float*)d_in[26];
  const float* ln2_b  = (const float*)d_in[27];
  const float* ln3_g  = (const float*)d_in[28];
  const float* ln3_b  = (const float*)d_in[29];

  float* ws = (float*)d_ws;
  // All offsets in f32 elements. Peak footprint 54,675,456 f = 218.7 MB.
  unsigned short* XB = (unsigned short*)(ws);                 // x/h1/h2 bf16 [16384][1024]
  unsigned short* EB = (unsigned short*)(ws + 8388608LL);     // enc bf16 / AO / (ff1T+ff2T)
  unsigned short* Qb = (unsigned short*)(ws + 16777216LL);    // [4][4096][1024]
  unsigned short* Kb = (unsigned short*)(ws + 25165824LL);
  unsigned short* Vb = (unsigned short*)(ws + 33554432LL);
  unsigned short* Pq = (unsigned short*)(ws + 41943040LL);    // per-(b,g) [8][4096][256]
  unsigned short* Pk = (unsigned short*)(ws + 46137344LL);
  unsigned short* PO = Pq;                                     // [16384][1024] (spans Pq+Pk)
  unsigned short* MIDB = Pq;                                   // FFN mid chunk [4096][4096]
  unsigned short* FO = (unsigned short*)(ws + 50331648LL);    // FFN out chunk [4096][1024]
  unsigned short* WTph = (unsigned short*)(ws + 52428800LL);  // 4 x [1024][1024] bf16
  unsigned short* pjT = (unsigned short*)(ws + 54525952LL);   // 2 x [64][256] bf16
  float* ctx  = ws + 54542336LL;                               // [8][256][64] f32
  float* ksum = ws + 54673408LL;                               // [8][256] f32

  unsigned short* ff1T = EB;                 // [4096][1024] bf16 (FFN phase)
  unsigned short* ff2T = EB + 4194304LL;     // [1024][4096] bf16
  unsigned short* pjT_sa = pjT, *pjT_ca = pjT + 16384;

  dim3 blk(256, 1, 1);
  const long long sB = (long long)N_ * H_;
  const long long sAO = (long long)N_ * HD_;

  projT_cvt<<<dim3(64), blk, 0, stream>>>(sa_pj, pjT_sa);
  projT_cvt<<<dim3(64), blk, 0, stream>>>(ca_pj, pjT_ca);
  cvt_bf16<<<dim3(2048), blk, 0, stream>>>(x, XB, 16777216LL);

  auto attn = [&](const unsigned short* qA, const unsigned short* kvA,
                  const float* const* wsrc, const float* const* bs,
                  const unsigned short* pj) {
    for (int i = 0; i < 4; ++i)
      wt_cvt<<<dim3(32, 32), blk, 0, stream>>>(wsrc[i], WTph + (long long)i * 1048576, H_, H_);
    gemm_mfma<0><<<dim3(8,128), blk, 0, stream>>>(qA, H_, WTph, bs[0], Qb, H_, H_);
    gemm_mfma<0><<<dim3(8,128), blk, 0, stream>>>(kvA, H_, WTph + 1048576, bs[1], Kb, H_, H_);
    gemm_mfma<0><<<dim3(8,128), blk, 0, stream>>>(kvA, H_, WTph + 2097152, bs[2], Vb, H_, H_);
    for (int b = 0; b < B_; ++b) {
      for (int g = 0; g < 2; ++g) {
        const long long go = (long long)b * sB + g * 512;
        feat_gemm<<<dim3(1,64,8), blk, 0, stream>>>(Qb + go, H_, pj, nullptr, Pq);
        hipMemsetAsync(ksum, 0, 8 * 256 * sizeof(float), stream);
        feat_gemm<<<dim3(1,64,8), blk, 0, stream>>>(Kb + go, H_, pj, ksum, Pk);
        hipMemsetAsync(ctx, 0, 8 * M_ * HD_ * sizeof(float), stream);
        ctx_k<<<dim3(4,16,8), blk, 0, stream>>>(Pk, Vb + go, ctx);
        ao_gemm<<<dim3(1,32,8), blk, 0, stream>>>(Pq, ctx, ksum,
            EB + (long long)b * NH_ * sAO + (long long)g * 8 * sAO);
      }
    }
    gemm_mfma<0><<<dim3(8,128), blk, 0, stream>>>(EB, H_, WTph + 3145728, bs[3], PO, H_, H_);
  };

  // self-attention; ln1 reads pristine f32 x as residual; h1 bf16 -> XB
  attn(XB, XB, sa_w, sa_b, pjT_sa);
  ln_k<<<dim3(16384), blk, 0, stream>>>(x, nullptr, PO, ln1_g, ln1_b, nullptr, XB);

  // cross-attention; residual h1 bf16 (XB); h2 bf16 -> XB in place
  cvt_bf16<<<dim3(2048), blk, 0, stream>>>(enc, EB, 16777216LL);
  attn(XB, EB, ca_w, ca_b, pjT_ca);
  ln_k<<<dim3(16384), blk, 0, stream>>>(nullptr, XB, PO, ln2_g, ln2_b, nullptr, XB);

  // FFN (EB dead -> holds ff1T/ff2T; MIDB/FO chunked; ln3 -> d_out f32)
  wt_cvt<<<dim3(128, 32), blk, 0, stream>>>(ff_w1, ff1T, H_, 4096);
  wt_cvt<<<dim3(32, 128), blk, 0, stream>>>(ff_w2, ff2T, 4096, H_);
  for (int c = 0; c < 4; ++c) {
    const long long co = (long long)c * 4096 * H_;
    gemm_mfma<1><<<dim3(32,32), blk, 0, stream>>>(XB + co, H_, ff1T, ff_b1, MIDB, 4096, H_);
    gemm_mfma<0><<<dim3(8,32), blk, 0, stream>>>(MIDB, 4096, ff2T, ff_b2, FO, H_, 4096);
    ln_k<<<dim3(4096), blk, 0, stream>>>(nullptr, XB + co, FO, ln3_g, ln3_b,
                                         (float*)d_out + co, nullptr);
  }
}

// Round 8
// 4404.680 us; speedup vs baseline: 3.6292x; 1.3427x over previous
//
#include <hip/hip_runtime.h>
#include <hip/hip_bf16.h>

#define B_ 4
#define N_ 4096
#define H_ 1024
#define NH_ 16
#define HD_ 64
#define M_ 256

typedef __attribute__((ext_vector_type(8))) __bf16 bf16x8;
typedef __attribute__((ext_vector_type(4))) float f32x4;
typedef __attribute__((ext_vector_type(4))) unsigned int u32x4;

__device__ __forceinline__ float bf2f(unsigned short u) {
  union { unsigned int i; float f; } x; x.i = ((unsigned int)u) << 16; return x.f;
}
__device__ __forceinline__ unsigned short f2b(float f) {
  __hip_bfloat16 h = __float2bfloat16(f);
  return *(unsigned short*)&h;
}
__device__ __forceinline__ float gelu_f(float x) {
  const float c = 0.7978845608028654f;
  float t = tanhf(c * (x + 0.044715f * x * x * x));
  return 0.5f * x * (1.0f + t);
}

typedef __attribute__((address_space(3))) unsigned int as3_uint;
typedef const __attribute__((address_space(1))) unsigned int as1_uint;
__device__ __forceinline__ void gload16(const void* g, void* l) {
  __builtin_amdgcn_global_load_lds((as1_uint*)g, (as3_uint*)l, 16, 0, 0);
}

// ---------------------------------------------------------------------------
// Dense bf16 MFMA GEMM: C[M,N] = act(A @ BT^T + bias); C bf16.
// Tile 128x128, BK=64, 4 waves.
// - global_load_lds width-16 staging: linear LDS dest (wave base + lane*16),
//   source address pre-XOR-swizzled so LDS content == old swizzled layout.
// - XCD-aware bijective block swizzle (same-row tiles share an XCD's L2).
// - LDS-staged epilogue with nontemporal coalesced stores.
// ---------------------------------------------------------------------------
template<int ACT>
__launch_bounds__(256)
__global__ void gemm_mfma(const unsigned short* __restrict__ A, int lda,
                          const unsigned short* __restrict__ BT,
                          const float* __restrict__ bias,
                          unsigned short* __restrict__ C, int ldc, int K) {
  __shared__ unsigned short S[16384];           // 32 KB: A-tile 16K | B-tile 16K
  char* SB  = (char*)S;
  char* AsB = SB;
  char* BsB = SB + 16384;

  const int tid = threadIdx.x;
  // XCD swizzle (bijective: all our grids have nwg % 8 == 0)
  const int nwg = gridDim.x * gridDim.y;
  const int lin = blockIdx.y * gridDim.x + blockIdx.x;
  const int mm = (lin & 7) * (nwg >> 3) + (lin >> 3);
  const int bx = mm % gridDim.x, by = mm / gridDim.x;
  const int row0 = by * 128;
  const int col0 = bx * 128;

  const int w = tid >> 6, lane = tid & 63;
  const int wm = w >> 1, wn = w & 1;
  const int ln = lane & 15, hi = lane >> 4;
  const int rswz = (ln & 7) << 4;

  // staging: wave w covers rows w*8 + (lane>>3) + i*32; chunk pre-swizzled
  const int srow = w * 8 + (lane >> 3);
  const int schunk = ((lane & 7) ^ (lane >> 3)) * 8;   // element offset in k
  const unsigned short* Ag = A + (long long)(row0 + srow) * lda + schunk;
  const unsigned short* Bg = BT + (long long)(col0 + srow) * K + schunk;
  const int ldsw = w * 1024;                            // wave's byte base

  f32x4 acc[4][4];
#pragma unroll
  for (int i = 0; i < 4; ++i)
#pragma unroll
    for (int j = 0; j < 4; ++j) acc[i][j] = (f32x4){0.f, 0.f, 0.f, 0.f};

  for (int k0 = 0; k0 < K; k0 += 64) {
#pragma unroll
    for (int i = 0; i < 4; ++i) {
      gload16(Ag + (long long)i * 32 * lda + k0, AsB + ldsw + i * 4096);
      gload16(Bg + (long long)i * 32 * K + k0, BsB + ldsw + i * 4096);
    }
    __syncthreads();   // drains vmcnt (compiler emits s_waitcnt before barrier)
#pragma unroll
    for (int kc = 0; kc < 2; ++kc) {
      const int koff = (kc * 64 + hi * 16) ^ rswz;
      bf16x8 av[4], bv[4];
#pragma unroll
      for (int i = 0; i < 4; ++i)
        av[i] = *(bf16x8*)(AsB + (wm * 64 + i * 16 + ln) * 128 + koff);
#pragma unroll
      for (int j = 0; j < 4; ++j)
        bv[j] = *(bf16x8*)(BsB + (wn * 64 + j * 16 + ln) * 128 + koff);
#pragma unroll
      for (int i = 0; i < 4; ++i)
#pragma unroll
        for (int j = 0; j < 4; ++j)
          acc[i][j] = __builtin_amdgcn_mfma_f32_16x16x32_bf16(av[i], bv[j], acc[i][j], 0, 0, 0);
    }
    __syncthreads();
  }

  // ---- coalesced epilogue: stage bf16 C tile in LDS (row-XOR swizzled) ----
#pragma unroll
  for (int j = 0; j < 4; ++j) {
    const int lcol = wn * 64 + j * 16 + ln;
    const float bj = bias ? bias[col0 + lcol] : 0.0f;
#pragma unroll
    for (int i = 0; i < 4; ++i) {
      const int rb_ = wm * 64 + i * 16 + hi * 4;
#pragma unroll
      for (int r = 0; r < 4; ++r) {
        float v = acc[i][j][r] + bj;
        if (ACT == 1) v = gelu_f(v);
        const int row = rb_ + r;
        *(unsigned short*)(SB + ((row * 256 + lcol * 2) ^ ((row & 7) << 4))) = f2b(v);
      }
    }
  }
  __syncthreads();
#pragma unroll
  for (int p = 0; p < 8; ++p) {
    const int idx = p * 256 + tid;
    const int row = idx >> 4, seg = idx & 15;
    u32x4 v = *(u32x4*)(SB + ((row * 256 + seg * 16) ^ ((row & 7) << 4)));
    __builtin_nontemporal_store(v, (u32x4*)(C + (long long)(row0 + row) * ldc + col0 + seg * 8));
  }
}

// ---------------------------------------------------------------------------
// FAVOR+ feature GEMM (SIMT fp32 math, bf16 in/out), K=64, BM=64, BN=256.
// P = (1/16)*(exp(dd - ssq/16 - rowmax) + 1e-4); optional atomic ksum.
// zk/zc: buffers this launch zeroes (from blockIdx.y==0) for the NEXT kernels
// (replaces hipMemsetAsync launches).
// ---------------------------------------------------------------------------
__launch_bounds__(256)
__global__ void feat_gemm(const unsigned short* __restrict__ A, int lda,
                          const unsigned short* __restrict__ W,   // [64][256] bf16
                          float* __restrict__ ksum,
                          unsigned short* __restrict__ C,
                          float* __restrict__ zk, float* __restrict__ zc) {
  __shared__ float As[8][64];
  __shared__ float Ws[8][256];
  __shared__ unsigned short Ct[64 * 256];   // 32 KB output tile
  const int hh = blockIdx.z;
  const int tid = threadIdx.x;
  if (zk && blockIdx.y == 0) {
    zk[hh * 256 + tid] = 0.f;
    float4* p = (float4*)(zc + (long long)hh * 16384);
    for (int q = tid; q < 4096; q += 256) p[q] = (float4){0.f, 0.f, 0.f, 0.f};
  }
  A += hh * 64;
  C += (long long)hh * (N_ * M_);
  const int row0 = blockIdx.y * 64;
  const int tx = tid & 31, ty = tid >> 5;
  float acc[8][8];
#pragma unroll
  for (int i = 0; i < 8; ++i)
#pragma unroll
    for (int j = 0; j < 8; ++j) acc[i][j] = 0.f;
  float dacc[8];
#pragma unroll
  for (int i = 0; i < 8; ++i) dacc[i] = 0.f;

  for (int k0 = 0; k0 < 64; k0 += 8) {
    if (tid < 128) {
      int r = tid >> 1, kk = (tid & 1) * 4;
      ushort4 v = *(const ushort4*)&A[(long long)(row0 + r) * lda + k0 + kk];
      As[kk + 0][r] = bf2f(v.x); As[kk + 1][r] = bf2f(v.y);
      As[kk + 2][r] = bf2f(v.z); As[kk + 3][r] = bf2f(v.w);
    }
    {
      int kk = tid >> 5, c = (tid & 31) * 8;
      ushort4 v0 = *(const ushort4*)&W[(k0 + kk) * 256 + c];
      ushort4 v1 = *(const ushort4*)&W[(k0 + kk) * 256 + c + 4];
      Ws[kk][c + 0] = bf2f(v0.x); Ws[kk][c + 1] = bf2f(v0.y);
      Ws[kk][c + 2] = bf2f(v0.z); Ws[kk][c + 3] = bf2f(v0.w);
      Ws[kk][c + 4] = bf2f(v1.x); Ws[kk][c + 5] = bf2f(v1.y);
      Ws[kk][c + 6] = bf2f(v1.z); Ws[kk][c + 7] = bf2f(v1.w);
    }
    __syncthreads();
#pragma unroll
    for (int kk = 0; kk < 8; ++kk) {
      float a[8], ww[8];
#pragma unroll
      for (int i = 0; i < 8; ++i) {
        int r = (i < 4) ? ty * 4 + i : 32 + ty * 4 + (i - 4);
        a[i] = As[kk][r];
      }
#pragma unroll
      for (int j = 0; j < 8; ++j) {
        int c = (j < 4) ? tx * 4 + j : 128 + tx * 4 + (j - 4);
        ww[j] = Ws[kk][c];
      }
#pragma unroll
      for (int i = 0; i < 8; ++i) dacc[i] += a[i] * a[i];
#pragma unroll
      for (int i = 0; i < 8; ++i)
#pragma unroll
        for (int j = 0; j < 8; ++j) acc[i][j] += a[i] * ww[j];
    }
    __syncthreads();
  }

  float cs[8];
#pragma unroll
  for (int j = 0; j < 8; ++j) cs[j] = 0.f;
#pragma unroll
  for (int i = 0; i < 8; ++i) {
    int ri = (i < 4) ? ty * 4 + i : 32 + ty * 4 + (i - 4);
    float rm = acc[i][0];
#pragma unroll
    for (int j = 1; j < 8; ++j) rm = fmaxf(rm, acc[i][j]);
#pragma unroll
    for (int mls = 1; mls < 32; mls <<= 1) rm = fmaxf(rm, __shfl_xor(rm, mls, 32));
    float base = 0.0625f * dacc[i] + rm;
#pragma unroll
    for (int j = 0; j < 8; ++j) {
      int cj = (j < 4) ? tx * 4 + j : 128 + tx * 4 + (j - 4);
      float v = 0.0625f * (expf(acc[i][j] - base) + 1e-4f);
      cs[j] += v;
      Ct[ri * 256 + cj] = f2b(v);
    }
  }
  __syncthreads();
#pragma unroll
  for (int p = 0; p < 8; ++p) {
    const int idx = p * 256 + tid;
    const int row = idx >> 5, seg = idx & 31;
    uint4 v = *(uint4*)((char*)Ct + row * 512 + seg * 16);
    *(uint4*)(C + (long long)(row0 + row) * 256 + seg * 8) = v;
  }
  if (ksum) {
#pragma unroll
    for (int j = 0; j < 8; ++j) {
      int cj = (j < 4) ? tx * 4 + j : 128 + tx * 4 + (j - 4);
      atomicAdd(&ksum[hh * 256 + cj], cs[j]);
    }
  }
}

// ctx[hh][m][d] += sum_{n in split} Kp[hh][n][m] * V[n][hh*64+d]
__launch_bounds__(256)
__global__ void ctx_k(const unsigned short* __restrict__ Kp, const unsigned short* __restrict__ V,
                      float* __restrict__ ctx) {
  constexpr int BK = 16;
  __shared__ float As[BK][64];
  __shared__ float Ws[BK][64];
  const int hh = blockIdx.z;
  const int m0 = blockIdx.x * 64;
  const int n0 = blockIdx.y * 256;
  const unsigned short* Kph = Kp + (long long)hh * N_ * M_;
  const unsigned short* Vh = V + hh * 64;
  const int tid = threadIdx.x;
  const int tx = tid % 16, ty = tid / 16;
  const int lr = tid / 16, lc = (tid % 16) * 4;
  float acc[4][4];
#pragma unroll
  for (int i = 0; i < 4; ++i)
#pragma unroll
    for (int j = 0; j < 4; ++j) acc[i][j] = 0.f;

  for (int k0 = n0; k0 < n0 + 256; k0 += BK) {
    ushort4 a4 = *(const ushort4*)&Kph[(long long)(k0 + lr) * M_ + m0 + lc];
    ushort4 w4 = *(const ushort4*)&Vh[(long long)(k0 + lr) * H_ + lc];
    As[lr][lc + 0] = bf2f(a4.x); As[lr][lc + 1] = bf2f(a4.y);
    As[lr][lc + 2] = bf2f(a4.z); As[lr][lc + 3] = bf2f(a4.w);
    Ws[lr][lc + 0] = bf2f(w4.x); Ws[lr][lc + 1] = bf2f(w4.y);
    Ws[lr][lc + 2] = bf2f(w4.z); Ws[lr][lc + 3] = bf2f(w4.w);
    __syncthreads();
#pragma unroll
    for (int kk = 0; kk < BK; ++kk) {
      float a[4], w[4];
#pragma unroll
      for (int i = 0; i < 4; ++i) a[i] = As[kk][ty * 4 + i];
#pragma unroll
      for (int j = 0; j < 4; ++j) w[j] = Ws[kk][tx * 4 + j];
#pragma unroll
      for (int i = 0; i < 4; ++i)
#pragma unroll
        for (int j = 0; j < 4; ++j) acc[i][j] += a[i] * w[j];
    }
    __syncthreads();
  }
#pragma unroll
  for (int i = 0; i < 4; ++i)
#pragma unroll
    for (int j = 0; j < 4; ++j)
      atomicAdd(&ctx[((long long)hh * M_ + m0 + ty * 4 + i) * 64 + tx * 4 + j], acc[i][j]);
}

// attn_out[hh][n][d] = (Qp @ ctx) / (Qp . ksum); LDS-staged coalesced output
__launch_bounds__(256)
__global__ void ao_gemm(const unsigned short* __restrict__ A,
                        const float* __restrict__ Wc, const float* __restrict__ ksum,
                        unsigned short* __restrict__ C) {
  __shared__ float As[8][128];
  __shared__ float Ws[8][64];
  __shared__ float Ks[8];
  __shared__ unsigned short Ct[128 * 64];   // 16 KB output tile
  const int hh = blockIdx.z;
  A += (long long)hh * (N_ * M_);
  const float* W = Wc + (long long)hh * M_ * HD_;
  const float* ksp = ksum + hh * 256;
  C += (long long)hh * (N_ * HD_);
  const int tid = threadIdx.x;
  const int row0 = blockIdx.y * 128;
  const int tx = tid & 15, ty = tid >> 4;
  float acc[8][4];
#pragma unroll
  for (int i = 0; i < 8; ++i)
#pragma unroll
    for (int j = 0; j < 4; ++j) acc[i][j] = 0.f;
  float dacc[8];
#pragma unroll
  for (int i = 0; i < 8; ++i) dacc[i] = 0.f;

  for (int k0 = 0; k0 < 256; k0 += 8) {
    {
      int r = tid >> 1, kk = (tid & 1) * 4;
      ushort4 v = *(const ushort4*)&A[(long long)(row0 + r) * 256 + k0 + kk];
      As[kk + 0][r] = bf2f(v.x); As[kk + 1][r] = bf2f(v.y);
      As[kk + 2][r] = bf2f(v.z); As[kk + 3][r] = bf2f(v.w);
    }
    if (tid < 128) {
      int kk = tid >> 4, c4 = (tid & 15) * 4;
      *(float4*)&Ws[kk][c4] = *(const float4*)&W[(k0 + kk) * 64 + c4];
    }
    if (tid < 8) Ks[tid] = ksp[k0 + tid];
    __syncthreads();
#pragma unroll
    for (int kk = 0; kk < 8; ++kk) {
      float a[8], w[4];
#pragma unroll
      for (int i = 0; i < 8; ++i) {
        int r = (i < 4) ? ty * 4 + i : 64 + ty * 4 + (i - 4);
        a[i] = As[kk][r];
      }
#pragma unroll
      for (int j = 0; j < 4; ++j) w[j] = Ws[kk][tx * 4 + j];
#pragma unroll
      for (int i = 0; i < 8; ++i) dacc[i] += a[i] * Ks[kk];
#pragma unroll
      for (int i = 0; i < 8; ++i)
#pragma unroll
        for (int j = 0; j < 4; ++j) acc[i][j] += a[i] * w[j];
    }
    __syncthreads();
  }
#pragma unroll
  for (int i = 0; i < 8; ++i) {
    int ri = (i < 4) ? ty * 4 + i : 64 + ty * 4 + (i - 4);
    float inv = 1.0f / dacc[i];
#pragma unroll
    for (int j = 0; j < 4; ++j)
      Ct[ri * 64 + tx * 4 + j] = f2b(acc[i][j] * inv);
  }
  __syncthreads();
  // 128 rows x 64 cols (bf16) = 128 B/row = 8 segs of 16 B per row
#pragma unroll
  for (int p = 0; p < 4; ++p) {
    const int idx = p * 256 + tid;
    const int row = idx >> 3, seg = idx & 7;
    uint4 v = *(uint4*)((char*)Ct + row * 128 + seg * 16);
    *(uint4*)(C + (long long)(row0 + row) * 64 + seg * 8) = v;
  }
}

// weight transpose+convert: out[n*K+k] = bf16(in[k*N+n])
__launch_bounds__(256)
__global__ void wt_cvt(const float* __restrict__ in, unsigned short* __restrict__ out,
                       int K, int N) {
  __shared__ float t[32][33];
  int k0 = blockIdx.y * 32, n0 = blockIdx.x * 32;
  int tx = threadIdx.x & 31, ty = threadIdx.x >> 5;
  for (int r = ty; r < 32; r += 8) t[r][tx] = in[(long long)(k0 + r) * N + n0 + tx];
  __syncthreads();
  for (int r = ty; r < 32; r += 8) out[(long long)(n0 + r) * K + k0 + tx] = f2b(t[tx][r]);
}

// projT[k][m] = bf16(dn * proj[m][k])
__launch_bounds__(256)
__global__ void projT_cvt(const float* __restrict__ proj, unsigned short* __restrict__ out) {
  int i = blockIdx.x * 256 + threadIdx.x;
  int m = i >> 6, d = i & 63;
  out[d * 256 + m] = f2b(0.35355339059327373f * proj[i]);
}

__launch_bounds__(256)
__global__ void cvt_bf16(const float* __restrict__ in, unsigned short* __restrict__ out,
                         long long n) {
  long long stride = (long long)gridDim.x * 1024;
  for (long long i = ((long long)blockIdx.x * 256 + threadIdx.x) * 4; i < n; i += stride) {
    float4 v = *(const float4*)&in[i];
    ushort4 o;
    o.x = f2b(v.x); o.y = f2b(v.y); o.z = f2b(v.z); o.w = f2b(v.w);
    *(ushort4*)&out[i] = o;
  }
}

// out = LN(res + po) * g + beta, rows of 1024.
__launch_bounds__(256)
__global__ void ln_k(const float* __restrict__ resf, const unsigned short* __restrict__ resb,
                     const unsigned short* __restrict__ po,
                     const float* __restrict__ g, const float* __restrict__ be,
                     float* __restrict__ outf, unsigned short* __restrict__ outb) {
  long long row = blockIdx.x;
  int t = threadIdx.x;
  float x0, x1, x2, x3;
  if (resf) {
    float4 va = ((const float4*)(resf + row * H_))[t];
    x0 = va.x; x1 = va.y; x2 = va.z; x3 = va.w;
  } else {
    ushort4 va = ((const ushort4*)(resb + row * H_))[t];
    x0 = bf2f(va.x); x1 = bf2f(va.y); x2 = bf2f(va.z); x3 = bf2f(va.w);
  }
  {
    ushort4 vp = ((const ushort4*)(po + row * H_))[t];
    x0 += bf2f(vp.x); x1 += bf2f(vp.y); x2 += bf2f(vp.z); x3 += bf2f(vp.w);
  }
  float s = x0 + x1 + x2 + x3;
  float q = x0 * x0 + x1 * x1 + x2 * x2 + x3 * x3;
#pragma unroll
  for (int m = 1; m < 64; m <<= 1) { s += __shfl_xor(s, m, 64); q += __shfl_xor(q, m, 64); }
  __shared__ float ssum[4], ssq[4];
  int w = t >> 6, lane = t & 63;
  if (lane == 0) { ssum[w] = s; ssq[w] = q; }
  __syncthreads();
  s = ssum[0] + ssum[1] + ssum[2] + ssum[3];
  q = ssq[0] + ssq[1] + ssq[2] + ssq[3];
  float mean = s * (1.0f / H_);
  float var = q * (1.0f / H_) - mean * mean;
  float rstd = rsqrtf(var + 1e-5f);
  float4 vg = ((const float4*)g)[t];
  float4 vbe = ((const float4*)be)[t];
  float o0 = (x0 - mean) * rstd * vg.x + vbe.x;
  float o1 = (x1 - mean) * rstd * vg.y + vbe.y;
  float o2 = (x2 - mean) * rstd * vg.z + vbe.z;
  float o3 = (x3 - mean) * rstd * vg.w + vbe.w;
  if (outf) {
    float4 o; o.x = o0; o.y = o1; o.z = o2; o.w = o3;
    ((float4*)(outf + row * H_))[t] = o;
  }
  if (outb) {
    ushort4 ob; ob.x = f2b(o0); ob.y = f2b(o1); ob.z = f2b(o2); ob.w = f2b(o3);
    ((ushort4*)(outb + row * H_))[t] = ob;
  }
}

extern "C" void kernel_launch(void* const* d_in, const int* in_sizes, int n_in,
                              void* d_out, int out_size, void* d_ws, size_t ws_size,
                              hipStream_t stream) {
  (void)in_sizes; (void)n_in; (void)out_size; (void)ws_size;
  const float* x      = (const float*)d_in[0];
  const float* enc    = (const float*)d_in[1];
  const float* sa_w[4] = {(const float*)d_in[2], (const float*)d_in[4], (const float*)d_in[6], (const float*)d_in[8]};
  const float* sa_b[4] = {(const float*)d_in[3], (const float*)d_in[5], (const float*)d_in[7], (const float*)d_in[9]};
  const float* sa_pj  = (const float*)d_in[10];
  const float* ca_w[4] = {(const float*)d_in[11], (const float*)d_in[13], (const float*)d_in[15], (const float*)d_in[17]};
  const float* ca_b[4] = {(const float*)d_in[12], (const float*)d_in[14], (const float*)d_in[16], (const float*)d_in[18]};
  const float* ca_pj  = (const float*)d_in[19];
  const float* ff_w1  = (const float*)d_in[20];
  const float* ff_b1  = (const float*)d_in[21];
  const float* ff_w2  = (const float*)d_in[22];
  const float* ff_b2  = (const float*)d_in[23];
  const float* ln1_g  = (const float*)d_in[24];
  const float* ln1_b  = (const float*)d_in[25];
  const float* ln2_g  = (const float*)d_in[26];
  const float* ln2_b  = (const float*)d_in[27];
  const float* ln3_g  = (const float*)d_in[28];
  const float* ln3_b  = (const float*)d_in[29];

  float* ws = (float*)d_ws;
  // All offsets in f32 elements. Peak footprint 54,675,456 f = 218.7 MB.
  unsigned short* XB = (unsigned short*)(ws);                 // x/h1/h2 bf16 [16384][1024]
  unsigned short* EB = (unsigned short*)(ws + 8388608LL);     // enc bf16 / AO / (ff1T+ff2T)
  unsigned short* Qb = (unsigned short*)(ws + 16777216LL);    // [4][4096][1024]
  unsigned short* Kb = (unsigned short*)(ws + 25165824LL);
  unsigned short* Vb = (unsigned short*)(ws + 33554432LL);
  unsigned short* Pq = (unsigned short*)(ws + 41943040LL);    // per-(b,g) [8][4096][256]
  unsigned short* Pk = (unsigned short*)(ws + 46137344LL);
  unsigned short* PO = Pq;                                     // [16384][1024] (spans Pq+Pk)
  unsigned short* MIDB = Pq;                                   // FFN mid chunk [4096][4096]
  unsigned short* FO = (unsigned short*)(ws + 50331648LL);    // FFN out chunk [4096][1024]
  unsigned short* WTph = (unsigned short*)(ws + 52428800LL);  // 4 x [1024][1024] bf16
  unsigned short* pjT = (unsigned short*)(ws + 54525952LL);   // 2 x [64][256] bf16
  float* ctx  = ws + 54542336LL;                               // [8][256][64] f32
  float* ksum = ws + 54673408LL;                               // [8][256] f32

  unsigned short* ff1T = EB;                 // [4096][1024] bf16 (FFN phase)
  unsigned short* ff2T = EB + 4194304LL;     // [1024][4096] bf16
  unsigned short* pjT_sa = pjT, *pjT_ca = pjT + 16384;

  dim3 blk(256, 1, 1);
  const long long sB = (long long)N_ * H_;
  const long long sAO = (long long)N_ * HD_;

  projT_cvt<<<dim3(64), blk, 0, stream>>>(sa_pj, pjT_sa);
  projT_cvt<<<dim3(64), blk, 0, stream>>>(ca_pj, pjT_ca);
  cvt_bf16<<<dim3(2048), blk, 0, stream>>>(x, XB, 16777216LL);

  auto attn = [&](const unsigned short* qA, const unsigned short* kvA,
                  const float* const* wsrc, const float* const* bs,
                  const unsigned short* pj) {
    for (int i = 0; i < 4; ++i)
      wt_cvt<<<dim3(32, 32), blk, 0, stream>>>(wsrc[i], WTph + (long long)i * 1048576, H_, H_);
    gemm_mfma<0><<<dim3(8,128), blk, 0, stream>>>(qA, H_, WTph, bs[0], Qb, H_, H_);
    gemm_mfma<0><<<dim3(8,128), blk, 0, stream>>>(kvA, H_, WTph + 1048576, bs[1], Kb, H_, H_);
    gemm_mfma<0><<<dim3(8,128), blk, 0, stream>>>(kvA, H_, WTph + 2097152, bs[2], Vb, H_, H_);
    for (int b = 0; b < B_; ++b) {
      for (int g = 0; g < 2; ++g) {
        const long long go = (long long)b * sB + g * 512;
        // Q-feat also zeroes ksum+ctx for the following K-feat/ctx_k (no memsets)
        feat_gemm<<<dim3(1,64,8), blk, 0, stream>>>(Qb + go, H_, pj, nullptr, Pq, ksum, ctx);
        feat_gemm<<<dim3(1,64,8), blk, 0, stream>>>(Kb + go, H_, pj, ksum, Pk, nullptr, nullptr);
        ctx_k<<<dim3(4,16,8), blk, 0, stream>>>(Pk, Vb + go, ctx);
        ao_gemm<<<dim3(1,32,8), blk, 0, stream>>>(Pq, ctx, ksum,
            EB + (long long)b * NH_ * sAO + (long long)g * 8 * sAO);
      }
    }
    gemm_mfma<0><<<dim3(8,128), blk, 0, stream>>>(EB, H_, WTph + 3145728, bs[3], PO, H_, H_);
  };

  // self-attention; ln1 reads pristine f32 x as residual; h1 bf16 -> XB
  attn(XB, XB, sa_w, sa_b, pjT_sa);
  ln_k<<<dim3(16384), blk, 0, stream>>>(x, nullptr, PO, ln1_g, ln1_b, nullptr, XB);

  // cross-attention; residual h1 bf16 (XB); h2 bf16 -> XB in place
  cvt_bf16<<<dim3(2048), blk, 0, stream>>>(enc, EB, 16777216LL);
  attn(XB, EB, ca_w, ca_b, pjT_ca);
  ln_k<<<dim3(16384), blk, 0, stream>>>(nullptr, XB, PO, ln2_g, ln2_b, nullptr, XB);

  // FFN (EB dead -> holds ff1T/ff2T; MIDB/FO chunked; ln3 -> d_out f32)
  wt_cvt<<<dim3(128, 32), blk, 0, stream>>>(ff_w1, ff1T, H_, 4096);
  wt_cvt<<<dim3(32, 128), blk, 0, stream>>>(ff_w2, ff2T, 4096, H_);
  for (int c = 0; c < 4; ++c) {
    const long long co = (long long)c * 4096 * H_;
    gemm_mfma<1><<<dim3(32,32), blk, 0, stream>>>(XB + co, H_, ff1T, ff_b1, MIDB, 4096, H_);
    gemm_mfma<0><<<dim3(8,32), blk, 0, stream>>>(MIDB, 4096, ff2T, ff_b2, FO, H_, 4096);
    ln_k<<<dim3(4096), blk, 0, stream>>>(nullptr, XB + co, FO, ln3_g, ln3_b,
                                         (float*)d_out + co, nullptr);
  }
}

// Round 9
// 2480.944 us; speedup vs baseline: 6.4433x; 1.7754x over previous
//
#include <hip/hip_runtime.h>
#include <hip/hip_bf16.h>

#define B_ 4
#define N_ 4096
#define H_ 1024
#define NH_ 16
#define HD_ 64
#define M_ 256

typedef __attribute__((ext_vector_type(8))) __bf16 bf16x8;
typedef __attribute__((ext_vector_type(4))) float f32x4;
typedef __attribute__((ext_vector_type(4))) unsigned int u32x4;

__device__ __forceinline__ float bf2f(unsigned short u) {
  union { unsigned int i; float f; } x; x.i = ((unsigned int)u) << 16; return x.f;
}
__device__ __forceinline__ unsigned short f2b(float f) {
  __hip_bfloat16 h = __float2bfloat16(f);
  return *(unsigned short*)&h;
}
__device__ __forceinline__ float gelu_f(float x) {
  const float c = 0.7978845608028654f;
  float t = tanhf(c * (x + 0.044715f * x * x * x));
  return 0.5f * x * (1.0f + t);
}

typedef __attribute__((address_space(3))) unsigned int as3_uint;
typedef const __attribute__((address_space(1))) unsigned int as1_uint;
__device__ __forceinline__ void gload16(const void* g, void* l) {
  __builtin_amdgcn_global_load_lds((as1_uint*)g, (as3_uint*)l, 16, 0, 0);
}

// ---------------------------------------------------------------------------
// Dense bf16 MFMA GEMM (unchanged from round 8; verified).
// ---------------------------------------------------------------------------
template<int ACT>
__launch_bounds__(256)
__global__ void gemm_mfma(const unsigned short* __restrict__ A, int lda,
                          const unsigned short* __restrict__ BT,
                          const float* __restrict__ bias,
                          unsigned short* __restrict__ C, int ldc, int K) {
  __shared__ unsigned short S[16384];
  char* SB  = (char*)S;
  char* AsB = SB;
  char* BsB = SB + 16384;

  const int tid = threadIdx.x;
  const int nwg = gridDim.x * gridDim.y;
  const int lin = blockIdx.y * gridDim.x + blockIdx.x;
  const int mm = (lin & 7) * (nwg >> 3) + (lin >> 3);
  const int bx = mm % gridDim.x, by = mm / gridDim.x;
  const int row0 = by * 128;
  const int col0 = bx * 128;

  const int w = tid >> 6, lane = tid & 63;
  const int wm = w >> 1, wn = w & 1;
  const int ln = lane & 15, hi = lane >> 4;
  const int rswz = (ln & 7) << 4;

  const int srow = w * 8 + (lane >> 3);
  const int schunk = ((lane & 7) ^ (lane >> 3)) * 8;
  const unsigned short* Ag = A + (long long)(row0 + srow) * lda + schunk;
  const unsigned short* Bg = BT + (long long)(col0 + srow) * K + schunk;
  const int ldsw = w * 1024;

  f32x4 acc[4][4];
#pragma unroll
  for (int i = 0; i < 4; ++i)
#pragma unroll
    for (int j = 0; j < 4; ++j) acc[i][j] = (f32x4){0.f, 0.f, 0.f, 0.f};

  for (int k0 = 0; k0 < K; k0 += 64) {
#pragma unroll
    for (int i = 0; i < 4; ++i) {
      gload16(Ag + (long long)i * 32 * lda + k0, AsB + ldsw + i * 4096);
      gload16(Bg + (long long)i * 32 * K + k0, BsB + ldsw + i * 4096);
    }
    __syncthreads();
#pragma unroll
    for (int kc = 0; kc < 2; ++kc) {
      const int koff = (kc * 64 + hi * 16) ^ rswz;
      bf16x8 av[4], bv[4];
#pragma unroll
      for (int i = 0; i < 4; ++i)
        av[i] = *(bf16x8*)(AsB + (wm * 64 + i * 16 + ln) * 128 + koff);
#pragma unroll
      for (int j = 0; j < 4; ++j)
        bv[j] = *(bf16x8*)(BsB + (wn * 64 + j * 16 + ln) * 128 + koff);
#pragma unroll
      for (int i = 0; i < 4; ++i)
#pragma unroll
        for (int j = 0; j < 4; ++j)
          acc[i][j] = __builtin_amdgcn_mfma_f32_16x16x32_bf16(av[i], bv[j], acc[i][j], 0, 0, 0);
    }
    __syncthreads();
  }

#pragma unroll
  for (int j = 0; j < 4; ++j) {
    const int lcol = wn * 64 + j * 16 + ln;
    const float bj = bias ? bias[col0 + lcol] : 0.0f;
#pragma unroll
    for (int i = 0; i < 4; ++i) {
      const int rb_ = wm * 64 + i * 16 + hi * 4;
#pragma unroll
      for (int r = 0; r < 4; ++r) {
        float v = acc[i][j][r] + bj;
        if (ACT == 1) v = gelu_f(v);
        const int row = rb_ + r;
        *(unsigned short*)(SB + ((row * 256 + lcol * 2) ^ ((row & 7) << 4))) = f2b(v);
      }
    }
  }
  __syncthreads();
#pragma unroll
  for (int p = 0; p < 8; ++p) {
    const int idx = p * 256 + tid;
    const int row = idx >> 4, seg = idx & 15;
    u32x4 v = *(u32x4*)(SB + ((row * 256 + seg * 16) ^ ((row & 7) << 4)));
    __builtin_nontemporal_store(v, (u32x4*)(C + (long long)(row0 + row) * ldc + col0 + seg * 8));
  }
}

// ---------------------------------------------------------------------------
// FAVOR+ feature GEMM via MFMA. Tile 64 rows x 256 cols, K=64, 4 waves
// (wave w owns cols w*64..w*64+63). A: activations (bf16, lda=1024, head off
// hh*64). B: pjB = dn*proj [256][64] bf16. P=(1/16)(exp(dd-ssq/16-rowmax)+1e-4).
// MODE 0 (K): atomicAdd column sums into ksum[hh][m].
// MODE 1 (Q): read final ksum, emit denom[hh*4096+row] = sum_m P*ksum.
// ---------------------------------------------------------------------------
template<int MODE>
__launch_bounds__(256)
__global__ void feat_mfma(const unsigned short* __restrict__ A, int lda,
                          const unsigned short* __restrict__ pjB,
                          float* __restrict__ ksum,
                          unsigned short* __restrict__ P,
                          float* __restrict__ denom) {
  __shared__ char AsB[8192];     // A tile 64x64 bf16 (xor-swizzled rows)
  __shared__ char BsB[32768];    // B 256x64 bf16 swizzled; aliased as Ct later
  __shared__ float rmaxL[4][64];
  __shared__ float ssqL[64];
  __shared__ float dprt[4][64];
  const int hh = blockIdx.z;
  const int row0 = blockIdx.y * 64;
  const unsigned short* Ag = A + hh * 64;
  P += (long long)hh * (N_ * M_);
  const int tid = threadIdx.x;
  const int w = tid >> 6, lane = tid & 63;
  const int ln = lane & 15, hi = lane >> 4;
  const int rswz = (ln & 7) << 4;

  // stage A (2 passes) and B (8 passes): linear LDS dest, pre-swizzled source
#pragma unroll
  for (int p = 0; p < 2; ++p) {
    int id = p * 256 + tid;
    int r = id >> 3, c = id & 7;
    gload16(Ag + (long long)(row0 + r) * lda + ((c ^ (r & 7)) * 8), AsB + id * 16);
  }
#pragma unroll
  for (int p = 0; p < 8; ++p) {
    int id = p * 256 + tid;
    int r = id >> 3, c = id & 7;
    gload16(pjB + r * 64 + ((c ^ (r & 7)) * 8), BsB + id * 16);
  }
  __syncthreads();

  f32x4 acc[4][4];
#pragma unroll
  for (int i = 0; i < 4; ++i)
#pragma unroll
    for (int j = 0; j < 4; ++j) acc[i][j] = (f32x4){0.f, 0.f, 0.f, 0.f};
#pragma unroll
  for (int kc = 0; kc < 2; ++kc) {
    const int koff = (kc * 64 + hi * 16) ^ rswz;
    bf16x8 av[4], bv[4];
#pragma unroll
    for (int i = 0; i < 4; ++i)
      av[i] = *(bf16x8*)(AsB + (i * 16 + ln) * 128 + koff);
#pragma unroll
    for (int j = 0; j < 4; ++j)
      bv[j] = *(bf16x8*)(BsB + (w * 64 + j * 16 + ln) * 128 + koff);
#pragma unroll
    for (int i = 0; i < 4; ++i)
#pragma unroll
      for (int j = 0; j < 4; ++j)
        acc[i][j] = __builtin_amdgcn_mfma_f32_16x16x32_bf16(av[i], bv[j], acc[i][j], 0, 0, 0);
  }

  // wave-local rowmax over 64 cols -> rmaxL[w][row]
  float rmf[4][4];
#pragma unroll
  for (int i = 0; i < 4; ++i)
#pragma unroll
    for (int r = 0; r < 4; ++r) {
      float m = fmaxf(fmaxf(acc[i][0][r], acc[i][1][r]), fmaxf(acc[i][2][r], acc[i][3][r]));
      m = fmaxf(m, __shfl_xor(m, 1, 64));
      m = fmaxf(m, __shfl_xor(m, 2, 64));
      m = fmaxf(m, __shfl_xor(m, 4, 64));
      m = fmaxf(m, __shfl_xor(m, 8, 64));
      rmf[i][r] = m;
    }
  if (ln == 0) {
#pragma unroll
    for (int i = 0; i < 4; ++i)
#pragma unroll
      for (int r = 0; r < 4; ++r) rmaxL[w][i * 16 + hi * 4 + r] = rmf[i][r];
  }

  // ssq[row] = sum_k A[row][k]^2 from the A tile in LDS (4 threads/row)
  {
    int r = tid >> 2, q = tid & 3;
    int b0 = (r * 128 + q * 32) ^ ((r & 7) << 4);
    int b1 = (r * 128 + q * 32 + 16) ^ ((r & 7) << 4);
    u32x4 x0 = *(u32x4*)(AsB + b0);
    u32x4 x1 = *(u32x4*)(AsB + b1);
    float s = 0.f;
#pragma unroll
    for (int e = 0; e < 4; ++e) {
      float a0 = bf2f((unsigned short)(x0[e] & 0xffff)), a1 = bf2f((unsigned short)(x0[e] >> 16));
      float a2 = bf2f((unsigned short)(x1[e] & 0xffff)), a3 = bf2f((unsigned short)(x1[e] >> 16));
      s += a0 * a0 + a1 * a1 + a2 * a2 + a3 * a3;
    }
    s += __shfl_xor(s, 1, 64);
    s += __shfl_xor(s, 2, 64);
    if (q == 0) ssqL[r] = s;
  }
  __syncthreads();

  // epilogue: P values, ksum (MODE0) or denom partials (MODE1); Ct over BsB
  char* CtB = BsB;
  float cs[4] = {0.f, 0.f, 0.f, 0.f};
  float ks[4];
  if (MODE == 1) {
#pragma unroll
    for (int j = 0; j < 4; ++j) ks[j] = ksum[hh * 256 + w * 64 + j * 16 + ln];
  }
#pragma unroll
  for (int i = 0; i < 4; ++i)
#pragma unroll
    for (int r = 0; r < 4; ++r) {
      int row = i * 16 + hi * 4 + r;
      float base = 0.0625f * ssqL[row] +
                   fmaxf(fmaxf(rmaxL[0][row], rmaxL[1][row]), fmaxf(rmaxL[2][row], rmaxL[3][row]));
      float dp = 0.f;
#pragma unroll
      for (int j = 0; j < 4; ++j) {
        float v = 0.0625f * (expf(acc[i][j][r] - base) + 1e-4f);
        int col = w * 64 + j * 16 + ln;
        *(unsigned short*)(CtB + row * 512 + col * 2) = f2b(v);
        if (MODE == 0) cs[j] += v;
        else dp += v * ks[j];
      }
      if (MODE == 1) {
        dp += __shfl_xor(dp, 1, 64);
        dp += __shfl_xor(dp, 2, 64);
        dp += __shfl_xor(dp, 4, 64);
        dp += __shfl_xor(dp, 8, 64);
        if (ln == 0) dprt[w][row] = dp;
      }
    }
  if (MODE == 0) {
#pragma unroll
    for (int j = 0; j < 4; ++j) {
      cs[j] += __shfl_xor(cs[j], 16, 64);
      cs[j] += __shfl_xor(cs[j], 32, 64);
    }
    if (hi == 0) {
#pragma unroll
      for (int j = 0; j < 4; ++j)
        atomicAdd(&ksum[hh * 256 + w * 64 + j * 16 + ln], cs[j]);
    }
  }
  __syncthreads();

  // coalesced write-out of the 64x256 bf16 tile
#pragma unroll
  for (int p = 0; p < 8; ++p) {
    const int idx = p * 256 + tid;
    const int r = idx >> 5, seg = idx & 31;
    uint4 v = *(uint4*)(CtB + r * 512 + seg * 16);
    *(uint4*)(P + (long long)(row0 + r) * 256 + seg * 8) = v;
  }
  if (MODE == 1 && tid < 64)
    denom[hh * 4096 + row0 + tid] = dprt[0][tid] + dprt[1][tid] + dprt[2][tid] + dprt[3][tid];
}

// ctxT[hh][d][m] += sum_{n in split} Kp[hh][n][m] * V[n][hh*64+d]
__launch_bounds__(256)
__global__ void ctx_k(const unsigned short* __restrict__ Kp, const unsigned short* __restrict__ V,
                      float* __restrict__ ctxT) {
  constexpr int BK = 16;
  __shared__ float As[BK][64];
  __shared__ float Ws[BK][64];
  const int hh = blockIdx.z;
  const int m0 = blockIdx.x * 64;
  const int n0 = blockIdx.y * 256;
  const unsigned short* Kph = Kp + (long long)hh * N_ * M_;
  const unsigned short* Vh = V + hh * 64;
  const int tid = threadIdx.x;
  const int tx = tid % 16, ty = tid / 16;
  const int lr = tid / 16, lc = (tid % 16) * 4;
  float acc[4][4];
#pragma unroll
  for (int i = 0; i < 4; ++i)
#pragma unroll
    for (int j = 0; j < 4; ++j) acc[i][j] = 0.f;

  for (int k0 = n0; k0 < n0 + 256; k0 += BK) {
    ushort4 a4 = *(const ushort4*)&Kph[(long long)(k0 + lr) * M_ + m0 + lc];
    ushort4 w4 = *(const ushort4*)&Vh[(long long)(k0 + lr) * H_ + lc];
    As[lr][lc + 0] = bf2f(a4.x); As[lr][lc + 1] = bf2f(a4.y);
    As[lr][lc + 2] = bf2f(a4.z); As[lr][lc + 3] = bf2f(a4.w);
    Ws[lr][lc + 0] = bf2f(w4.x); Ws[lr][lc + 1] = bf2f(w4.y);
    Ws[lr][lc + 2] = bf2f(w4.z); Ws[lr][lc + 3] = bf2f(w4.w);
    __syncthreads();
#pragma unroll
    for (int kk = 0; kk < BK; ++kk) {
      float a[4], w[4];
#pragma unroll
      for (int i = 0; i < 4; ++i) a[i] = As[kk][ty * 4 + i];
#pragma unroll
      for (int j = 0; j < 4; ++j) w[j] = Ws[kk][tx * 4 + j];
#pragma unroll
      for (int i = 0; i < 4; ++i)
#pragma unroll
        for (int j = 0; j < 4; ++j) acc[i][j] += a[i] * w[j];
    }
    __syncthreads();
  }
#pragma unroll
  for (int i = 0; i < 4; ++i)
#pragma unroll
    for (int j = 0; j < 4; ++j)
      atomicAdd(&ctxT[((long long)hh * 64 + tx * 4 + j) * 256 + m0 + ty * 4 + i], acc[i][j]);
}

// ---------------------------------------------------------------------------
// attn_out[hh][n][d] = (Qp @ ctxT^T) / denom[n] via MFMA.
// Tile 128 rows x 64 cols, K=256, BK=64, 4 waves (wave w owns rows w*32..+31).
// A staged via global_load_lds; B (ctxT f32) converted to bf16 in LDS.
// ---------------------------------------------------------------------------
__launch_bounds__(256)
__global__ void ao_mfma(const unsigned short* __restrict__ A,
                        const float* __restrict__ ctxT,
                        const float* __restrict__ denom,
                        unsigned short* __restrict__ C) {
  __shared__ char AsB[16384];   // 128x64 bf16 swz; later Ct 128x64 bf16
  __shared__ char BsB[8192];    // 64x64 bf16 swz
  const int hh = blockIdx.z;
  A += (long long)hh * (N_ * M_);
  ctxT += (long long)hh * (64 * 256);
  C += (long long)hh * (N_ * HD_);
  const float* dnm = denom + hh * 4096;
  const int tid = threadIdx.x;
  const int row0 = blockIdx.y * 128;
  const int w = tid >> 6, lane = tid & 63;
  const int ln = lane & 15, hi = lane >> 4;
  const int rswz = (ln & 7) << 4;

  f32x4 acc[2][4];
#pragma unroll
  for (int i = 0; i < 2; ++i)
#pragma unroll
    for (int j = 0; j < 4; ++j) acc[i][j] = (f32x4){0.f, 0.f, 0.f, 0.f};

  for (int k0 = 0; k0 < 256; k0 += 64) {
#pragma unroll
    for (int p = 0; p < 4; ++p) {
      int id = p * 256 + tid;
      int r = id >> 3, c = id & 7;
      gload16(A + (long long)(row0 + r) * 256 + k0 + ((c ^ (r & 7)) * 8), AsB + id * 16);
    }
    {
      int d = tid >> 2, q = tid & 3;
      const float* src = ctxT + d * 256 + k0 + q * 16;
      unsigned short tmp[16];
#pragma unroll
      for (int e = 0; e < 16; ++e) tmp[e] = f2b(src[e]);
      int b0 = (d * 128 + q * 32) ^ ((d & 7) << 4);
      int b1 = (d * 128 + q * 32 + 16) ^ ((d & 7) << 4);
      *(uint4*)(BsB + b0) = *(uint4*)tmp;
      *(uint4*)(BsB + b1) = *(uint4*)(tmp + 8);
    }
    __syncthreads();
#pragma unroll
    for (int kc = 0; kc < 2; ++kc) {
      const int koff = (kc * 64 + hi * 16) ^ rswz;
      bf16x8 av[2], bv[4];
#pragma unroll
      for (int i = 0; i < 2; ++i)
        av[i] = *(bf16x8*)(AsB + (w * 32 + i * 16 + ln) * 128 + koff);
#pragma unroll
      for (int j = 0; j < 4; ++j)
        bv[j] = *(bf16x8*)(BsB + (j * 16 + ln) * 128 + koff);
#pragma unroll
      for (int i = 0; i < 2; ++i)
#pragma unroll
        for (int j = 0; j < 4; ++j)
          acc[i][j] = __builtin_amdgcn_mfma_f32_16x16x32_bf16(av[i], bv[j], acc[i][j], 0, 0, 0);
    }
    __syncthreads();
  }

  // epilogue: divide by denom, stage Ct (over AsB), coalesced store
  float inv[2][4];
#pragma unroll
  for (int i = 0; i < 2; ++i)
#pragma unroll
    for (int r = 0; r < 4; ++r)
      inv[i][r] = 1.0f / dnm[row0 + w * 32 + i * 16 + hi * 4 + r];
  char* CtB = AsB;
#pragma unroll
  for (int i = 0; i < 2; ++i)
#pragma unroll
    for (int r = 0; r < 4; ++r) {
      int row = w * 32 + i * 16 + hi * 4 + r;
#pragma unroll
      for (int j = 0; j < 4; ++j) {
        int col = j * 16 + ln;
        *(unsigned short*)(CtB + row * 128 + col * 2) = f2b(acc[i][j][r] * inv[i][r]);
      }
    }
  __syncthreads();
#pragma unroll
  for (int p = 0; p < 4; ++p) {
    const int idx = p * 256 + tid;
    const int r = idx >> 3, seg = idx & 7;
    uint4 v = *(uint4*)(CtB + r * 128 + seg * 16);
    *(uint4*)(C + (long long)(row0 + r) * 64 + seg * 8) = v;
  }
}

// weight transpose+convert: out[n*K+k] = bf16(in[k*N+n])
__launch_bounds__(256)
__global__ void wt_cvt(const float* __restrict__ in, unsigned short* __restrict__ out,
                       int K, int N) {
  __shared__ float t[32][33];
  int k0 = blockIdx.y * 32, n0 = blockIdx.x * 32;
  int tx = threadIdx.x & 31, ty = threadIdx.x >> 5;
  for (int r = ty; r < 32; r += 8) t[r][tx] = in[(long long)(k0 + r) * N + n0 + tx];
  __syncthreads();
  for (int r = ty; r < 32; r += 8) out[(long long)(n0 + r) * K + k0 + tx] = f2b(t[tx][r]);
}

// pjB[m][d] = bf16(dn * proj[m][d])   (no transpose)
__launch_bounds__(256)
__global__ void projB_cvt(const float* __restrict__ proj, unsigned short* __restrict__ out) {
  int i = blockIdx.x * 256 + threadIdx.x;
  out[i] = f2b(0.35355339059327373f * proj[i]);
}

__launch_bounds__(256)
__global__ void cvt_bf16(const float* __restrict__ in, unsigned short* __restrict__ out,
                         long long n) {
  long long stride = (long long)gridDim.x * 1024;
  for (long long i = ((long long)blockIdx.x * 256 + threadIdx.x) * 4; i < n; i += stride) {
    float4 v = *(const float4*)&in[i];
    ushort4 o;
    o.x = f2b(v.x); o.y = f2b(v.y); o.z = f2b(v.z); o.w = f2b(v.w);
    *(ushort4*)&out[i] = o;
  }
}

// out = LN(res + po) * g + beta, rows of 1024.
__launch_bounds__(256)
__global__ void ln_k(const float* __restrict__ resf, const unsigned short* __restrict__ resb,
                     const unsigned short* __restrict__ po,
                     const float* __restrict__ g, const float* __restrict__ be,
                     float* __restrict__ outf, unsigned short* __restrict__ outb) {
  long long row = blockIdx.x;
  int t = threadIdx.x;
  float x0, x1, x2, x3;
  if (resf) {
    float4 va = ((const float4*)(resf + row * H_))[t];
    x0 = va.x; x1 = va.y; x2 = va.z; x3 = va.w;
  } else {
    ushort4 va = ((const ushort4*)(resb + row * H_))[t];
    x0 = bf2f(va.x); x1 = bf2f(va.y); x2 = bf2f(va.z); x3 = bf2f(va.w);
  }
  {
    ushort4 vp = ((const ushort4*)(po + row * H_))[t];
    x0 += bf2f(vp.x); x1 += bf2f(vp.y); x2 += bf2f(vp.z); x3 += bf2f(vp.w);
  }
  float s = x0 + x1 + x2 + x3;
  float q = x0 * x0 + x1 * x1 + x2 * x2 + x3 * x3;
#pragma unroll
  for (int m = 1; m < 64; m <<= 1) { s += __shfl_xor(s, m, 64); q += __shfl_xor(q, m, 64); }
  __shared__ float ssum[4], ssq[4];
  int w = t >> 6, lane = t & 63;
  if (lane == 0) { ssum[w] = s; ssq[w] = q; }
  __syncthreads();
  s = ssum[0] + ssum[1] + ssum[2] + ssum[3];
  q = ssq[0] + ssq[1] + ssq[2] + ssq[3];
  float mean = s * (1.0f / H_);
  float var = q * (1.0f / H_) - mean * mean;
  float rstd = rsqrtf(var + 1e-5f);
  float4 vg = ((const float4*)g)[t];
  float4 vbe = ((const float4*)be)[t];
  float o0 = (x0 - mean) * rstd * vg.x + vbe.x;
  float o1 = (x1 - mean) * rstd * vg.y + vbe.y;
  float o2 = (x2 - mean) * rstd * vg.z + vbe.z;
  float o3 = (x3 - mean) * rstd * vg.w + vbe.w;
  if (outf) {
    float4 o; o.x = o0; o.y = o1; o.z = o2; o.w = o3;
    ((float4*)(outf + row * H_))[t] = o;
  }
  if (outb) {
    ushort4 ob; ob.x = f2b(o0); ob.y = f2b(o1); ob.z = f2b(o2); ob.w = f2b(o3);
    ((ushort4*)(outb + row * H_))[t] = ob;
  }
}

extern "C" void kernel_launch(void* const* d_in, const int* in_sizes, int n_in,
                              void* d_out, int out_size, void* d_ws, size_t ws_size,
                              hipStream_t stream) {
  (void)in_sizes; (void)n_in; (void)out_size; (void)ws_size;
  const float* x      = (const float*)d_in[0];
  const float* enc    = (const float*)d_in[1];
  const float* sa_w[4] = {(const float*)d_in[2], (const float*)d_in[4], (const float*)d_in[6], (const float*)d_in[8]};
  const float* sa_b[4] = {(const float*)d_in[3], (const float*)d_in[5], (const float*)d_in[7], (const float*)d_in[9]};
  const float* sa_pj  = (const float*)d_in[10];
  const float* ca_w[4] = {(const float*)d_in[11], (const float*)d_in[13], (const float*)d_in[15], (const float*)d_in[17]};
  const float* ca_b[4] = {(const float*)d_in[12], (const float*)d_in[14], (const float*)d_in[16], (const float*)d_in[18]};
  const float* ca_pj  = (const float*)d_in[19];
  const float* ff_w1  = (const float*)d_in[20];
  const float* ff_b1  = (const float*)d_in[21];
  const float* ff_w2  = (const float*)d_in[22];
  const float* ff_b2  = (const float*)d_in[23];
  const float* ln1_g  = (const float*)d_in[24];
  const float* ln1_b  = (const float*)d_in[25];
  const float* ln2_g  = (const float*)d_in[26];
  const float* ln2_b  = (const float*)d_in[27];
  const float* ln3_g  = (const float*)d_in[28];
  const float* ln3_b  = (const float*)d_in[29];

  float* ws = (float*)d_ws;
  // Offsets in f32 elements. Peak footprint ~222.6 MB (<235 proven good).
  unsigned short* XB = (unsigned short*)(ws);                 // [16384][1024] bf16
  unsigned short* EB = (unsigned short*)(ws + 8388608LL);     // enc bf16 / AO / ffT
  unsigned short* Qb = (unsigned short*)(ws + 16777216LL);
  unsigned short* Kb = (unsigned short*)(ws + 25165824LL);
  unsigned short* Vb = (unsigned short*)(ws + 33554432LL);
  unsigned short* Pq = (unsigned short*)(ws + 41943040LL);    // [8][4096][256] bf16
  unsigned short* Pk = (unsigned short*)(ws + 46137344LL);
  unsigned short* PO = Pq;                                     // [16384][1024] bf16 (Pq+Pk)
  unsigned short* MIDB = Pq;                                   // FFN mid chunk
  unsigned short* FO = (unsigned short*)(ws + 50331648LL);
  unsigned short* WTph = (unsigned short*)(ws + 52428800LL);  // 4 x [1024][1024] bf16
  unsigned short* pjB = (unsigned short*)(ws + 54525952LL);   // 2 x [256][64] bf16
  float* ctxA  = ws + 54542336LL;                              // 8 slots x [8][64][256] f32
  float* ksumA = ws + 55590912LL;                              // 8 slots x [8][256] f32
  float* denomB = ws + 55607296LL;                             // [8][4096] f32

  unsigned short* ff1T = EB;
  unsigned short* ff2T = EB + 4194304LL;
  unsigned short* pjB_sa = pjB, *pjB_ca = pjB + 16384;

  dim3 blk(256, 1, 1);
  const long long sB = (long long)N_ * H_;
  const long long sAO = (long long)N_ * HD_;

  projB_cvt<<<dim3(64), blk, 0, stream>>>(sa_pj, pjB_sa);
  projB_cvt<<<dim3(64), blk, 0, stream>>>(ca_pj, pjB_ca);
  cvt_bf16<<<dim3(2048), blk, 0, stream>>>(x, XB, 16777216LL);

  auto attn = [&](const unsigned short* qA, const unsigned short* kvA,
                  const float* const* wsrc, const float* const* bs,
                  const unsigned short* pj) {
    for (int i = 0; i < 4; ++i)
      wt_cvt<<<dim3(32, 32), blk, 0, stream>>>(wsrc[i], WTph + (long long)i * 1048576, H_, H_);
    gemm_mfma<0><<<dim3(8,128), blk, 0, stream>>>(qA, H_, WTph, bs[0], Qb, H_, H_);
    gemm_mfma<0><<<dim3(8,128), blk, 0, stream>>>(kvA, H_, WTph + 1048576, bs[1], Kb, H_, H_);
    gemm_mfma<0><<<dim3(8,128), blk, 0, stream>>>(kvA, H_, WTph + 2097152, bs[2], Vb, H_, H_);
    // zero all ctx/ksum slots for this phase (adjacent -> one memset)
    hipMemsetAsync(ctxA, 0, (1048576LL + 16384LL) * sizeof(float), stream);
    for (int b = 0; b < B_; ++b) {
      for (int g = 0; g < 2; ++g) {
        const int idx = b * 2 + g;
        const long long go = (long long)b * sB + g * 512;
        float* ksum = ksumA + (long long)idx * 2048;
        float* ctxT = ctxA + (long long)idx * 131072;
        feat_mfma<0><<<dim3(1,64,8), blk, 0, stream>>>(Kb + go, H_, pj, ksum, Pk, nullptr);
        feat_mfma<1><<<dim3(1,64,8), blk, 0, stream>>>(Qb + go, H_, pj, ksum, Pq, denomB);
        ctx_k<<<dim3(4,16,8), blk, 0, stream>>>(Pk, Vb + go, ctxT);
        ao_mfma<<<dim3(1,32,8), blk, 0, stream>>>(Pq, ctxT, denomB,
            EB + (long long)b * NH_ * sAO + (long long)g * 8 * sAO);
      }
    }
    gemm_mfma<0><<<dim3(8,128), blk, 0, stream>>>(EB, H_, WTph + 3145728, bs[3], PO, H_, H_);
  };

  // self-attention; ln1 reads pristine f32 x as residual; h1 bf16 -> XB
  attn(XB, XB, sa_w, sa_b, pjB_sa);
  ln_k<<<dim3(16384), blk, 0, stream>>>(x, nullptr, PO, ln1_g, ln1_b, nullptr, XB);

  // cross-attention; residual h1 bf16 (XB); h2 bf16 -> XB in place
  cvt_bf16<<<dim3(2048), blk, 0, stream>>>(enc, EB, 16777216LL);
  attn(XB, EB, ca_w, ca_b, pjB_ca);
  ln_k<<<dim3(16384), blk, 0, stream>>>(nullptr, XB, PO, ln2_g, ln2_b, nullptr, XB);

  // FFN
  wt_cvt<<<dim3(128, 32), blk, 0, stream>>>(ff_w1, ff1T, H_, 4096);
  wt_cvt<<<dim3(32, 128), blk, 0, stream>>>(ff_w2, ff2T, 4096, H_);
  for (int c = 0; c < 4; ++c) {
    const long long co = (long long)c * 4096 * H_;
    gemm_mfma<1><<<dim3(32,32), blk, 0, stream>>>(XB + co, H_, ff1T, ff_b1, MIDB, 4096, H_);
    gemm_mfma<0><<<dim3(8,32), blk, 0, stream>>>(MIDB, 4096, ff2T, ff_b2, FO, H_, 4096);
    ln_k<<<dim3(4096), blk, 0, stream>>>(nullptr, XB + co, FO, ln3_g, ln3_b,
                                         (float*)d_out + co, nullptr);
  }
}

// Round 10
// 2343.717 us; speedup vs baseline: 6.8206x; 1.0586x over previous
//
#include <hip/hip_runtime.h>
#include <hip/hip_bf16.h>

#define B_ 4
#define N_ 4096
#define H_ 1024
#define NH_ 16
#define HD_ 64
#define M_ 256

typedef __attribute__((ext_vector_type(8))) __bf16 bf16x8;
typedef __attribute__((ext_vector_type(4))) float f32x4;
typedef __attribute__((ext_vector_type(4))) unsigned int u32x4;

__device__ __forceinline__ float bf2f(unsigned short u) {
  union { unsigned int i; float f; } x; x.i = ((unsigned int)u) << 16; return x.f;
}
__device__ __forceinline__ unsigned short f2b(float f) {
  __hip_bfloat16 h = __float2bfloat16(f);
  return *(unsigned short*)&h;
}
__device__ __forceinline__ float gelu_f(float x) {
  const float c = 0.7978845608028654f;
  float t = tanhf(c * (x + 0.044715f * x * x * x));
  return 0.5f * x * (1.0f + t);
}

typedef __attribute__((address_space(3))) unsigned int as3_uint;
typedef const __attribute__((address_space(1))) unsigned int as1_uint;
__device__ __forceinline__ void gload16(const void* g, void* l) {
  __builtin_amdgcn_global_load_lds((as1_uint*)g, (as3_uint*)l, 16, 0, 0);
}

// ---------------------------------------------------------------------------
// Dense bf16 MFMA GEMM: C[M,N] = act(A @ BT^T + bias); C bf16.
// Tile 128x128, BK=64, 4 waves. DOUBLE-BUFFERED global_load_lds staging
// (T3 minimum 2-phase): issue next tile's loads before computing current;
// one barrier per K-step drains loads that had the MFMA phase to land.
// XCD-aware bijective block swizzle; LDS-staged nontemporal epilogue.
// ---------------------------------------------------------------------------
template<int ACT>
__launch_bounds__(256)
__global__ void gemm_mfma(const unsigned short* __restrict__ A, int lda,
                          const unsigned short* __restrict__ BT,
                          const float* __restrict__ bias,
                          unsigned short* __restrict__ C, int ldc, int K) {
  __shared__ __align__(16) char LDS[65536];   // 2 x (A 16K | B 16K)

  const int tid = threadIdx.x;
  const int nwg = gridDim.x * gridDim.y;
  const int lin = blockIdx.y * gridDim.x + blockIdx.x;
  const int mm = (lin & 7) * (nwg >> 3) + (lin >> 3);
  const int bx = mm % gridDim.x, by = mm / gridDim.x;
  const int row0 = by * 128;
  const int col0 = bx * 128;

  const int w = tid >> 6, lane = tid & 63;
  const int wm = w >> 1, wn = w & 1;
  const int ln = lane & 15, hi = lane >> 4;
  const int rswz = (ln & 7) << 4;

  const int srow = w * 8 + (lane >> 3);
  const int schunk = ((lane & 7) ^ (lane >> 3)) * 8;
  const unsigned short* Ag = A + (long long)(row0 + srow) * lda + schunk;
  const unsigned short* Bg = BT + (long long)(col0 + srow) * K + schunk;
  const int ldsw = w * 1024;

  f32x4 acc[4][4];
#pragma unroll
  for (int i = 0; i < 4; ++i)
#pragma unroll
    for (int j = 0; j < 4; ++j) acc[i][j] = (f32x4){0.f, 0.f, 0.f, 0.f};

  auto STAGE = [&](int p, int k0) {
    char* dst = LDS + p * 32768 + ldsw;
#pragma unroll
    for (int i = 0; i < 4; ++i) {
      gload16(Ag + (long long)i * 32 * lda + k0, dst + i * 4096);
      gload16(Bg + (long long)i * 32 * K + k0, dst + 16384 + i * 4096);
    }
  };
  auto COMPUTE = [&](int p) {
    char* AsB = LDS + p * 32768;
    char* BsB = AsB + 16384;
#pragma unroll
    for (int kc = 0; kc < 2; ++kc) {
      const int koff = (kc * 64 + hi * 16) ^ rswz;
      bf16x8 av[4], bv[4];
#pragma unroll
      for (int i = 0; i < 4; ++i)
        av[i] = *(bf16x8*)(AsB + (wm * 64 + i * 16 + ln) * 128 + koff);
#pragma unroll
      for (int j = 0; j < 4; ++j)
        bv[j] = *(bf16x8*)(BsB + (wn * 64 + j * 16 + ln) * 128 + koff);
#pragma unroll
      for (int i = 0; i < 4; ++i)
#pragma unroll
        for (int j = 0; j < 4; ++j)
          acc[i][j] = __builtin_amdgcn_mfma_f32_16x16x32_bf16(av[i], bv[j], acc[i][j], 0, 0, 0);
    }
  };

  STAGE(0, 0);
  __syncthreads();
  int cur = 0;
  for (int k0 = 64; k0 < K; k0 += 64) {
    STAGE(cur ^ 1, k0);     // issue next tile first (latency hides under MFMA)
    COMPUTE(cur);
    __syncthreads();
    cur ^= 1;
  }
  COMPUTE(cur);
  __syncthreads();

  // ---- coalesced epilogue: stage bf16 C tile in LDS (row-XOR swizzled) ----
  char* SB = LDS;
#pragma unroll
  for (int j = 0; j < 4; ++j) {
    const int lcol = wn * 64 + j * 16 + ln;
    const float bj = bias ? bias[col0 + lcol] : 0.0f;
#pragma unroll
    for (int i = 0; i < 4; ++i) {
      const int rb_ = wm * 64 + i * 16 + hi * 4;
#pragma unroll
      for (int r = 0; r < 4; ++r) {
        float v = acc[i][j][r] + bj;
        if (ACT == 1) v = gelu_f(v);
        const int row = rb_ + r;
        *(unsigned short*)(SB + ((row * 256 + lcol * 2) ^ ((row & 7) << 4))) = f2b(v);
      }
    }
  }
  __syncthreads();
#pragma unroll
  for (int p = 0; p < 8; ++p) {
    const int idx = p * 256 + tid;
    const int row = idx >> 4, seg = idx & 15;
    u32x4 v = *(u32x4*)(SB + ((row * 256 + seg * 16) ^ ((row & 7) << 4)));
    __builtin_nontemporal_store(v, (u32x4*)(C + (long long)(row0 + row) * ldc + col0 + seg * 8));
  }
}

// ---------------------------------------------------------------------------
// FAVOR+ feature GEMM via MFMA (verified round 9). Tile 64x256, K=64, 4 waves.
// MODE 0 (K): atomic ksum. MODE 1 (Q): read ksum, emit denom.
// ---------------------------------------------------------------------------
template<int MODE>
__launch_bounds__(256)
__global__ void feat_mfma(const unsigned short* __restrict__ A, int lda,
                          const unsigned short* __restrict__ pjB,
                          float* __restrict__ ksum,
                          unsigned short* __restrict__ P,
                          float* __restrict__ denom) {
  __shared__ char AsB[8192];
  __shared__ char BsB[32768];
  __shared__ float rmaxL[4][64];
  __shared__ float ssqL[64];
  __shared__ float dprt[4][64];
  const int hh = blockIdx.z;
  const int row0 = blockIdx.y * 64;
  const unsigned short* Ag = A + hh * 64;
  P += (long long)hh * (N_ * M_);
  const int tid = threadIdx.x;
  const int w = tid >> 6, lane = tid & 63;
  const int ln = lane & 15, hi = lane >> 4;
  const int rswz = (ln & 7) << 4;

#pragma unroll
  for (int p = 0; p < 2; ++p) {
    int id = p * 256 + tid;
    int r = id >> 3, c = id & 7;
    gload16(Ag + (long long)(row0 + r) * lda + ((c ^ (r & 7)) * 8), AsB + id * 16);
  }
#pragma unroll
  for (int p = 0; p < 8; ++p) {
    int id = p * 256 + tid;
    int r = id >> 3, c = id & 7;
    gload16(pjB + r * 64 + ((c ^ (r & 7)) * 8), BsB + id * 16);
  }
  __syncthreads();

  f32x4 acc[4][4];
#pragma unroll
  for (int i = 0; i < 4; ++i)
#pragma unroll
    for (int j = 0; j < 4; ++j) acc[i][j] = (f32x4){0.f, 0.f, 0.f, 0.f};
#pragma unroll
  for (int kc = 0; kc < 2; ++kc) {
    const int koff = (kc * 64 + hi * 16) ^ rswz;
    bf16x8 av[4], bv[4];
#pragma unroll
    for (int i = 0; i < 4; ++i)
      av[i] = *(bf16x8*)(AsB + (i * 16 + ln) * 128 + koff);
#pragma unroll
    for (int j = 0; j < 4; ++j)
      bv[j] = *(bf16x8*)(BsB + (w * 64 + j * 16 + ln) * 128 + koff);
#pragma unroll
    for (int i = 0; i < 4; ++i)
#pragma unroll
      for (int j = 0; j < 4; ++j)
        acc[i][j] = __builtin_amdgcn_mfma_f32_16x16x32_bf16(av[i], bv[j], acc[i][j], 0, 0, 0);
  }

  float rmf[4][4];
#pragma unroll
  for (int i = 0; i < 4; ++i)
#pragma unroll
    for (int r = 0; r < 4; ++r) {
      float m = fmaxf(fmaxf(acc[i][0][r], acc[i][1][r]), fmaxf(acc[i][2][r], acc[i][3][r]));
      m = fmaxf(m, __shfl_xor(m, 1, 64));
      m = fmaxf(m, __shfl_xor(m, 2, 64));
      m = fmaxf(m, __shfl_xor(m, 4, 64));
      m = fmaxf(m, __shfl_xor(m, 8, 64));
      rmf[i][r] = m;
    }
  if (ln == 0) {
#pragma unroll
    for (int i = 0; i < 4; ++i)
#pragma unroll
      for (int r = 0; r < 4; ++r) rmaxL[w][i * 16 + hi * 4 + r] = rmf[i][r];
  }

  {
    int r = tid >> 2, q = tid & 3;
    int b0 = (r * 128 + q * 32) ^ ((r & 7) << 4);
    int b1 = (r * 128 + q * 32 + 16) ^ ((r & 7) << 4);
    u32x4 x0 = *(u32x4*)(AsB + b0);
    u32x4 x1 = *(u32x4*)(AsB + b1);
    float s = 0.f;
#pragma unroll
    for (int e = 0; e < 4; ++e) {
      float a0 = bf2f((unsigned short)(x0[e] & 0xffff)), a1 = bf2f((unsigned short)(x0[e] >> 16));
      float a2 = bf2f((unsigned short)(x1[e] & 0xffff)), a3 = bf2f((unsigned short)(x1[e] >> 16));
      s += a0 * a0 + a1 * a1 + a2 * a2 + a3 * a3;
    }
    s += __shfl_xor(s, 1, 64);
    s += __shfl_xor(s, 2, 64);
    if (q == 0) ssqL[r] = s;
  }
  __syncthreads();

  char* CtB = BsB;
  float cs[4] = {0.f, 0.f, 0.f, 0.f};
  float ks[4];
  if (MODE == 1) {
#pragma unroll
    for (int j = 0; j < 4; ++j) ks[j] = ksum[hh * 256 + w * 64 + j * 16 + ln];
  }
#pragma unroll
  for (int i = 0; i < 4; ++i)
#pragma unroll
    for (int r = 0; r < 4; ++r) {
      int row = i * 16 + hi * 4 + r;
      float base = 0.0625f * ssqL[row] +
                   fmaxf(fmaxf(rmaxL[0][row], rmaxL[1][row]), fmaxf(rmaxL[2][row], rmaxL[3][row]));
      float dp = 0.f;
#pragma unroll
      for (int j = 0; j < 4; ++j) {
        float v = 0.0625f * (expf(acc[i][j][r] - base) + 1e-4f);
        int col = w * 64 + j * 16 + ln;
        *(unsigned short*)(CtB + row * 512 + col * 2) = f2b(v);
        if (MODE == 0) cs[j] += v;
        else dp += v * ks[j];
      }
      if (MODE == 1) {
        dp += __shfl_xor(dp, 1, 64);
        dp += __shfl_xor(dp, 2, 64);
        dp += __shfl_xor(dp, 4, 64);
        dp += __shfl_xor(dp, 8, 64);
        if (ln == 0) dprt[w][row] = dp;
      }
    }
  if (MODE == 0) {
#pragma unroll
    for (int j = 0; j < 4; ++j) {
      cs[j] += __shfl_xor(cs[j], 16, 64);
      cs[j] += __shfl_xor(cs[j], 32, 64);
    }
    if (hi == 0) {
#pragma unroll
      for (int j = 0; j < 4; ++j)
        atomicAdd(&ksum[hh * 256 + w * 64 + j * 16 + ln], cs[j]);
    }
  }
  __syncthreads();

#pragma unroll
  for (int p = 0; p < 8; ++p) {
    const int idx = p * 256 + tid;
    const int r = idx >> 5, seg = idx & 31;
    uint4 v = *(uint4*)(CtB + r * 512 + seg * 16);
    *(uint4*)(P + (long long)(row0 + r) * 256 + seg * 8) = v;
  }
  if (MODE == 1 && tid < 64)
    denom[hh * 4096 + row0 + tid] = dprt[0][tid] + dprt[1][tid] + dprt[2][tid] + dprt[3][tid];
}

// ctxT[hh][d][m] += sum_{n in split} Kp[hh][n][m] * V[n][hh*64+d] ; V row stride ldv
__launch_bounds__(256)
__global__ void ctx_k(const unsigned short* __restrict__ Kp, const unsigned short* __restrict__ V,
                      int ldv, float* __restrict__ ctxT) {
  constexpr int BK = 16;
  __shared__ float As[BK][64];
  __shared__ float Ws[BK][64];
  const int hh = blockIdx.z;
  const int m0 = blockIdx.x * 64;
  const int n0 = blockIdx.y * 256;
  const unsigned short* Kph = Kp + (long long)hh * N_ * M_;
  const unsigned short* Vh = V + hh * 64;
  const int tid = threadIdx.x;
  const int tx = tid % 16, ty = tid / 16;
  const int lr = tid / 16, lc = (tid % 16) * 4;
  float acc[4][4];
#pragma unroll
  for (int i = 0; i < 4; ++i)
#pragma unroll
    for (int j = 0; j < 4; ++j) acc[i][j] = 0.f;

  for (int k0 = n0; k0 < n0 + 256; k0 += BK) {
    ushort4 a4 = *(const ushort4*)&Kph[(long long)(k0 + lr) * M_ + m0 + lc];
    ushort4 w4 = *(const ushort4*)&Vh[(long long)(k0 + lr) * ldv + lc];
    As[lr][lc + 0] = bf2f(a4.x); As[lr][lc + 1] = bf2f(a4.y);
    As[lr][lc + 2] = bf2f(a4.z); As[lr][lc + 3] = bf2f(a4.w);
    Ws[lr][lc + 0] = bf2f(w4.x); Ws[lr][lc + 1] = bf2f(w4.y);
    Ws[lr][lc + 2] = bf2f(w4.z); Ws[lr][lc + 3] = bf2f(w4.w);
    __syncthreads();
#pragma unroll
    for (int kk = 0; kk < BK; ++kk) {
      float a[4], w[4];
#pragma unroll
      for (int i = 0; i < 4; ++i) a[i] = As[kk][ty * 4 + i];
#pragma unroll
      for (int j = 0; j < 4; ++j) w[j] = Ws[kk][tx * 4 + j];
#pragma unroll
      for (int i = 0; i < 4; ++i)
#pragma unroll
        for (int j = 0; j < 4; ++j) acc[i][j] += a[i] * w[j];
    }
    __syncthreads();
  }
#pragma unroll
  for (int i = 0; i < 4; ++i)
#pragma unroll
    for (int j = 0; j < 4; ++j)
      atomicAdd(&ctxT[((long long)hh * 64 + tx * 4 + j) * 256 + m0 + ty * 4 + i], acc[i][j]);
}

// attn_out[hh][n][d] = (Qp @ ctxT^T) / denom[n] via MFMA (verified round 9).
__launch_bounds__(256)
__global__ void ao_mfma(const unsigned short* __restrict__ A,
                        const float* __restrict__ ctxT,
                        const float* __restrict__ denom,
                        unsigned short* __restrict__ C) {
  __shared__ char AsB[16384];
  __shared__ char BsB[8192];
  const int hh = blockIdx.z;
  A += (long long)hh * (N_ * M_);
  ctxT += (long long)hh * (64 * 256);
  C += (long long)hh * (N_ * HD_);
  const float* dnm = denom + hh * 4096;
  const int tid = threadIdx.x;
  const int row0 = blockIdx.y * 128;
  const int w = tid >> 6, lane = tid & 63;
  const int ln = lane & 15, hi = lane >> 4;
  const int rswz = (ln & 7) << 4;

  f32x4 acc[2][4];
#pragma unroll
  for (int i = 0; i < 2; ++i)
#pragma unroll
    for (int j = 0; j < 4; ++j) acc[i][j] = (f32x4){0.f, 0.f, 0.f, 0.f};

  for (int k0 = 0; k0 < 256; k0 += 64) {
#pragma unroll
    for (int p = 0; p < 4; ++p) {
      int id = p * 256 + tid;
      int r = id >> 3, c = id & 7;
      gload16(A + (long long)(row0 + r) * 256 + k0 + ((c ^ (r & 7)) * 8), AsB + id * 16);
    }
    {
      int d = tid >> 2, q = tid & 3;
      const float* src = ctxT + d * 256 + k0 + q * 16;
      unsigned short tmp[16];
#pragma unroll
      for (int e = 0; e < 16; ++e) tmp[e] = f2b(src[e]);
      int b0 = (d * 128 + q * 32) ^ ((d & 7) << 4);
      int b1 = (d * 128 + q * 32 + 16) ^ ((d & 7) << 4);
      *(uint4*)(BsB + b0) = *(uint4*)tmp;
      *(uint4*)(BsB + b1) = *(uint4*)(tmp + 8);
    }
    __syncthreads();
#pragma unroll
    for (int kc = 0; kc < 2; ++kc) {
      const int koff = (kc * 64 + hi * 16) ^ rswz;
      bf16x8 av[2], bv[4];
#pragma unroll
      for (int i = 0; i < 2; ++i)
        av[i] = *(bf16x8*)(AsB + (w * 32 + i * 16 + ln) * 128 + koff);
#pragma unroll
      for (int j = 0; j < 4; ++j)
        bv[j] = *(bf16x8*)(BsB + (j * 16 + ln) * 128 + koff);
#pragma unroll
      for (int i = 0; i < 2; ++i)
#pragma unroll
        for (int j = 0; j < 4; ++j)
          acc[i][j] = __builtin_amdgcn_mfma_f32_16x16x32_bf16(av[i], bv[j], acc[i][j], 0, 0, 0);
    }
    __syncthreads();
  }

  float inv[2][4];
#pragma unroll
  for (int i = 0; i < 2; ++i)
#pragma unroll
    for (int r = 0; r < 4; ++r)
      inv[i][r] = 1.0f / dnm[row0 + w * 32 + i * 16 + hi * 4 + r];
  char* CtB = AsB;
#pragma unroll
  for (int i = 0; i < 2; ++i)
#pragma unroll
    for (int r = 0; r < 4; ++r) {
      int row = w * 32 + i * 16 + hi * 4 + r;
#pragma unroll
      for (int j = 0; j < 4; ++j) {
        int col = j * 16 + ln;
        *(unsigned short*)(CtB + row * 128 + col * 2) = f2b(acc[i][j][r] * inv[i][r]);
      }
    }
  __syncthreads();
#pragma unroll
  for (int p = 0; p < 4; ++p) {
    const int idx = p * 256 + tid;
    const int r = idx >> 3, seg = idx & 7;
    uint4 v = *(uint4*)(CtB + r * 128 + seg * 16);
    *(uint4*)(C + (long long)(row0 + r) * 64 + seg * 8) = v;
  }
}

// weight transpose+convert: out[n*K+k] = bf16(in[k*N+n])
__launch_bounds__(256)
__global__ void wt_cvt(const float* __restrict__ in, unsigned short* __restrict__ out,
                       int K, int N) {
  __shared__ float t[32][33];
  int k0 = blockIdx.y * 32, n0 = blockIdx.x * 32;
  int tx = threadIdx.x & 31, ty = threadIdx.x >> 5;
  for (int r = ty; r < 32; r += 8) t[r][tx] = in[(long long)(k0 + r) * N + n0 + tx];
  __syncthreads();
  for (int r = ty; r < 32; r += 8) out[(long long)(n0 + r) * K + k0 + tx] = f2b(t[tx][r]);
}

// pjB[m][d] = bf16(dn * proj[m][d])
__launch_bounds__(256)
__global__ void projB_cvt(const float* __restrict__ proj, unsigned short* __restrict__ out) {
  int i = blockIdx.x * 256 + threadIdx.x;
  out[i] = f2b(0.35355339059327373f * proj[i]);
}

// bias concat: out[0..1023]=b0, [1024..2047]=b1, [2048..3071]=b2 (b2 may be null)
__launch_bounds__(256)
__global__ void bias_cat(const float* __restrict__ b0, const float* __restrict__ b1,
                         const float* __restrict__ b2, float* __restrict__ out) {
  int i = blockIdx.x * 256 + threadIdx.x;
  float v;
  if (i < 1024) v = b0[i];
  else if (i < 2048) v = b1[i - 1024];
  else v = b2[i - 2048];
  out[i] = v;
}

__launch_bounds__(256)
__global__ void cvt_bf16(const float* __restrict__ in, unsigned short* __restrict__ out,
                         long long n) {
  long long stride = (long long)gridDim.x * 1024;
  for (long long i = ((long long)blockIdx.x * 256 + threadIdx.x) * 4; i < n; i += stride) {
    float4 v = *(const float4*)&in[i];
    ushort4 o;
    o.x = f2b(v.x); o.y = f2b(v.y); o.z = f2b(v.z); o.w = f2b(v.w);
    *(ushort4*)&out[i] = o;
  }
}

// out = LN(res + po) * g + beta, rows of 1024.
__launch_bounds__(256)
__global__ void ln_k(const float* __restrict__ resf, const unsigned short* __restrict__ resb,
                     const unsigned short* __restrict__ po,
                     const float* __restrict__ g, const float* __restrict__ be,
                     float* __restrict__ outf, unsigned short* __restrict__ outb) {
  long long row = blockIdx.x;
  int t = threadIdx.x;
  float x0, x1, x2, x3;
  if (resf) {
    float4 va = ((const float4*)(resf + row * H_))[t];
    x0 = va.x; x1 = va.y; x2 = va.z; x3 = va.w;
  } else {
    ushort4 va = ((const ushort4*)(resb + row * H_))[t];
    x0 = bf2f(va.x); x1 = bf2f(va.y); x2 = bf2f(va.z); x3 = bf2f(va.w);
  }
  {
    ushort4 vp = ((const ushort4*)(po + row * H_))[t];
    x0 += bf2f(vp.x); x1 += bf2f(vp.y); x2 += bf2f(vp.z); x3 += bf2f(vp.w);
  }
  float s = x0 + x1 + x2 + x3;
  float q = x0 * x0 + x1 * x1 + x2 * x2 + x3 * x3;
#pragma unroll
  for (int m = 1; m < 64; m <<= 1) { s += __shfl_xor(s, m, 64); q += __shfl_xor(q, m, 64); }
  __shared__ float ssum[4], ssq[4];
  int w = t >> 6, lane = t & 63;
  if (lane == 0) { ssum[w] = s; ssq[w] = q; }
  __syncthreads();
  s = ssum[0] + ssum[1] + ssum[2] + ssum[3];
  q = ssq[0] + ssq[1] + ssq[2] + ssq[3];
  float mean = s * (1.0f / H_);
  float var = q * (1.0f / H_) - mean * mean;
  float rstd = rsqrtf(var + 1e-5f);
  float4 vg = ((const float4*)g)[t];
  float4 vbe = ((const float4*)be)[t];
  float o0 = (x0 - mean) * rstd * vg.x + vbe.x;
  float o1 = (x1 - mean) * rstd * vg.y + vbe.y;
  float o2 = (x2 - mean) * rstd * vg.z + vbe.z;
  float o3 = (x3 - mean) * rstd * vg.w + vbe.w;
  if (outf) {
    float4 o; o.x = o0; o.y = o1; o.z = o2; o.w = o3;
    ((float4*)(outf + row * H_))[t] = o;
  }
  if (outb) {
    ushort4 ob; ob.x = f2b(o0); ob.y = f2b(o1); ob.z = f2b(o2); ob.w = f2b(o3);
    ((ushort4*)(outb + row * H_))[t] = ob;
  }
}

extern "C" void kernel_launch(void* const* d_in, const int* in_sizes, int n_in,
                              void* d_out, int out_size, void* d_ws, size_t ws_size,
                              hipStream_t stream) {
  (void)in_sizes; (void)n_in; (void)out_size; (void)ws_size;
  const float* x      = (const float*)d_in[0];
  const float* enc    = (const float*)d_in[1];
  const float* sa_w[4] = {(const float*)d_in[2], (const float*)d_in[4], (const float*)d_in[6], (const float*)d_in[8]};
  const float* sa_b[4] = {(const float*)d_in[3], (const float*)d_in[5], (const float*)d_in[7], (const float*)d_in[9]};
  const float* sa_pj  = (const float*)d_in[10];
  const float* ca_w[4] = {(const float*)d_in[11], (const float*)d_in[13], (const float*)d_in[15], (const float*)d_in[17]};
  const float* ca_b[4] = {(const float*)d_in[12], (const float*)d_in[14], (const float*)d_in[16], (const float*)d_in[18]};
  const float* ca_pj  = (const float*)d_in[19];
  const float* ff_w1  = (const float*)d_in[20];
  const float* ff_b1  = (const float*)d_in[21];
  const float* ff_w2  = (const float*)d_in[22];
  const float* ff_b2  = (const float*)d_in[23];
  const float* ln1_g  = (const float*)d_in[24];
  const float* ln1_b  = (const float*)d_in[25];
  const float* ln2_g  = (const float*)d_in[26];
  const float* ln2_b  = (const float*)d_in[27];
  const float* ln3_g  = (const float*)d_in[28];
  const float* ln3_b  = (const float*)d_in[29];

  float* ws = (float*)d_ws;
  // Offsets in f32 elements. Peak ~222.6 MB (<235 proven good).
  unsigned short* XB = (unsigned short*)(ws);                 // [16384][1024] bf16
  unsigned short* EB = (unsigned short*)(ws + 8388608LL);     // enc bf16 / AO / ffT
  unsigned short* QKVb = (unsigned short*)(ws + 16777216LL);  // [16384][3072] bf16
  unsigned short* Pq = (unsigned short*)(ws + 41943040LL);    // [8][4096][256] bf16
  unsigned short* Pk = (unsigned short*)(ws + 46137344LL);
  unsigned short* PO = Pq;                                     // [16384][1024] bf16
  unsigned short* MIDB = Pq;                                   // FFN mid chunk
  unsigned short* FO = (unsigned short*)(ws + 50331648LL);
  unsigned short* WTph = (unsigned short*)(ws + 52428800LL);  // 4 x [1024][1024] bf16
  unsigned short* pjB = (unsigned short*)(ws + 54525952LL);   // 2 x [256][64] bf16
  float* ctxA  = ws + 54542336LL;                              // 8 x [8][64][256] f32
  float* ksumA = ws + 55590912LL;                              // 8 x [8][256] f32
  float* denomB = ws + 55607296LL;                             // [8][4096] f32
  float* biasC = ws + 55640064LL;                              // [3072] f32

  unsigned short* ff1T = EB;
  unsigned short* ff2T = EB + 4194304LL;
  unsigned short* pjB_sa = pjB, *pjB_ca = pjB + 16384;

  dim3 blk(256, 1, 1);
  const long long sAO = (long long)N_ * HD_;
  const int LDQ = 3072;

  projB_cvt<<<dim3(64), blk, 0, stream>>>(sa_pj, pjB_sa);
  projB_cvt<<<dim3(64), blk, 0, stream>>>(ca_pj, pjB_ca);
  cvt_bf16<<<dim3(2048), blk, 0, stream>>>(x, XB, 16777216LL);

  auto attn_core = [&](const unsigned short* pj, const float* const* bs) {
    hipMemsetAsync(ctxA, 0, (1048576LL + 16384LL) * sizeof(float), stream);
    for (int b = 0; b < B_; ++b) {
      for (int g = 0; g < 2; ++g) {
        const int idx = b * 2 + g;
        const long long ro = (long long)b * 4096 * LDQ + g * 512;
        float* ksum = ksumA + (long long)idx * 2048;
        float* ctxT = ctxA + (long long)idx * 131072;
        feat_mfma<0><<<dim3(1,64,8), blk, 0, stream>>>(QKVb + 1024 + ro, LDQ, pj, ksum, Pk, nullptr);
        feat_mfma<1><<<dim3(1,64,8), blk, 0, stream>>>(QKVb + ro, LDQ, pj, ksum, Pq, denomB);
        ctx_k<<<dim3(4,16,8), blk, 0, stream>>>(Pk, QKVb + 2048 + ro, LDQ, ctxT);
        ao_mfma<<<dim3(1,32,8), blk, 0, stream>>>(Pq, ctxT, denomB,
            EB + (long long)b * NH_ * sAO + (long long)g * 8 * sAO);
      }
    }
    gemm_mfma<0><<<dim3(8,128), blk, 0, stream>>>(EB, H_, WTph + 3145728, bs[3], PO, H_, H_);
  };

  // ---- self-attention: fused QKV projection ----
  for (int i = 0; i < 4; ++i)
    wt_cvt<<<dim3(32, 32), blk, 0, stream>>>(sa_w[i], WTph + (long long)i * 1048576, H_, H_);
  bias_cat<<<dim3(12), blk, 0, stream>>>(sa_b[0], sa_b[1], sa_b[2], biasC);
  gemm_mfma<0><<<dim3(24,128), blk, 0, stream>>>(XB, H_, WTph, biasC, QKVb, LDQ, H_);
  attn_core(pjB_sa, sa_b);
  ln_k<<<dim3(16384), blk, 0, stream>>>(x, nullptr, PO, ln1_g, ln1_b, nullptr, XB);

  // ---- cross-attention: Q from h1, fused KV from enc ----
  cvt_bf16<<<dim3(2048), blk, 0, stream>>>(enc, EB, 16777216LL);
  for (int i = 0; i < 4; ++i)
    wt_cvt<<<dim3(32, 32), blk, 0, stream>>>(ca_w[i], WTph + (long long)i * 1048576, H_, H_);
  bias_cat<<<dim3(8), blk, 0, stream>>>(ca_b[1], ca_b[2], nullptr, biasC);
  gemm_mfma<0><<<dim3(8,128), blk, 0, stream>>>(XB, H_, WTph, ca_b[0], QKVb, LDQ, H_);
  gemm_mfma<0><<<dim3(16,128), blk, 0, stream>>>(EB, H_, WTph + 1048576, biasC, QKVb + 1024, LDQ, H_);
  attn_core(pjB_ca, ca_b);
  ln_k<<<dim3(16384), blk, 0, stream>>>(nullptr, XB, PO, ln2_g, ln2_b, nullptr, XB);

  // ---- FFN ----
  wt_cvt<<<dim3(128, 32), blk, 0, stream>>>(ff_w1, ff1T, H_, 4096);
  wt_cvt<<<dim3(32, 128), blk, 0, stream>>>(ff_w2, ff2T, 4096, H_);
  for (int c = 0; c < 4; ++c) {
    const long long co = (long long)c * 4096 * H_;
    gemm_mfma<1><<<dim3(32,32), blk, 0, stream>>>(XB + co, H_, ff1T, ff_b1, MIDB, 4096, H_);
    gemm_mfma<0><<<dim3(8,32), blk, 0, stream>>>(MIDB, 4096, ff2T, ff_b2, FO, H_, 4096);
    ln_k<<<dim3(4096), blk, 0, stream>>>(nullptr, XB + co, FO, ln3_g, ln3_b,
                                         (float*)d_out + co, nullptr);
  }
}

// Round 11
// 1543.114 us; speedup vs baseline: 10.3593x; 1.5188x over previous
//
#include <hip/hip_runtime.h>
#include <hip/hip_bf16.h>

#define B_ 4
#define N_ 4096
#define H_ 1024
#define NH_ 16
#define HD_ 64
#define M_ 256

typedef __attribute__((ext_vector_type(8))) __bf16 bf16x8;
typedef __attribute__((ext_vector_type(4))) float f32x4;
typedef __attribute__((ext_vector_type(4))) unsigned int u32x4;

__device__ __forceinline__ float bf2f(unsigned short u) {
  union { unsigned int i; float f; } x; x.i = ((unsigned int)u) << 16; return x.f;
}
__device__ __forceinline__ unsigned short f2b(float f) {
  __hip_bfloat16 h = __float2bfloat16(f);
  return *(unsigned short*)&h;
}
__device__ __forceinline__ float gelu_f(float x) {
  const float c = 0.7978845608028654f;
  float t = tanhf(c * (x + 0.044715f * x * x * x));
  return 0.5f * x * (1.0f + t);
}

typedef __attribute__((address_space(3))) unsigned int as3_uint;
typedef const __attribute__((address_space(1))) unsigned int as1_uint;
__device__ __forceinline__ void gload16(const void* g, void* l) {
  __builtin_amdgcn_global_load_lds((as1_uint*)g, (as3_uint*)l, 16, 0, 0);
}

// ---------------------------------------------------------------------------
// Dense bf16 MFMA GEMM (round-10 verified: dbuf global_load_lds, XCD swizzle,
// LDS-staged nontemporal epilogue).
// ---------------------------------------------------------------------------
template<int ACT>
__launch_bounds__(256)
__global__ void gemm_mfma(const unsigned short* __restrict__ A, int lda,
                          const unsigned short* __restrict__ BT,
                          const float* __restrict__ bias,
                          unsigned short* __restrict__ C, int ldc, int K) {
  __shared__ __align__(16) char LDS[65536];

  const int tid = threadIdx.x;
  const int nwg = gridDim.x * gridDim.y;
  const int lin = blockIdx.y * gridDim.x + blockIdx.x;
  const int mm = (lin & 7) * (nwg >> 3) + (lin >> 3);
  const int bx = mm % gridDim.x, by = mm / gridDim.x;
  const int row0 = by * 128;
  const int col0 = bx * 128;

  const int w = tid >> 6, lane = tid & 63;
  const int wm = w >> 1, wn = w & 1;
  const int ln = lane & 15, hi = lane >> 4;
  const int rswz = (ln & 7) << 4;

  const int srow = w * 8 + (lane >> 3);
  const int schunk = ((lane & 7) ^ (lane >> 3)) * 8;
  const unsigned short* Ag = A + (long long)(row0 + srow) * lda + schunk;
  const unsigned short* Bg = BT + (long long)(col0 + srow) * K + schunk;
  const int ldsw = w * 1024;

  f32x4 acc[4][4];
#pragma unroll
  for (int i = 0; i < 4; ++i)
#pragma unroll
    for (int j = 0; j < 4; ++j) acc[i][j] = (f32x4){0.f, 0.f, 0.f, 0.f};

  auto STAGE = [&](int p, int k0) {
    char* dst = LDS + p * 32768 + ldsw;
#pragma unroll
    for (int i = 0; i < 4; ++i) {
      gload16(Ag + (long long)i * 32 * lda + k0, dst + i * 4096);
      gload16(Bg + (long long)i * 32 * K + k0, dst + 16384 + i * 4096);
    }
  };
  auto COMPUTE = [&](int p) {
    char* AsB = LDS + p * 32768;
    char* BsB = AsB + 16384;
#pragma unroll
    for (int kc = 0; kc < 2; ++kc) {
      const int koff = (kc * 64 + hi * 16) ^ rswz;
      bf16x8 av[4], bv[4];
#pragma unroll
      for (int i = 0; i < 4; ++i)
        av[i] = *(bf16x8*)(AsB + (wm * 64 + i * 16 + ln) * 128 + koff);
#pragma unroll
      for (int j = 0; j < 4; ++j)
        bv[j] = *(bf16x8*)(BsB + (wn * 64 + j * 16 + ln) * 128 + koff);
#pragma unroll
      for (int i = 0; i < 4; ++i)
#pragma unroll
        for (int j = 0; j < 4; ++j)
          acc[i][j] = __builtin_amdgcn_mfma_f32_16x16x32_bf16(av[i], bv[j], acc[i][j], 0, 0, 0);
    }
  };

  STAGE(0, 0);
  __syncthreads();
  int cur = 0;
  for (int k0 = 64; k0 < K; k0 += 64) {
    STAGE(cur ^ 1, k0);
    COMPUTE(cur);
    __syncthreads();
    cur ^= 1;
  }
  COMPUTE(cur);
  __syncthreads();

  char* SB = LDS;
#pragma unroll
  for (int j = 0; j < 4; ++j) {
    const int lcol = wn * 64 + j * 16 + ln;
    const float bj = bias ? bias[col0 + lcol] : 0.0f;
#pragma unroll
    for (int i = 0; i < 4; ++i) {
      const int rb_ = wm * 64 + i * 16 + hi * 4;
#pragma unroll
      for (int r = 0; r < 4; ++r) {
        float v = acc[i][j][r] + bj;
        if (ACT == 1) v = gelu_f(v);
        const int row = rb_ + r;
        *(unsigned short*)(SB + ((row * 256 + lcol * 2) ^ ((row & 7) << 4))) = f2b(v);
      }
    }
  }
  __syncthreads();
#pragma unroll
  for (int p = 0; p < 8; ++p) {
    const int idx = p * 256 + tid;
    const int row = idx >> 4, seg = idx & 15;
    u32x4 v = *(u32x4*)(SB + ((row * 256 + seg * 16) ^ ((row & 7) << 4)));
    __builtin_nontemporal_store(v, (u32x4*)(C + (long long)(row0 + row) * ldc + col0 + seg * 8));
  }
}

// ---------------------------------------------------------------------------
// Fused K-feature + ctx + ksum (flash-style, no P materialization).
// grid (8 n-splits, 1, 64 heads), block 256 (4 waves).
// Per 64-row tile: Kp = FAVOR+(K-tile) via MFMA -> P^T, V^T in LDS ->
// ctx[m][d] += P^T @ V accumulated in registers; atomics at end.
// ---------------------------------------------------------------------------
__launch_bounds__(256)
__global__ void ctxksum_mfma(const unsigned short* __restrict__ QKV,
                             const unsigned short* __restrict__ pjB,   // [256][64] bf16
                             float* __restrict__ ksum,                 // [64][256]
                             float* __restrict__ ctxA) {               // [64][256][64]
  __shared__ char Kt[8192];      // 64 n x 128 B (k), row-xor swz
  __shared__ char Vt[8192];      // 64 d x 128 B (n), row-xor swz
  __shared__ char Pt[32768];     // 256 m x 128 B (n), row-xor swz
  __shared__ float rmaxL[4][64];
  __shared__ float ssqL[64];
  const int z = blockIdx.z, b = z >> 4, hh = z & 15;
  const int n0 = blockIdx.x * 512;
  const unsigned short* Kg = QKV + (long long)(b * 4096) * 3072 + 1024 + hh * 64;
  const unsigned short* Vg = QKV + (long long)(b * 4096) * 3072 + 2048 + hh * 64;
  const int tid = threadIdx.x;
  const int w = tid >> 6, lane = tid & 63;
  const int ln = lane & 15, hi = lane >> 4;
  const int rswz = (ln & 7) << 4;

  f32x4 accC[4][4];
#pragma unroll
  for (int i = 0; i < 4; ++i)
#pragma unroll
    for (int j = 0; j < 4; ++j) accC[i][j] = (f32x4){0.f, 0.f, 0.f, 0.f};
  float cs[4] = {0.f, 0.f, 0.f, 0.f};

  for (int t = 0; t < 8; ++t) {
    const long long nt = n0 + t * 64;
    __syncthreads();                       // protect LDS from prior tile's readers
    // stage K-tile (swizzled-source -> linear LDS)
#pragma unroll
    for (int p = 0; p < 2; ++p) {
      int id = p * 256 + tid;
      int r = id >> 3, c = id & 7;
      gload16(Kg + (nt + r) * 3072 + ((c ^ (r & 7)) * 8), Kt + id * 16);
    }
    // stage V^T (reg round-trip, b16 scatter with row-xor swz)
    {
      int n = tid >> 2, d0 = (tid & 3) * 16;
      const unsigned short* src = Vg + (nt + n) * 3072 + d0;
      ushort4 v0 = *(const ushort4*)src;
      ushort4 v1 = *(const ushort4*)(src + 4);
      ushort4 v2 = *(const ushort4*)(src + 8);
      ushort4 v3 = *(const ushort4*)(src + 12);
      unsigned short vals[16] = {v0.x, v0.y, v0.z, v0.w, v1.x, v1.y, v1.z, v1.w,
                                 v2.x, v2.y, v2.z, v2.w, v3.x, v3.y, v3.z, v3.w};
#pragma unroll
      for (int e = 0; e < 16; ++e) {
        int d = d0 + e;
        *(unsigned short*)(Vt + ((d * 128 + n * 2) ^ ((d & 7) << 4))) = vals[e];
      }
    }
    __syncthreads();

    // feat MFMA: dd[64n][256m]; wave w owns m-quarter w*64
    f32x4 accF[4][4];
#pragma unroll
    for (int i = 0; i < 4; ++i)
#pragma unroll
      for (int j = 0; j < 4; ++j) accF[i][j] = (f32x4){0.f, 0.f, 0.f, 0.f};
#pragma unroll
    for (int kc = 0; kc < 2; ++kc) {
      const int koff = (kc * 64 + hi * 16) ^ rswz;
      bf16x8 av[4], bq[4];
#pragma unroll
      for (int i = 0; i < 4; ++i)
        av[i] = *(bf16x8*)(Kt + (i * 16 + ln) * 128 + koff);
#pragma unroll
      for (int j = 0; j < 4; ++j)
        bq[j] = *(const bf16x8*)(pjB + (w * 64 + j * 16 + ln) * 64 + kc * 32 + hi * 8);
#pragma unroll
      for (int i = 0; i < 4; ++i)
#pragma unroll
        for (int j = 0; j < 4; ++j)
          accF[i][j] = __builtin_amdgcn_mfma_f32_16x16x32_bf16(av[i], bq[j], accF[i][j], 0, 0, 0);
    }

    // wave-local rowmax -> rmaxL
#pragma unroll
    for (int i = 0; i < 4; ++i)
#pragma unroll
      for (int r = 0; r < 4; ++r) {
        float m = fmaxf(fmaxf(accF[i][0][r], accF[i][1][r]), fmaxf(accF[i][2][r], accF[i][3][r]));
        m = fmaxf(m, __shfl_xor(m, 1, 64));
        m = fmaxf(m, __shfl_xor(m, 2, 64));
        m = fmaxf(m, __shfl_xor(m, 4, 64));
        m = fmaxf(m, __shfl_xor(m, 8, 64));
        if (ln == 0) rmaxL[w][i * 16 + hi * 4 + r] = m;
      }
    // ssq[n] from K-tile
    {
      int r = tid >> 2, q = tid & 3;
      int b0 = (r * 128 + q * 32) ^ ((r & 7) << 4);
      int b1 = (r * 128 + q * 32 + 16) ^ ((r & 7) << 4);
      u32x4 x0 = *(u32x4*)(Kt + b0);
      u32x4 x1 = *(u32x4*)(Kt + b1);
      float s = 0.f;
#pragma unroll
      for (int e = 0; e < 4; ++e) {
        float a0 = bf2f((unsigned short)(x0[e] & 0xffff)), a1 = bf2f((unsigned short)(x0[e] >> 16));
        float a2 = bf2f((unsigned short)(x1[e] & 0xffff)), a3 = bf2f((unsigned short)(x1[e] >> 16));
        s += a0 * a0 + a1 * a1 + a2 * a2 + a3 * a3;
      }
      s += __shfl_xor(s, 1, 64);
      s += __shfl_xor(s, 2, 64);
      if (q == 0) ssqL[r] = s;
    }
    __syncthreads();

    // epilogue: P values -> Pt (b64 packs), colsum accumulation
    float base[4][4];
#pragma unroll
    for (int i = 0; i < 4; ++i)
#pragma unroll
      for (int r = 0; r < 4; ++r) {
        int row = i * 16 + hi * 4 + r;
        base[i][r] = 0.0625f * ssqL[row] +
                     fmaxf(fmaxf(rmaxL[0][row], rmaxL[1][row]), fmaxf(rmaxL[2][row], rmaxL[3][row]));
      }
#pragma unroll
    for (int i = 0; i < 4; ++i)
#pragma unroll
      for (int j = 0; j < 4; ++j) {
        ushort4 pk;
        float v0 = 0.0625f * (expf(accF[i][j][0] - base[i][0]) + 1e-4f);
        float v1 = 0.0625f * (expf(accF[i][j][1] - base[i][1]) + 1e-4f);
        float v2 = 0.0625f * (expf(accF[i][j][2] - base[i][2]) + 1e-4f);
        float v3 = 0.0625f * (expf(accF[i][j][3] - base[i][3]) + 1e-4f);
        cs[j] += v0 + v1 + v2 + v3;
        pk.x = f2b(v0); pk.y = f2b(v1); pk.z = f2b(v2); pk.w = f2b(v3);
        int m = w * 64 + j * 16 + ln;
        *(ushort4*)(Pt + ((m * 128 + i * 32 + hi * 8) ^ ((m & 7) << 4))) = pk;
      }
    __syncthreads();

    // ctx MFMA: ctx[m][d] += P^T @ V ; wave w owns m-quarter w*64
#pragma unroll
    for (int kc = 0; kc < 2; ++kc) {
      const int koff = (kc * 64 + hi * 16) ^ rswz;
      bf16x8 am[4], bv[4];
#pragma unroll
      for (int i = 0; i < 4; ++i)
        am[i] = *(bf16x8*)(Pt + (w * 64 + i * 16 + ln) * 128 + koff);
#pragma unroll
      for (int j = 0; j < 4; ++j)
        bv[j] = *(bf16x8*)(Vt + (j * 16 + ln) * 128 + koff);
#pragma unroll
      for (int i = 0; i < 4; ++i)
#pragma unroll
        for (int j = 0; j < 4; ++j)
          accC[i][j] = __builtin_amdgcn_mfma_f32_16x16x32_bf16(am[i], bv[j], accC[i][j], 0, 0, 0);
    }
  }

  // ksum atomics (colsum over this split's 512 rows)
#pragma unroll
  for (int j = 0; j < 4; ++j) {
    cs[j] += __shfl_xor(cs[j], 16, 64);
    cs[j] += __shfl_xor(cs[j], 32, 64);
  }
  if (hi == 0) {
#pragma unroll
    for (int j = 0; j < 4; ++j)
      atomicAdd(&ksum[z * 256 + w * 64 + j * 16 + ln], cs[j]);
  }
  // ctx atomics
#pragma unroll
  for (int i = 0; i < 4; ++i)
#pragma unroll
    for (int j = 0; j < 4; ++j)
#pragma unroll
      for (int r = 0; r < 4; ++r)
        atomicAdd(&ctxA[(long long)z * 16384 + (w * 64 + i * 16 + hi * 4 + r) * 64 + j * 16 + ln],
                  accC[i][j][r]);
}

// ctx finalize: f32 [z][256m][64d] -> bf16 ctx^T [z][2mh][64d][16 swizzled chunks][8]
__launch_bounds__(256)
__global__ void ctx_fin(const float* __restrict__ ctxA, unsigned short* __restrict__ ctxbf) {
  const int z = blockIdx.x;
  const float* src = ctxA + (long long)z * 16384;
  unsigned short* dst = ctxbf + (long long)z * 16384;
  for (int cc = threadIdx.x; cc < 2048; cc += 256) {
    int mh = cc >> 10, rem = cc & 1023, d = rem >> 4, cl = rem & 15;
    int m0 = mh * 128 + cl * 8;
    ushort4 o0, o1;
    o0.x = f2b(src[(m0 + 0) * 64 + d]); o0.y = f2b(src[(m0 + 1) * 64 + d]);
    o0.z = f2b(src[(m0 + 2) * 64 + d]); o0.w = f2b(src[(m0 + 3) * 64 + d]);
    o1.x = f2b(src[(m0 + 4) * 64 + d]); o1.y = f2b(src[(m0 + 5) * 64 + d]);
    o1.z = f2b(src[(m0 + 6) * 64 + d]); o1.w = f2b(src[(m0 + 7) * 64 + d]);
    unsigned short* p = dst + (long long)mh * 8192 + (d * 16 + (cl ^ (d & 7))) * 8;
    *(ushort4*)p = o0;
    *(ushort4*)(p + 4) = o1;
  }
}

// ---------------------------------------------------------------------------
// Fused Q-feature + denom + PV (attn out). grid (64 n-tiles, 1, 64 heads).
// Qp computed on the fly (P in LDS natural layout); denom = sum Qp*ksum;
// out[n][d] = (Qp @ ctx^T) / denom, LDS-staged coalesced store.
// ---------------------------------------------------------------------------
__launch_bounds__(256)
__global__ void ao_fused(const unsigned short* __restrict__ QKV,
                         const unsigned short* __restrict__ pjB,
                         const float* __restrict__ ksum,
                         const unsigned short* __restrict__ ctxbf,
                         unsigned short* __restrict__ AO) {   // [16384][1024]
  __shared__ char Qt[8192];        // Q tile; later Ct (out tile)
  __shared__ char Ps[32768];       // P [64n][512B], row-xor swz
  __shared__ char Ch[16384];       // ctx^T half [64d][256B], row-xor swz
  __shared__ float rmaxL[4][64];
  __shared__ float ssqL[64];
  __shared__ float dprt[4][64];
  __shared__ float denomS[64];
  const int z = blockIdx.z, b = z >> 4, hh = z & 15;
  const int n0 = blockIdx.x * 64;
  const unsigned short* Qg = QKV + (long long)(b * 4096) * 3072 + hh * 64;
  const int tid = threadIdx.x;
  const int w = tid >> 6, lane = tid & 63;
  const int ln = lane & 15, hi = lane >> 4;
  const int rswz = (ln & 7) << 4;

  // stage Q tile
#pragma unroll
  for (int p = 0; p < 2; ++p) {
    int id = p * 256 + tid;
    int r = id >> 3, c = id & 7;
    gload16(Qg + (long long)(n0 + r) * 3072 + ((c ^ (r & 7)) * 8), Qt + id * 16);
  }
  __syncthreads();

  // feat MFMA
  f32x4 accF[4][4];
#pragma unroll
  for (int i = 0; i < 4; ++i)
#pragma unroll
    for (int j = 0; j < 4; ++j) accF[i][j] = (f32x4){0.f, 0.f, 0.f, 0.f};
#pragma unroll
  for (int kc = 0; kc < 2; ++kc) {
    const int koff = (kc * 64 + hi * 16) ^ rswz;
    bf16x8 av[4], bq[4];
#pragma unroll
    for (int i = 0; i < 4; ++i)
      av[i] = *(bf16x8*)(Qt + (i * 16 + ln) * 128 + koff);
#pragma unroll
    for (int j = 0; j < 4; ++j)
      bq[j] = *(const bf16x8*)(pjB + (w * 64 + j * 16 + ln) * 64 + kc * 32 + hi * 8);
#pragma unroll
    for (int i = 0; i < 4; ++i)
#pragma unroll
      for (int j = 0; j < 4; ++j)
        accF[i][j] = __builtin_amdgcn_mfma_f32_16x16x32_bf16(av[i], bq[j], accF[i][j], 0, 0, 0);
  }

#pragma unroll
  for (int i = 0; i < 4; ++i)
#pragma unroll
    for (int r = 0; r < 4; ++r) {
      float m = fmaxf(fmaxf(accF[i][0][r], accF[i][1][r]), fmaxf(accF[i][2][r], accF[i][3][r]));
      m = fmaxf(m, __shfl_xor(m, 1, 64));
      m = fmaxf(m, __shfl_xor(m, 2, 64));
      m = fmaxf(m, __shfl_xor(m, 4, 64));
      m = fmaxf(m, __shfl_xor(m, 8, 64));
      if (ln == 0) rmaxL[w][i * 16 + hi * 4 + r] = m;
    }
  {
    int r = tid >> 2, q = tid & 3;
    int b0 = (r * 128 + q * 32) ^ ((r & 7) << 4);
    int b1 = (r * 128 + q * 32 + 16) ^ ((r & 7) << 4);
    u32x4 x0 = *(u32x4*)(Qt + b0);
    u32x4 x1 = *(u32x4*)(Qt + b1);
    float s = 0.f;
#pragma unroll
    for (int e = 0; e < 4; ++e) {
      float a0 = bf2f((unsigned short)(x0[e] & 0xffff)), a1 = bf2f((unsigned short)(x0[e] >> 16));
      float a2 = bf2f((unsigned short)(x1[e] & 0xffff)), a3 = bf2f((unsigned short)(x1[e] >> 16));
      s += a0 * a0 + a1 * a1 + a2 * a2 + a3 * a3;
    }
    s += __shfl_xor(s, 1, 64);
    s += __shfl_xor(s, 2, 64);
    if (q == 0) ssqL[r] = s;
  }
  __syncthreads();

  // epilogue: P -> Ps (natural [n][m]), denom partials
  float ks[4];
#pragma unroll
  for (int j = 0; j < 4; ++j) ks[j] = ksum[z * 256 + w * 64 + j * 16 + ln];
#pragma unroll
  for (int i = 0; i < 4; ++i)
#pragma unroll
    for (int r = 0; r < 4; ++r) {
      int n = i * 16 + hi * 4 + r;
      float base = 0.0625f * ssqL[n] +
                   fmaxf(fmaxf(rmaxL[0][n], rmaxL[1][n]), fmaxf(rmaxL[2][n], rmaxL[3][n]));
      float dp = 0.f;
#pragma unroll
      for (int j = 0; j < 4; ++j) {
        float v = 0.0625f * (expf(accF[i][j][r] - base) + 1e-4f);
        int m = w * 64 + j * 16 + ln;
        *(unsigned short*)(Ps + n * 512 + ((m * 2) ^ ((n & 7) << 4))) = f2b(v);
        dp += v * ks[j];
      }
      dp += __shfl_xor(dp, 1, 64);
      dp += __shfl_xor(dp, 2, 64);
      dp += __shfl_xor(dp, 4, 64);
      dp += __shfl_xor(dp, 8, 64);
      if (ln == 0) dprt[w][n] = dp;
    }
  __syncthreads();
  if (tid < 64) denomS[tid] = dprt[0][tid] + dprt[1][tid] + dprt[2][tid] + dprt[3][tid];

  // PV: wave w computes rows w*16..+15, cols 64; k over m in 2 halves
  f32x4 accO[4];
#pragma unroll
  for (int j = 0; j < 4; ++j) accO[j] = (f32x4){0.f, 0.f, 0.f, 0.f};
#pragma unroll
  for (int mh = 0; mh < 2; ++mh) {
#pragma unroll
    for (int p = 0; p < 4; ++p) {
      int id = p * 256 + tid;
      gload16(ctxbf + (long long)z * 16384 + mh * 8192 + id * 8, Ch + id * 16);
    }
    __syncthreads();
#pragma unroll
    for (int ms = 0; ms < 4; ++ms) {
      const int koff = (ms * 64 + hi * 16);
      bf16x8 ap = *(bf16x8*)(Ps + (w * 16 + ln) * 512 + ((mh * 256 + koff) ^ rswz));
      bf16x8 bc[4];
#pragma unroll
      for (int j = 0; j < 4; ++j)
        bc[j] = *(bf16x8*)(Ch + (j * 16 + ln) * 256 + (koff ^ rswz));
#pragma unroll
      for (int j = 0; j < 4; ++j)
        accO[j] = __builtin_amdgcn_mfma_f32_16x16x32_bf16(ap, bc[j], accO[j], 0, 0, 0);
    }
    __syncthreads();
  }

  // epilogue: divide by denom, stage Ct (reuse Qt), coalesced store
  float inv[4];
#pragma unroll
  for (int r = 0; r < 4; ++r) inv[r] = 1.0f / denomS[w * 16 + hi * 4 + r];
  char* Ct = Qt;
#pragma unroll
  for (int j = 0; j < 4; ++j)
#pragma unroll
    for (int r = 0; r < 4; ++r) {
      int n = w * 16 + hi * 4 + r;
      int d = j * 16 + ln;
      *(unsigned short*)(Ct + ((n * 128 + d * 2) ^ ((n & 7) << 4))) = f2b(accO[j][r] * inv[r]);
    }
  __syncthreads();
#pragma unroll
  for (int p = 0; p < 2; ++p) {
    int idx = p * 256 + tid;
    int row = idx >> 3, seg = idx & 7;
    u32x4 v = *(u32x4*)(Ct + ((row * 128 + seg * 16) ^ ((row & 7) << 4)));
    *(u32x4*)(AO + (long long)(b * 4096 + n0 + row) * 1024 + hh * 64 + seg * 8) = v;
  }
}

// weight transpose+convert: out[n*K+k] = bf16(in[k*N+n])
__launch_bounds__(256)
__global__ void wt_cvt(const float* __restrict__ in, unsigned short* __restrict__ out,
                       int K, int N) {
  __shared__ float t[32][33];
  int k0 = blockIdx.y * 32, n0 = blockIdx.x * 32;
  int tx = threadIdx.x & 31, ty = threadIdx.x >> 5;
  for (int r = ty; r < 32; r += 8) t[r][tx] = in[(long long)(k0 + r) * N + n0 + tx];
  __syncthreads();
  for (int r = ty; r < 32; r += 8) out[(long long)(n0 + r) * K + k0 + tx] = f2b(t[tx][r]);
}

// pjB[m][d] = bf16(dn * proj[m][d])
__launch_bounds__(256)
__global__ void projB_cvt(const float* __restrict__ proj, unsigned short* __restrict__ out) {
  int i = blockIdx.x * 256 + threadIdx.x;
  out[i] = f2b(0.35355339059327373f * proj[i]);
}

// bias concat
__launch_bounds__(256)
__global__ void bias_cat(const float* __restrict__ b0, const float* __restrict__ b1,
                         const float* __restrict__ b2, float* __restrict__ out) {
  int i = blockIdx.x * 256 + threadIdx.x;
  float v;
  if (i < 1024) v = b0[i];
  else if (i < 2048) v = b1[i - 1024];
  else v = b2[i - 2048];
  out[i] = v;
}

__launch_bounds__(256)
__global__ void cvt_bf16(const float* __restrict__ in, unsigned short* __restrict__ out,
                         long long n) {
  long long stride = (long long)gridDim.x * 1024;
  for (long long i = ((long long)blockIdx.x * 256 + threadIdx.x) * 4; i < n; i += stride) {
    float4 v = *(const float4*)&in[i];
    ushort4 o;
    o.x = f2b(v.x); o.y = f2b(v.y); o.z = f2b(v.z); o.w = f2b(v.w);
    *(ushort4*)&out[i] = o;
  }
}

// out = LN(res + po) * g + beta, rows of 1024.
__launch_bounds__(256)
__global__ void ln_k(const float* __restrict__ resf, const unsigned short* __restrict__ resb,
                     const unsigned short* __restrict__ po,
                     const float* __restrict__ g, const float* __restrict__ be,
                     float* __restrict__ outf, unsigned short* __restrict__ outb) {
  long long row = blockIdx.x;
  int t = threadIdx.x;
  float x0, x1, x2, x3;
  if (resf) {
    float4 va = ((const float4*)(resf + row * H_))[t];
    x0 = va.x; x1 = va.y; x2 = va.z; x3 = va.w;
  } else {
    ushort4 va = ((const ushort4*)(resb + row * H_))[t];
    x0 = bf2f(va.x); x1 = bf2f(va.y); x2 = bf2f(va.z); x3 = bf2f(va.w);
  }
  {
    ushort4 vp = ((const ushort4*)(po + row * H_))[t];
    x0 += bf2f(vp.x); x1 += bf2f(vp.y); x2 += bf2f(vp.z); x3 += bf2f(vp.w);
  }
  float s = x0 + x1 + x2 + x3;
  float q = x0 * x0 + x1 * x1 + x2 * x2 + x3 * x3;
#pragma unroll
  for (int m = 1; m < 64; m <<= 1) { s += __shfl_xor(s, m, 64); q += __shfl_xor(q, m, 64); }
  __shared__ float ssum[4], ssq[4];
  int w = t >> 6, lane = t & 63;
  if (lane == 0) { ssum[w] = s; ssq[w] = q; }
  __syncthreads();
  s = ssum[0] + ssum[1] + ssum[2] + ssum[3];
  q = ssq[0] + ssq[1] + ssq[2] + ssq[3];
  float mean = s * (1.0f / H_);
  float var = q * (1.0f / H_) - mean * mean;
  float rstd = rsqrtf(var + 1e-5f);
  float4 vg = ((const float4*)g)[t];
  float4 vbe = ((const float4*)be)[t];
  float o0 = (x0 - mean) * rstd * vg.x + vbe.x;
  float o1 = (x1 - mean) * rstd * vg.y + vbe.y;
  float o2 = (x2 - mean) * rstd * vg.z + vbe.z;
  float o3 = (x3 - mean) * rstd * vg.w + vbe.w;
  if (outf) {
    float4 o; o.x = o0; o.y = o1; o.z = o2; o.w = o3;
    ((float4*)(outf + row * H_))[t] = o;
  }
  if (outb) {
    ushort4 ob; ob.x = f2b(o0); ob.y = f2b(o1); ob.z = f2b(o2); ob.w = f2b(o3);
    ((ushort4*)(outb + row * H_))[t] = ob;
  }
}

extern "C" void kernel_launch(void* const* d_in, const int* in_sizes, int n_in,
                              void* d_out, int out_size, void* d_ws, size_t ws_size,
                              hipStream_t stream) {
  (void)in_sizes; (void)n_in; (void)out_size; (void)ws_size;
  const float* x      = (const float*)d_in[0];
  const float* enc    = (const float*)d_in[1];
  const float* sa_w[4] = {(const float*)d_in[2], (const float*)d_in[4], (const float*)d_in[6], (const float*)d_in[8]};
  const float* sa_b[4] = {(const float*)d_in[3], (const float*)d_in[5], (const float*)d_in[7], (const float*)d_in[9]};
  const float* sa_pj  = (const float*)d_in[10];
  const float* ca_w[4] = {(const float*)d_in[11], (const float*)d_in[13], (const float*)d_in[15], (const float*)d_in[17]};
  const float* ca_b[4] = {(const float*)d_in[12], (const float*)d_in[14], (const float*)d_in[16], (const float*)d_in[18]};
  const float* ca_pj  = (const float*)d_in[19];
  const float* ff_w1  = (const float*)d_in[20];
  const float* ff_b1  = (const float*)d_in[21];
  const float* ff_w2  = (const float*)d_in[22];
  const float* ff_b2  = (const float*)d_in[23];
  const float* ln1_g  = (const float*)d_in[24];
  const float* ln1_b  = (const float*)d_in[25];
  const float* ln2_g  = (const float*)d_in[26];
  const float* ln2_b  = (const float*)d_in[27];
  const float* ln3_g  = (const float*)d_in[28];
  const float* ln3_b  = (const float*)d_in[29];

  float* ws = (float*)d_ws;
  // Offsets in f32 elements. Peak ~224.6 MB (<235 proven good).
  unsigned short* XB = (unsigned short*)(ws);                 // [16384][1024] bf16
  unsigned short* EB = (unsigned short*)(ws + 8388608LL);     // enc bf16 / AO / ffT
  unsigned short* QKVb = (unsigned short*)(ws + 16777216LL);  // [16384][3072] bf16
  unsigned short* PO = (unsigned short*)(ws + 41943040LL);    // [16384][1024] bf16
  unsigned short* MIDB = PO;                                   // FFN mid chunk [4096][4096]
  unsigned short* FO = (unsigned short*)(ws + 50331648LL);
  unsigned short* WTph = (unsigned short*)(ws + 52428800LL);  // 4 x [1024][1024] bf16
  unsigned short* pjB = (unsigned short*)(ws + 54525952LL);   // 2 x [256][64] bf16
  float* ctxA  = ws + 54542336LL;                              // [64][256][64] f32
  float* ksumA = ws + 55590912LL;                              // [64][256] f32
  unsigned short* ctxbf = (unsigned short*)(ws + 55607296LL); // [64][16384] bf16
  float* biasC = ws + 56131584LL;                              // [3072] f32

  unsigned short* ff1T = EB;
  unsigned short* ff2T = EB + 4194304LL;
  unsigned short* pjB_sa = pjB, *pjB_ca = pjB + 16384;

  dim3 blk(256, 1, 1);
  const int LDQ = 3072;

  projB_cvt<<<dim3(64), blk, 0, stream>>>(sa_pj, pjB_sa);
  projB_cvt<<<dim3(64), blk, 0, stream>>>(ca_pj, pjB_ca);
  cvt_bf16<<<dim3(2048), blk, 0, stream>>>(x, XB, 16777216LL);

  auto attn_core = [&](const unsigned short* pj, const float* wo_bias) {
    hipMemsetAsync(ctxA, 0, (1048576LL + 16384LL) * sizeof(float), stream);
    ctxksum_mfma<<<dim3(8, 1, 64), blk, 0, stream>>>(QKVb, pj, ksumA, ctxA);
    ctx_fin<<<dim3(64), blk, 0, stream>>>(ctxA, ctxbf);
    ao_fused<<<dim3(64, 1, 64), blk, 0, stream>>>(QKVb, pj, ksumA, ctxbf, EB);
    gemm_mfma<0><<<dim3(8, 128), blk, 0, stream>>>(EB, H_, WTph + 3145728, wo_bias, PO, H_, H_);
  };

  // ---- self-attention ----
  for (int i = 0; i < 4; ++i)
    wt_cvt<<<dim3(32, 32), blk, 0, stream>>>(sa_w[i], WTph + (long long)i * 1048576, H_, H_);
  bias_cat<<<dim3(12), blk, 0, stream>>>(sa_b[0], sa_b[1], sa_b[2], biasC);
  gemm_mfma<0><<<dim3(24, 128), blk, 0, stream>>>(XB, H_, WTph, biasC, QKVb, LDQ, H_);
  attn_core(pjB_sa, sa_b[3]);
  ln_k<<<dim3(16384), blk, 0, stream>>>(x, nullptr, PO, ln1_g, ln1_b, nullptr, XB);

  // ---- cross-attention ----
  cvt_bf16<<<dim3(2048), blk, 0, stream>>>(enc, EB, 16777216LL);
  for (int i = 0; i < 4; ++i)
    wt_cvt<<<dim3(32, 32), blk, 0, stream>>>(ca_w[i], WTph + (long long)i * 1048576, H_, H_);
  bias_cat<<<dim3(8), blk, 0, stream>>>(ca_b[1], ca_b[2], nullptr, biasC);
  gemm_mfma<0><<<dim3(8, 128), blk, 0, stream>>>(XB, H_, WTph, ca_b[0], QKVb, LDQ, H_);
  gemm_mfma<0><<<dim3(16, 128), blk, 0, stream>>>(EB, H_, WTph + 1048576, biasC, QKVb + 1024, LDQ, H_);
  attn_core(pjB_ca, ca_b[3]);
  ln_k<<<dim3(16384), blk, 0, stream>>>(nullptr, XB, PO, ln2_g, ln2_b, nullptr, XB);

  // ---- FFN ----
  wt_cvt<<<dim3(128, 32), blk, 0, stream>>>(ff_w1, ff1T, H_, 4096);
  wt_cvt<<<dim3(32, 128), blk, 0, stream>>>(ff_w2, ff2T, 4096, H_);
  for (int c = 0; c < 4; ++c) {
    const long long co = (long long)c * 4096 * H_;
    gemm_mfma<1><<<dim3(32, 32), blk, 0, stream>>>(XB + co, H_, ff1T, ff_b1, MIDB, 4096, H_);
    gemm_mfma<0><<<dim3(8, 32), blk, 0, stream>>>(MIDB, 4096, ff2T, ff_b2, FO, H_, 4096);
    ln_k<<<dim3(4096), blk, 0, stream>>>(nullptr, XB + co, FO, ln3_g, ln3_b,
                                         (float*)d_out + co, nullptr);
  }
}

// Round 12
// 1533.215 us; speedup vs baseline: 10.4261x; 1.0065x over previous
//
#include <hip/hip_runtime.h>
#include <hip/hip_bf16.h>

#define B_ 4
#define N_ 4096
#define H_ 1024
#define NH_ 16
#define HD_ 64
#define M_ 256

typedef __attribute__((ext_vector_type(8))) __bf16 bf16x8;
typedef __attribute__((ext_vector_type(4))) float f32x4;
typedef __attribute__((ext_vector_type(4))) unsigned int u32x4;

__device__ __forceinline__ float bf2f(unsigned short u) {
  union { unsigned int i; float f; } x; x.i = ((unsigned int)u) << 16; return x.f;
}
__device__ __forceinline__ unsigned short f2b(float f) {
  __hip_bfloat16 h = __float2bfloat16(f);
  return *(unsigned short*)&h;
}
__device__ __forceinline__ float gelu_f(float x) {
  const float c = 0.7978845608028654f;
  float t = tanhf(c * (x + 0.044715f * x * x * x));
  return 0.5f * x * (1.0f + t);
}

typedef __attribute__((address_space(3))) unsigned int as3_uint;
typedef const __attribute__((address_space(1))) unsigned int as1_uint;
__device__ __forceinline__ void gload16(const void* g, void* l) {
  __builtin_amdgcn_global_load_lds((as1_uint*)g, (as3_uint*)l, 16, 0, 0);
}

// ---------------------------------------------------------------------------
// Dense bf16 MFMA GEMM (round-10 verified: dbuf global_load_lds, XCD swizzle,
// LDS-staged nontemporal epilogue).
// ---------------------------------------------------------------------------
template<int ACT>
__launch_bounds__(256)
__global__ void gemm_mfma(const unsigned short* __restrict__ A, int lda,
                          const unsigned short* __restrict__ BT,
                          const float* __restrict__ bias,
                          unsigned short* __restrict__ C, int ldc, int K) {
  __shared__ __align__(16) char LDS[65536];

  const int tid = threadIdx.x;
  const int nwg = gridDim.x * gridDim.y;
  const int lin = blockIdx.y * gridDim.x + blockIdx.x;
  const int mm = (lin & 7) * (nwg >> 3) + (lin >> 3);
  const int bx = mm % gridDim.x, by = mm / gridDim.x;
  const int row0 = by * 128;
  const int col0 = bx * 128;

  const int w = tid >> 6, lane = tid & 63;
  const int wm = w >> 1, wn = w & 1;
  const int ln = lane & 15, hi = lane >> 4;
  const int rswz = (ln & 7) << 4;

  const int srow = w * 8 + (lane >> 3);
  const int schunk = ((lane & 7) ^ (lane >> 3)) * 8;
  const unsigned short* Ag = A + (long long)(row0 + srow) * lda + schunk;
  const unsigned short* Bg = BT + (long long)(col0 + srow) * K + schunk;
  const int ldsw = w * 1024;

  f32x4 acc[4][4];
#pragma unroll
  for (int i = 0; i < 4; ++i)
#pragma unroll
    for (int j = 0; j < 4; ++j) acc[i][j] = (f32x4){0.f, 0.f, 0.f, 0.f};

  auto STAGE = [&](int p, int k0) {
    char* dst = LDS + p * 32768 + ldsw;
#pragma unroll
    for (int i = 0; i < 4; ++i) {
      gload16(Ag + (long long)i * 32 * lda + k0, dst + i * 4096);
      gload16(Bg + (long long)i * 32 * K + k0, dst + 16384 + i * 4096);
    }
  };
  auto COMPUTE = [&](int p) {
    char* AsB = LDS + p * 32768;
    char* BsB = AsB + 16384;
#pragma unroll
    for (int kc = 0; kc < 2; ++kc) {
      const int koff = (kc * 64 + hi * 16) ^ rswz;
      bf16x8 av[4], bv[4];
#pragma unroll
      for (int i = 0; i < 4; ++i)
        av[i] = *(bf16x8*)(AsB + (wm * 64 + i * 16 + ln) * 128 + koff);
#pragma unroll
      for (int j = 0; j < 4; ++j)
        bv[j] = *(bf16x8*)(BsB + (wn * 64 + j * 16 + ln) * 128 + koff);
#pragma unroll
      for (int i = 0; i < 4; ++i)
#pragma unroll
        for (int j = 0; j < 4; ++j)
          acc[i][j] = __builtin_amdgcn_mfma_f32_16x16x32_bf16(av[i], bv[j], acc[i][j], 0, 0, 0);
    }
  };

  STAGE(0, 0);
  __syncthreads();
  int cur = 0;
  for (int k0 = 64; k0 < K; k0 += 64) {
    STAGE(cur ^ 1, k0);
    COMPUTE(cur);
    __syncthreads();
    cur ^= 1;
  }
  COMPUTE(cur);
  __syncthreads();

  char* SB = LDS;
#pragma unroll
  for (int j = 0; j < 4; ++j) {
    const int lcol = wn * 64 + j * 16 + ln;
    const float bj = bias ? bias[col0 + lcol] : 0.0f;
#pragma unroll
    for (int i = 0; i < 4; ++i) {
      const int rb_ = wm * 64 + i * 16 + hi * 4;
#pragma unroll
      for (int r = 0; r < 4; ++r) {
        float v = acc[i][j][r] + bj;
        if (ACT == 1) v = gelu_f(v);
        const int row = rb_ + r;
        *(unsigned short*)(SB + ((row * 256 + lcol * 2) ^ ((row & 7) << 4))) = f2b(v);
      }
    }
  }
  __syncthreads();
#pragma unroll
  for (int p = 0; p < 8; ++p) {
    const int idx = p * 256 + tid;
    const int row = idx >> 4, seg = idx & 15;
    u32x4 v = *(u32x4*)(SB + ((row * 256 + seg * 16) ^ ((row & 7) << 4)));
    __builtin_nontemporal_store(v, (u32x4*)(C + (long long)(row0 + row) * ldc + col0 + seg * 8));
  }
}

// ---------------------------------------------------------------------------
// Fused K-feature + ctx + ksum, NO ATOMICS: per-(split,z) partial results
// stored to private slots (deterministic). ksum = colsum of bf16-ROUNDED Kp
// (matches the Kp used in the ctx MFMA -> normalization consistent).
// grid (8 n-splits, 1, 64 z), block 256.
// ctxP slot layout: [z*8+s][dh(2)][m(256)][dl(32)] f32.
// ---------------------------------------------------------------------------
__launch_bounds__(256)
__global__ void ctxksum_mfma(const unsigned short* __restrict__ QKV,
                             const unsigned short* __restrict__ pjB,
                             float* __restrict__ ksumP,     // [64z][8s][256]
                             float* __restrict__ ctxP) {    // [64z*8s][16384]
  __shared__ char Kt[8192];
  __shared__ char Vt[8192];
  __shared__ char Pt[32768];     // P^T tile; reused as f32 ctx staging at end
  __shared__ float rmaxL[4][64];
  __shared__ float ssqL[64];
  const int z = blockIdx.z, b = z >> 4, hh = z & 15;
  const int sp = blockIdx.x;
  const int n0 = sp * 512;
  const unsigned short* Kg = QKV + (long long)(b * 4096) * 3072 + 1024 + hh * 64;
  const unsigned short* Vg = QKV + (long long)(b * 4096) * 3072 + 2048 + hh * 64;
  const int tid = threadIdx.x;
  const int w = tid >> 6, lane = tid & 63;
  const int ln = lane & 15, hi = lane >> 4;
  const int rswz = (ln & 7) << 4;

  f32x4 accC[4][4];
#pragma unroll
  for (int i = 0; i < 4; ++i)
#pragma unroll
    for (int j = 0; j < 4; ++j) accC[i][j] = (f32x4){0.f, 0.f, 0.f, 0.f};
  float cs[4] = {0.f, 0.f, 0.f, 0.f};

  for (int t = 0; t < 8; ++t) {
    const long long nt = n0 + t * 64;
    __syncthreads();
#pragma unroll
    for (int p = 0; p < 2; ++p) {
      int id = p * 256 + tid;
      int r = id >> 3, c = id & 7;
      gload16(Kg + (nt + r) * 3072 + ((c ^ (r & 7)) * 8), Kt + id * 16);
    }
    {
      int n = tid >> 2, d0 = (tid & 3) * 16;
      const unsigned short* src = Vg + (nt + n) * 3072 + d0;
      ushort4 v0 = *(const ushort4*)src;
      ushort4 v1 = *(const ushort4*)(src + 4);
      ushort4 v2 = *(const ushort4*)(src + 8);
      ushort4 v3 = *(const ushort4*)(src + 12);
      unsigned short vals[16] = {v0.x, v0.y, v0.z, v0.w, v1.x, v1.y, v1.z, v1.w,
                                 v2.x, v2.y, v2.z, v2.w, v3.x, v3.y, v3.z, v3.w};
#pragma unroll
      for (int e = 0; e < 16; ++e) {
        int d = d0 + e;
        *(unsigned short*)(Vt + ((d * 128 + n * 2) ^ ((d & 7) << 4))) = vals[e];
      }
    }
    __syncthreads();

    f32x4 accF[4][4];
#pragma unroll
    for (int i = 0; i < 4; ++i)
#pragma unroll
      for (int j = 0; j < 4; ++j) accF[i][j] = (f32x4){0.f, 0.f, 0.f, 0.f};
#pragma unroll
    for (int kc = 0; kc < 2; ++kc) {
      const int koff = (kc * 64 + hi * 16) ^ rswz;
      bf16x8 av[4], bq[4];
#pragma unroll
      for (int i = 0; i < 4; ++i)
        av[i] = *(bf16x8*)(Kt + (i * 16 + ln) * 128 + koff);
#pragma unroll
      for (int j = 0; j < 4; ++j)
        bq[j] = *(const bf16x8*)(pjB + (w * 64 + j * 16 + ln) * 64 + kc * 32 + hi * 8);
#pragma unroll
      for (int i = 0; i < 4; ++i)
#pragma unroll
        for (int j = 0; j < 4; ++j)
          accF[i][j] = __builtin_amdgcn_mfma_f32_16x16x32_bf16(av[i], bq[j], accF[i][j], 0, 0, 0);
    }

#pragma unroll
    for (int i = 0; i < 4; ++i)
#pragma unroll
      for (int r = 0; r < 4; ++r) {
        float m = fmaxf(fmaxf(accF[i][0][r], accF[i][1][r]), fmaxf(accF[i][2][r], accF[i][3][r]));
        m = fmaxf(m, __shfl_xor(m, 1, 64));
        m = fmaxf(m, __shfl_xor(m, 2, 64));
        m = fmaxf(m, __shfl_xor(m, 4, 64));
        m = fmaxf(m, __shfl_xor(m, 8, 64));
        if (ln == 0) rmaxL[w][i * 16 + hi * 4 + r] = m;
      }
    {
      int r = tid >> 2, q = tid & 3;
      int b0 = (r * 128 + q * 32) ^ ((r & 7) << 4);
      int b1 = (r * 128 + q * 32 + 16) ^ ((r & 7) << 4);
      u32x4 x0 = *(u32x4*)(Kt + b0);
      u32x4 x1 = *(u32x4*)(Kt + b1);
      float s = 0.f;
#pragma unroll
      for (int e = 0; e < 4; ++e) {
        float a0 = bf2f((unsigned short)(x0[e] & 0xffff)), a1 = bf2f((unsigned short)(x0[e] >> 16));
        float a2 = bf2f((unsigned short)(x1[e] & 0xffff)), a3 = bf2f((unsigned short)(x1[e] >> 16));
        s += a0 * a0 + a1 * a1 + a2 * a2 + a3 * a3;
      }
      s += __shfl_xor(s, 1, 64);
      s += __shfl_xor(s, 2, 64);
      if (q == 0) ssqL[r] = s;
    }
    __syncthreads();

    float base[4][4];
#pragma unroll
    for (int i = 0; i < 4; ++i)
#pragma unroll
      for (int r = 0; r < 4; ++r) {
        int row = i * 16 + hi * 4 + r;
        base[i][r] = 0.0625f * ssqL[row] +
                     fmaxf(fmaxf(rmaxL[0][row], rmaxL[1][row]), fmaxf(rmaxL[2][row], rmaxL[3][row]));
      }
#pragma unroll
    for (int i = 0; i < 4; ++i)
#pragma unroll
      for (int j = 0; j < 4; ++j) {
        ushort4 pk;
        pk.x = f2b(0.0625f * (expf(accF[i][j][0] - base[i][0]) + 1e-4f));
        pk.y = f2b(0.0625f * (expf(accF[i][j][1] - base[i][1]) + 1e-4f));
        pk.z = f2b(0.0625f * (expf(accF[i][j][2] - base[i][2]) + 1e-4f));
        pk.w = f2b(0.0625f * (expf(accF[i][j][3] - base[i][3]) + 1e-4f));
        // consistent: ksum sums the SAME rounded Kp that the ctx MFMA consumes
        cs[j] += bf2f(pk.x) + bf2f(pk.y) + bf2f(pk.z) + bf2f(pk.w);
        int m = w * 64 + j * 16 + ln;
        *(ushort4*)(Pt + ((m * 128 + i * 32 + hi * 8) ^ ((m & 7) << 4))) = pk;
      }
    __syncthreads();

#pragma unroll
    for (int kc = 0; kc < 2; ++kc) {
      const int koff = (kc * 64 + hi * 16) ^ rswz;
      bf16x8 am[4], bv[4];
#pragma unroll
      for (int i = 0; i < 4; ++i)
        am[i] = *(bf16x8*)(Pt + (w * 64 + i * 16 + ln) * 128 + koff);
#pragma unroll
      for (int j = 0; j < 4; ++j)
        bv[j] = *(bf16x8*)(Vt + (j * 16 + ln) * 128 + koff);
#pragma unroll
      for (int i = 0; i < 4; ++i)
#pragma unroll
        for (int j = 0; j < 4; ++j)
          accC[i][j] = __builtin_amdgcn_mfma_f32_16x16x32_bf16(am[i], bv[j], accC[i][j], 0, 0, 0);
    }
  }

  // ksum partial (plain store, deterministic)
#pragma unroll
  for (int j = 0; j < 4; ++j) {
    cs[j] += __shfl_xor(cs[j], 16, 64);
    cs[j] += __shfl_xor(cs[j], 32, 64);
  }
  if (hi == 0) {
#pragma unroll
    for (int j = 0; j < 4; ++j)
      ksumP[((long long)z * 8 + sp) * 256 + w * 64 + j * 16 + ln] = cs[j];
  }

  // ctx partial: stage f32 halves in Pt, coalesced nontemporal store
  float* ctxPs = ctxP + ((long long)z * 8 + sp) * 16384;
#pragma unroll
  for (int dh = 0; dh < 2; ++dh) {
    __syncthreads();
#pragma unroll
    for (int i = 0; i < 4; ++i)
#pragma unroll
      for (int jj = 0; jj < 2; ++jj) {
        int j = dh * 2 + jj;
#pragma unroll
        for (int r = 0; r < 4; ++r) {
          int m = w * 64 + i * 16 + hi * 4 + r;
          int dl = jj * 16 + ln;
          *(float*)(Pt + ((m * 128 + dl * 4) ^ ((m & 7) << 4))) = accC[i][j][r];
        }
      }
    __syncthreads();
#pragma unroll
    for (int p = 0; p < 8; ++p) {
      int idx = p * 256 + tid;
      int row = idx >> 3, seg = idx & 7;
      u32x4 v = *(u32x4*)(Pt + ((row * 128 + seg * 16) ^ ((row & 7) << 4)));
      __builtin_nontemporal_store(v, (u32x4*)(ctxPs + dh * 8192 + row * 32 + seg * 4));
    }
  }
}

// reduce 8 partials (fixed order, deterministic) -> swizzled bf16 ctx^T + ksum
__launch_bounds__(256)
__global__ void ctx_fin(const float* __restrict__ ctxP, const float* __restrict__ ksumP,
                        unsigned short* __restrict__ ctxbf, float* __restrict__ ksumF) {
  __shared__ float acc[16384];   // [dh][m][32]
  const int z = blockIdx.x;
  const int tid = threadIdx.x;
  const float* base = ctxP + (long long)z * 8 * 16384;
  for (int i = tid; i < 16384; i += 256) {
    float s = 0.f;
#pragma unroll
    for (int q = 0; q < 8; ++q) s += base[(long long)q * 16384 + i];
    acc[i] = s;
  }
  {
    const float* kb = ksumP + (long long)z * 8 * 256;
    float s = 0.f;
#pragma unroll
    for (int q = 0; q < 8; ++q) s += kb[q * 256 + tid];
    ksumF[z * 256 + tid] = s;
  }
  __syncthreads();
  unsigned short* dst = ctxbf + (long long)z * 16384;
  for (int cc = tid; cc < 2048; cc += 256) {
    int mh = cc >> 10, rem = cc & 1023, d = rem >> 4, cl = rem & 15;
    int m0 = mh * 128 + cl * 8;
    int dh = d >> 5, dl = d & 31;
    ushort4 o0, o1;
    o0.x = f2b(acc[dh * 8192 + (m0 + 0) * 32 + dl]);
    o0.y = f2b(acc[dh * 8192 + (m0 + 1) * 32 + dl]);
    o0.z = f2b(acc[dh * 8192 + (m0 + 2) * 32 + dl]);
    o0.w = f2b(acc[dh * 8192 + (m0 + 3) * 32 + dl]);
    o1.x = f2b(acc[dh * 8192 + (m0 + 4) * 32 + dl]);
    o1.y = f2b(acc[dh * 8192 + (m0 + 5) * 32 + dl]);
    o1.z = f2b(acc[dh * 8192 + (m0 + 6) * 32 + dl]);
    o1.w = f2b(acc[dh * 8192 + (m0 + 7) * 32 + dl]);
    unsigned short* p = dst + (long long)mh * 8192 + (d * 16 + (cl ^ (d & 7))) * 8;
    *(ushort4*)p = o0;
    *(ushort4*)(p + 4) = o1;
  }
}

// ---------------------------------------------------------------------------
// Fused Q-feature + denom + PV. ctx^T staged up-front (latency hidden under
// Q staging + feat). denom uses bf16-ROUNDED Qp (consistent with numerator).
// ---------------------------------------------------------------------------
__launch_bounds__(256)
__global__ void ao_fused(const unsigned short* __restrict__ QKV,
                         const unsigned short* __restrict__ pjB,
                         const float* __restrict__ ksum,
                         const unsigned short* __restrict__ ctxbf,
                         unsigned short* __restrict__ AO) {
  __shared__ char Qt[8192];
  __shared__ char Ps[32768];
  __shared__ char Ch[32768];     // both ctx^T halves
  __shared__ float rmaxL[4][64];
  __shared__ float ssqL[64];
  __shared__ float dprt[4][64];
  __shared__ float denomS[64];
  const int z = blockIdx.z, b = z >> 4, hh = z & 15;
  const int n0 = blockIdx.x * 64;
  const unsigned short* Qg = QKV + (long long)(b * 4096) * 3072 + hh * 64;
  const int tid = threadIdx.x;
  const int w = tid >> 6, lane = tid & 63;
  const int ln = lane & 15, hi = lane >> 4;
  const int rswz = (ln & 7) << 4;

  // stage ctx^T (32 KB) early — drains at the first barrier
#pragma unroll
  for (int p = 0; p < 8; ++p) {
    int id = p * 256 + tid;
    gload16(ctxbf + (long long)z * 16384 + id * 8, Ch + id * 16);
  }
  // stage Q tile
#pragma unroll
  for (int p = 0; p < 2; ++p) {
    int id = p * 256 + tid;
    int r = id >> 3, c = id & 7;
    gload16(Qg + (long long)(n0 + r) * 3072 + ((c ^ (r & 7)) * 8), Qt + id * 16);
  }
  __syncthreads();

  f32x4 accF[4][4];
#pragma unroll
  for (int i = 0; i < 4; ++i)
#pragma unroll
    for (int j = 0; j < 4; ++j) accF[i][j] = (f32x4){0.f, 0.f, 0.f, 0.f};
#pragma unroll
  for (int kc = 0; kc < 2; ++kc) {
    const int koff = (kc * 64 + hi * 16) ^ rswz;
    bf16x8 av[4], bq[4];
#pragma unroll
    for (int i = 0; i < 4; ++i)
      av[i] = *(bf16x8*)(Qt + (i * 16 + ln) * 128 + koff);
#pragma unroll
    for (int j = 0; j < 4; ++j)
      bq[j] = *(const bf16x8*)(pjB + (w * 64 + j * 16 + ln) * 64 + kc * 32 + hi * 8);
#pragma unroll
    for (int i = 0; i < 4; ++i)
#pragma unroll
      for (int j = 0; j < 4; ++j)
        accF[i][j] = __builtin_amdgcn_mfma_f32_16x16x32_bf16(av[i], bq[j], accF[i][j], 0, 0, 0);
  }

#pragma unroll
  for (int i = 0; i < 4; ++i)
#pragma unroll
    for (int r = 0; r < 4; ++r) {
      float m = fmaxf(fmaxf(accF[i][0][r], accF[i][1][r]), fmaxf(accF[i][2][r], accF[i][3][r]));
      m = fmaxf(m, __shfl_xor(m, 1, 64));
      m = fmaxf(m, __shfl_xor(m, 2, 64));
      m = fmaxf(m, __shfl_xor(m, 4, 64));
      m = fmaxf(m, __shfl_xor(m, 8, 64));
      if (ln == 0) rmaxL[w][i * 16 + hi * 4 + r] = m;
    }
  {
    int r = tid >> 2, q = tid & 3;
    int b0 = (r * 128 + q * 32) ^ ((r & 7) << 4);
    int b1 = (r * 128 + q * 32 + 16) ^ ((r & 7) << 4);
    u32x4 x0 = *(u32x4*)(Qt + b0);
    u32x4 x1 = *(u32x4*)(Qt + b1);
    float s = 0.f;
#pragma unroll
    for (int e = 0; e < 4; ++e) {
      float a0 = bf2f((unsigned short)(x0[e] & 0xffff)), a1 = bf2f((unsigned short)(x0[e] >> 16));
      float a2 = bf2f((unsigned short)(x1[e] & 0xffff)), a3 = bf2f((unsigned short)(x1[e] >> 16));
      s += a0 * a0 + a1 * a1 + a2 * a2 + a3 * a3;
    }
    s += __shfl_xor(s, 1, 64);
    s += __shfl_xor(s, 2, 64);
    if (q == 0) ssqL[r] = s;
  }
  __syncthreads();

  float ks[4];
#pragma unroll
  for (int j = 0; j < 4; ++j) ks[j] = ksum[z * 256 + w * 64 + j * 16 + ln];
#pragma unroll
  for (int i = 0; i < 4; ++i)
#pragma unroll
    for (int r = 0; r < 4; ++r) {
      int n = i * 16 + hi * 4 + r;
      float base = 0.0625f * ssqL[n] +
                   fmaxf(fmaxf(rmaxL[0][n], rmaxL[1][n]), fmaxf(rmaxL[2][n], rmaxL[3][n]));
      float dp = 0.f;
#pragma unroll
      for (int j = 0; j < 4; ++j) {
        float v = 0.0625f * (expf(accF[i][j][r] - base) + 1e-4f);
        unsigned short vb = f2b(v);
        int m = w * 64 + j * 16 + ln;
        *(unsigned short*)(Ps + n * 512 + ((m * 2) ^ ((n & 7) << 4))) = vb;
        dp += bf2f(vb) * ks[j];    // consistent with the rounded numerator
      }
      dp += __shfl_xor(dp, 1, 64);
      dp += __shfl_xor(dp, 2, 64);
      dp += __shfl_xor(dp, 4, 64);
      dp += __shfl_xor(dp, 8, 64);
      if (ln == 0) dprt[w][n] = dp;
    }
  __syncthreads();
  if (tid < 64) denomS[tid] = dprt[0][tid] + dprt[1][tid] + dprt[2][tid] + dprt[3][tid];

  // PV from pre-staged Ch (no mid-loop staging)
  f32x4 accO[4];
#pragma unroll
  for (int j = 0; j < 4; ++j) accO[j] = (f32x4){0.f, 0.f, 0.f, 0.f};
#pragma unroll
  for (int mh = 0; mh < 2; ++mh) {
#pragma unroll
    for (int ms = 0; ms < 4; ++ms) {
      const int koff = (ms * 64 + hi * 16);
      bf16x8 ap = *(bf16x8*)(Ps + (w * 16 + ln) * 512 + ((mh * 256 + koff) ^ rswz));
      bf16x8 bc[4];
#pragma unroll
      for (int j = 0; j < 4; ++j)
        bc[j] = *(bf16x8*)(Ch + mh * 16384 + (j * 16 + ln) * 256 + (koff ^ rswz));
#pragma unroll
      for (int j = 0; j < 4; ++j)
        accO[j] = __builtin_amdgcn_mfma_f32_16x16x32_bf16(ap, bc[j], accO[j], 0, 0, 0);
    }
  }
  __syncthreads();   // denomS visible; Qt safe to reuse

  float inv[4];
#pragma unroll
  for (int r = 0; r < 4; ++r) inv[r] = 1.0f / denomS[w * 16 + hi * 4 + r];
  char* Ct = Qt;
#pragma unroll
  for (int j = 0; j < 4; ++j)
#pragma unroll
    for (int r = 0; r < 4; ++r) {
      int n = w * 16 + hi * 4 + r;
      int d = j * 16 + ln;
      *(unsigned short*)(Ct + ((n * 128 + d * 2) ^ ((n & 7) << 4))) = f2b(accO[j][r] * inv[r]);
    }
  __syncthreads();
#pragma unroll
  for (int p = 0; p < 2; ++p) {
    int idx = p * 256 + tid;
    int row = idx >> 3, seg = idx & 7;
    u32x4 v = *(u32x4*)(Ct + ((row * 128 + seg * 16) ^ ((row & 7) << 4)));
    *(u32x4*)(AO + (long long)(b * 4096 + n0 + row) * 1024 + hh * 64 + seg * 8) = v;
  }
}

// weight transpose+convert: out[n*K+k] = bf16(in[k*N+n])
__launch_bounds__(256)
__global__ void wt_cvt(const float* __restrict__ in, unsigned short* __restrict__ out,
                       int K, int N) {
  __shared__ float t[32][33];
  int k0 = blockIdx.y * 32, n0 = blockIdx.x * 32;
  int tx = threadIdx.x & 31, ty = threadIdx.x >> 5;
  for (int r = ty; r < 32; r += 8) t[r][tx] = in[(long long)(k0 + r) * N + n0 + tx];
  __syncthreads();
  for (int r = ty; r < 32; r += 8) out[(long long)(n0 + r) * K + k0 + tx] = f2b(t[tx][r]);
}

// pjB[m][d] = bf16(dn * proj[m][d])
__launch_bounds__(256)
__global__ void projB_cvt(const float* __restrict__ proj, unsigned short* __restrict__ out) {
  int i = blockIdx.x * 256 + threadIdx.x;
  out[i] = f2b(0.35355339059327373f * proj[i]);
}

// bias concat
__launch_bounds__(256)
__global__ void bias_cat(const float* __restrict__ b0, const float* __restrict__ b1,
                         const float* __restrict__ b2, float* __restrict__ out) {
  int i = blockIdx.x * 256 + threadIdx.x;
  float v;
  if (i < 1024) v = b0[i];
  else if (i < 2048) v = b1[i - 1024];
  else v = b2[i - 2048];
  out[i] = v;
}

__launch_bounds__(256)
__global__ void cvt_bf16(const float* __restrict__ in, unsigned short* __restrict__ out,
                         long long n) {
  long long stride = (long long)gridDim.x * 1024;
  for (long long i = ((long long)blockIdx.x * 256 + threadIdx.x) * 4; i < n; i += stride) {
    float4 v = *(const float4*)&in[i];
    ushort4 o;
    o.x = f2b(v.x); o.y = f2b(v.y); o.z = f2b(v.z); o.w = f2b(v.w);
    *(ushort4*)&out[i] = o;
  }
}

// out = LN(res + po) * g + beta, rows of 1024.
__launch_bounds__(256)
__global__ void ln_k(const float* __restrict__ resf, const unsigned short* __restrict__ resb,
                     const unsigned short* __restrict__ po,
                     const float* __restrict__ g, const float* __restrict__ be,
                     float* __restrict__ outf, unsigned short* __restrict__ outb) {
  long long row = blockIdx.x;
  int t = threadIdx.x;
  float x0, x1, x2, x3;
  if (resf) {
    float4 va = ((const float4*)(resf + row * H_))[t];
    x0 = va.x; x1 = va.y; x2 = va.z; x3 = va.w;
  } else {
    ushort4 va = ((const ushort4*)(resb + row * H_))[t];
    x0 = bf2f(va.x); x1 = bf2f(va.y); x2 = bf2f(va.z); x3 = bf2f(va.w);
  }
  {
    ushort4 vp = ((const ushort4*)(po + row * H_))[t];
    x0 += bf2f(vp.x); x1 += bf2f(vp.y); x2 += bf2f(vp.z); x3 += bf2f(vp.w);
  }
  float s = x0 + x1 + x2 + x3;
  float q = x0 * x0 + x1 * x1 + x2 * x2 + x3 * x3;
#pragma unroll
  for (int m = 1; m < 64; m <<= 1) { s += __shfl_xor(s, m, 64); q += __shfl_xor(q, m, 64); }
  __shared__ float ssum[4], ssq[4];
  int w = t >> 6, lane = t & 63;
  if (lane == 0) { ssum[w] = s; ssq[w] = q; }
  __syncthreads();
  s = ssum[0] + ssum[1] + ssum[2] + ssum[3];
  q = ssq[0] + ssq[1] + ssq[2] + ssq[3];
  float mean = s * (1.0f / H_);
  float var = q * (1.0f / H_) - mean * mean;
  float rstd = rsqrtf(var + 1e-5f);
  float4 vg = ((const float4*)g)[t];
  float4 vbe = ((const float4*)be)[t];
  float o0 = (x0 - mean) * rstd * vg.x + vbe.x;
  float o1 = (x1 - mean) * rstd * vg.y + vbe.y;
  float o2 = (x2 - mean) * rstd * vg.z + vbe.z;
  float o3 = (x3 - mean) * rstd * vg.w + vbe.w;
  if (outf) {
    float4 o; o.x = o0; o.y = o1; o.z = o2; o.w = o3;
    ((float4*)(outf + row * H_))[t] = o;
  }
  if (outb) {
    ushort4 ob; ob.x = f2b(o0); ob.y = f2b(o1); ob.z = f2b(o2); ob.w = f2b(o3);
    ((ushort4*)(outb + row * H_))[t] = ob;
  }
}

extern "C" void kernel_launch(void* const* d_in, const int* in_sizes, int n_in,
                              void* d_out, int out_size, void* d_ws, size_t ws_size,
                              hipStream_t stream) {
  (void)in_sizes; (void)n_in; (void)out_size; (void)ws_size;
  const float* x      = (const float*)d_in[0];
  const float* enc    = (const float*)d_in[1];
  const float* sa_w[4] = {(const float*)d_in[2], (const float*)d_in[4], (const float*)d_in[6], (const float*)d_in[8]};
  const float* sa_b[4] = {(const float*)d_in[3], (const float*)d_in[5], (const float*)d_in[7], (const float*)d_in[9]};
  const float* sa_pj  = (const float*)d_in[10];
  const float* ca_w[4] = {(const float*)d_in[11], (const float*)d_in[13], (const float*)d_in[15], (const float*)d_in[17]};
  const float* ca_b[4] = {(const float*)d_in[12], (const float*)d_in[14], (const float*)d_in[16], (const float*)d_in[18]};
  const float* ca_pj  = (const float*)d_in[19];
  const float* ff_w1  = (const float*)d_in[20];
  const float* ff_b1  = (const float*)d_in[21];
  const float* ff_w2  = (const float*)d_in[22];
  const float* ff_b2  = (const float*)d_in[23];
  const float* ln1_g  = (const float*)d_in[24];
  const float* ln1_b  = (const float*)d_in[25];
  const float* ln2_g  = (const float*)d_in[26];
  const float* ln2_b  = (const float*)d_in[27];
  const float* ln3_g  = (const float*)d_in[28];
  const float* ln3_b  = (const float*)d_in[29];

  float* ws = (float*)d_ws;
  // Offsets in f32 elements. Peak ~224.6 MB (<235 proven good).
  unsigned short* XB = (unsigned short*)(ws);                 // [16384][1024] bf16
  unsigned short* EB = (unsigned short*)(ws + 8388608LL);     // enc bf16 / AO / ffT
  unsigned short* QKVb = (unsigned short*)(ws + 16777216LL);  // [16384][3072] bf16
  unsigned short* PO = (unsigned short*)(ws + 41943040LL);    // [16384][1024] bf16
  float* ctxP = ws + 41943040LL;                               // ALIAS of PO: [512][16384] f32
  unsigned short* MIDB = PO;                                   // FFN mid chunk
  unsigned short* FO = (unsigned short*)(ws + 50331648LL);
  unsigned short* WTph = (unsigned short*)(ws + 52428800LL);  // 4 x [1024][1024] bf16
  unsigned short* pjB = (unsigned short*)(ws + 54525952LL);   // 2 x [256][64] bf16
  float* ksumP = ws + 54542336LL;                              // [64][8][256] f32
  float* ksumF = ws + 54673408LL;                              // [64][256] f32
  unsigned short* ctxbf = (unsigned short*)(ws + 55607296LL); // [64][16384] bf16
  float* biasC = ws + 56131584LL;                              // [3072] f32

  unsigned short* ff1T = EB;
  unsigned short* ff2T = EB + 4194304LL;
  unsigned short* pjB_sa = pjB, *pjB_ca = pjB + 16384;

  dim3 blk(256, 1, 1);
  const int LDQ = 3072;

  projB_cvt<<<dim3(64), blk, 0, stream>>>(sa_pj, pjB_sa);
  projB_cvt<<<dim3(64), blk, 0, stream>>>(ca_pj, pjB_ca);
  cvt_bf16<<<dim3(2048), blk, 0, stream>>>(x, XB, 16777216LL);

  auto attn_core = [&](const unsigned short* pj, const float* wo_bias) {
    ctxksum_mfma<<<dim3(8, 1, 64), blk, 0, stream>>>(QKVb, pj, ksumP, ctxP);
    ctx_fin<<<dim3(64), blk, 0, stream>>>(ctxP, ksumP, ctxbf, ksumF);
    ao_fused<<<dim3(64, 1, 64), blk, 0, stream>>>(QKVb, pj, ksumF, ctxbf, EB);
    gemm_mfma<0><<<dim3(8, 128), blk, 0, stream>>>(EB, H_, WTph + 3145728, wo_bias, PO, H_, H_);
  };

  // ---- self-attention ----
  for (int i = 0; i < 4; ++i)
    wt_cvt<<<dim3(32, 32), blk, 0, stream>>>(sa_w[i], WTph + (long long)i * 1048576, H_, H_);
  bias_cat<<<dim3(12), blk, 0, stream>>>(sa_b[0], sa_b[1], sa_b[2], biasC);
  gemm_mfma<0><<<dim3(24, 128), blk, 0, stream>>>(XB, H_, WTph, biasC, QKVb, LDQ, H_);
  attn_core(pjB_sa, sa_b[3]);
  ln_k<<<dim3(16384), blk, 0, stream>>>(x, nullptr, PO, ln1_g, ln1_b, nullptr, XB);

  // ---- cross-attention ----
  cvt_bf16<<<dim3(2048), blk, 0, stream>>>(enc, EB, 16777216LL);
  for (int i = 0; i < 4; ++i)
    wt_cvt<<<dim3(32, 32), blk, 0, stream>>>(ca_w[i], WTph + (long long)i * 1048576, H_, H_);
  bias_cat<<<dim3(8), blk, 0, stream>>>(ca_b[1], ca_b[2], nullptr, biasC);
  gemm_mfma<0><<<dim3(8, 128), blk, 0, stream>>>(XB, H_, WTph, ca_b[0], QKVb, LDQ, H_);
  gemm_mfma<0><<<dim3(16, 128), blk, 0, stream>>>(EB, H_, WTph + 1048576, biasC, QKVb + 1024, LDQ, H_);
  attn_core(pjB_ca, ca_b[3]);
  ln_k<<<dim3(16384), blk, 0, stream>>>(nullptr, XB, PO, ln2_g, ln2_b, nullptr, XB);

  // ---- FFN ----
  wt_cvt<<<dim3(128, 32), blk, 0, stream>>>(ff_w1, ff1T, H_, 4096);
  wt_cvt<<<dim3(32, 128), blk, 0, stream>>>(ff_w2, ff2T, 4096, H_);
  for (int c = 0; c < 4; ++c) {
    const long long co = (long long)c * 4096 * H_;
    gemm_mfma<1><<<dim3(32, 32), blk, 0, stream>>>(XB + co, H_, ff1T, ff_b1, MIDB, 4096, H_);
    gemm_mfma<0><<<dim3(8, 32), blk, 0, stream>>>(MIDB, 4096, ff2T, ff_b2, FO, H_, 4096);
    ln_k<<<dim3(4096), blk, 0, stream>>>(nullptr, XB + co, FO, ln3_g, ln3_b,
                                         (float*)d_out + co, nullptr);
  }
}

// Round 13
// 1532.708 us; speedup vs baseline: 10.4296x; 1.0003x over previous
//
#include <hip/hip_runtime.h>
#include <hip/hip_bf16.h>

#define B_ 4
#define N_ 4096
#define H_ 1024
#define NH_ 16
#define HD_ 64
#define M_ 256

typedef __attribute__((ext_vector_type(8))) __bf16 bf16x8;
typedef __attribute__((ext_vector_type(4))) float f32x4;
typedef __attribute__((ext_vector_type(4))) unsigned int u32x4;

__device__ __forceinline__ float bf2f(unsigned short u) {
  union { unsigned int i; float f; } x; x.i = ((unsigned int)u) << 16; return x.f;
}
__device__ __forceinline__ unsigned short f2b(float f) {
  __hip_bfloat16 h = __float2bfloat16(f);
  return *(unsigned short*)&h;
}
__device__ __forceinline__ float gelu_f(float x) {
  const float c = 0.7978845608028654f;
  float t = tanhf(c * (x + 0.044715f * x * x * x));
  return 0.5f * x * (1.0f + t);
}

typedef __attribute__((address_space(3))) unsigned int as3_uint;
typedef const __attribute__((address_space(1))) unsigned int as1_uint;
__device__ __forceinline__ void gload16(const void* g, void* l) {
  __builtin_amdgcn_global_load_lds((as1_uint*)g, (as3_uint*)l, 16, 0, 0);
}

// ---------------------------------------------------------------------------
// Dense bf16 MFMA GEMM (round-10 verified: dbuf global_load_lds, XCD swizzle,
// LDS-staged nontemporal epilogue).
// ---------------------------------------------------------------------------
template<int ACT>
__launch_bounds__(256)
__global__ void gemm_mfma(const unsigned short* __restrict__ A, int lda,
                          const unsigned short* __restrict__ BT,
                          const float* __restrict__ bias,
                          unsigned short* __restrict__ C, int ldc, int K) {
  __shared__ __align__(16) char LDS[65536];

  const int tid = threadIdx.x;
  const int nwg = gridDim.x * gridDim.y;
  const int lin = blockIdx.y * gridDim.x + blockIdx.x;
  const int mm = (lin & 7) * (nwg >> 3) + (lin >> 3);
  const int bx = mm % gridDim.x, by = mm / gridDim.x;
  const int row0 = by * 128;
  const int col0 = bx * 128;

  const int w = tid >> 6, lane = tid & 63;
  const int wm = w >> 1, wn = w & 1;
  const int ln = lane & 15, hi = lane >> 4;
  const int rswz = (ln & 7) << 4;

  const int srow = w * 8 + (lane >> 3);
  const int schunk = ((lane & 7) ^ (lane >> 3)) * 8;
  const unsigned short* Ag = A + (long long)(row0 + srow) * lda + schunk;
  const unsigned short* Bg = BT + (long long)(col0 + srow) * K + schunk;
  const int ldsw = w * 1024;

  f32x4 acc[4][4];
#pragma unroll
  for (int i = 0; i < 4; ++i)
#pragma unroll
    for (int j = 0; j < 4; ++j) acc[i][j] = (f32x4){0.f, 0.f, 0.f, 0.f};

  auto STAGE = [&](int p, int k0) {
    char* dst = LDS + p * 32768 + ldsw;
#pragma unroll
    for (int i = 0; i < 4; ++i) {
      gload16(Ag + (long long)i * 32 * lda + k0, dst + i * 4096);
      gload16(Bg + (long long)i * 32 * K + k0, dst + 16384 + i * 4096);
    }
  };
  auto COMPUTE = [&](int p) {
    char* AsB = LDS + p * 32768;
    char* BsB = AsB + 16384;
#pragma unroll
    for (int kc = 0; kc < 2; ++kc) {
      const int koff = (kc * 64 + hi * 16) ^ rswz;
      bf16x8 av[4], bv[4];
#pragma unroll
      for (int i = 0; i < 4; ++i)
        av[i] = *(bf16x8*)(AsB + (wm * 64 + i * 16 + ln) * 128 + koff);
#pragma unroll
      for (int j = 0; j < 4; ++j)
        bv[j] = *(bf16x8*)(BsB + (wn * 64 + j * 16 + ln) * 128 + koff);
#pragma unroll
      for (int i = 0; i < 4; ++i)
#pragma unroll
        for (int j = 0; j < 4; ++j)
          acc[i][j] = __builtin_amdgcn_mfma_f32_16x16x32_bf16(av[i], bv[j], acc[i][j], 0, 0, 0);
    }
  };

  STAGE(0, 0);
  __syncthreads();
  int cur = 0;
  for (int k0 = 64; k0 < K; k0 += 64) {
    STAGE(cur ^ 1, k0);
    COMPUTE(cur);
    __syncthreads();
    cur ^= 1;
  }
  COMPUTE(cur);
  __syncthreads();

  char* SB = LDS;
#pragma unroll
  for (int j = 0; j < 4; ++j) {
    const int lcol = wn * 64 + j * 16 + ln;
    const float bj = bias ? bias[col0 + lcol] : 0.0f;
#pragma unroll
    for (int i = 0; i < 4; ++i) {
      const int rb_ = wm * 64 + i * 16 + hi * 4;
#pragma unroll
      for (int r = 0; r < 4; ++r) {
        float v = acc[i][j][r] + bj;
        if (ACT == 1) v = gelu_f(v);
        const int row = rb_ + r;
        *(unsigned short*)(SB + ((row * 256 + lcol * 2) ^ ((row & 7) << 4))) = f2b(v);
      }
    }
  }
  __syncthreads();
#pragma unroll
  for (int p = 0; p < 8; ++p) {
    const int idx = p * 256 + tid;
    const int row = idx >> 4, seg = idx & 15;
    u32x4 v = *(u32x4*)(SB + ((row * 256 + seg * 16) ^ ((row & 7) << 4)));
    __builtin_nontemporal_store(v, (u32x4*)(C + (long long)(row0 + row) * ldc + col0 + seg * 8));
  }
}

// ---------------------------------------------------------------------------
// Fused K-feature + ctx + ksum, NO ATOMICS, DOUBLE-BUFFERED staging:
// tile t+1's K (global_load_lds) and V (reg loads) are issued at the top of
// tile t; V's ds_write lands after the mid-barrier (write-late, T14).
// pjB hoisted to registers. 2 barriers/tile.
// grid (8 n-splits, 1, 64 z), block 256.
// ---------------------------------------------------------------------------
__launch_bounds__(256)
__global__ void ctxksum_mfma(const unsigned short* __restrict__ QKV,
                             const unsigned short* __restrict__ pjB,
                             float* __restrict__ ksumP,     // [64z][8s][256]
                             float* __restrict__ ctxP) {    // [64z*8s][16384]
  __shared__ char Kt[2][8192];
  __shared__ char Vt[2][8192];
  __shared__ char Pt[32768];     // P^T tile; reused as f32 ctx staging at end
  __shared__ float rmaxL[4][64];
  __shared__ float ssqL[64];
  const int z = blockIdx.z, b = z >> 4, hh = z & 15;
  const int sp = blockIdx.x;
  const long long n0 = sp * 512;
  const unsigned short* Kg = QKV + (long long)(b * 4096) * 3072 + 1024 + hh * 64;
  const unsigned short* Vg = QKV + (long long)(b * 4096) * 3072 + 2048 + hh * 64;
  const int tid = threadIdx.x;
  const int w = tid >> 6, lane = tid & 63;
  const int ln = lane & 15, hi = lane >> 4;
  const int rswz = (ln & 7) << 4;

  // pjB fragments hoisted once (32 VGPR; occupancy unchanged at 2 waves/SIMD)
  bf16x8 bq[2][4];
#pragma unroll
  for (int kc = 0; kc < 2; ++kc)
#pragma unroll
    for (int j = 0; j < 4; ++j)
      bq[kc][j] = *(const bf16x8*)(pjB + (w * 64 + j * 16 + ln) * 64 + kc * 32 + hi * 8);

  const int vn = tid >> 2, vd0 = (tid & 3) * 16;
  ushort4 vr[4];
  auto VLOAD = [&](long long nt) {
    const unsigned short* src = Vg + (nt + vn) * 3072 + vd0;
    vr[0] = *(const ushort4*)src;
    vr[1] = *(const ushort4*)(src + 4);
    vr[2] = *(const ushort4*)(src + 8);
    vr[3] = *(const ushort4*)(src + 12);
  };
  auto VWRITE = [&](int buf) {
    unsigned short vals[16] = {vr[0].x, vr[0].y, vr[0].z, vr[0].w,
                               vr[1].x, vr[1].y, vr[1].z, vr[1].w,
                               vr[2].x, vr[2].y, vr[2].z, vr[2].w,
                               vr[3].x, vr[3].y, vr[3].z, vr[3].w};
#pragma unroll
    for (int e = 0; e < 16; ++e) {
      int d = vd0 + e;
      *(unsigned short*)(Vt[buf] + ((d * 128 + vn * 2) ^ ((d & 7) << 4))) = vals[e];
    }
  };
  auto KSTAGE = [&](long long nt, int buf) {
#pragma unroll
    for (int p = 0; p < 2; ++p) {
      int id = p * 256 + tid;
      int r = id >> 3, c = id & 7;
      gload16(Kg + (nt + r) * 3072 + ((c ^ (r & 7)) * 8), Kt[buf] + id * 16);
    }
  };

  f32x4 accC[4][4];
#pragma unroll
  for (int i = 0; i < 4; ++i)
#pragma unroll
    for (int j = 0; j < 4; ++j) accC[i][j] = (f32x4){0.f, 0.f, 0.f, 0.f};
  float cs[4] = {0.f, 0.f, 0.f, 0.f};

  // prologue: tile 0 staged fully
  KSTAGE(n0, 0);
  VLOAD(n0);
  VWRITE(0);
  __syncthreads();

  for (int t = 0; t < 8; ++t) {
    const int cur = t & 1;
    if (t < 7) {                       // prefetch tile t+1 (hidden under compute)
      KSTAGE(n0 + (t + 1) * 64, cur ^ 1);
      VLOAD(n0 + (t + 1) * 64);
    }

    // feat MFMA: dd[64n][256m]; wave w owns m-quarter w*64
    f32x4 accF[4][4];
#pragma unroll
    for (int i = 0; i < 4; ++i)
#pragma unroll
      for (int j = 0; j < 4; ++j) accF[i][j] = (f32x4){0.f, 0.f, 0.f, 0.f};
#pragma unroll
    for (int kc = 0; kc < 2; ++kc) {
      const int koff = (kc * 64 + hi * 16) ^ rswz;
      bf16x8 av[4];
#pragma unroll
      for (int i = 0; i < 4; ++i)
        av[i] = *(bf16x8*)(Kt[cur] + (i * 16 + ln) * 128 + koff);
#pragma unroll
      for (int i = 0; i < 4; ++i)
#pragma unroll
        for (int j = 0; j < 4; ++j)
          accF[i][j] = __builtin_amdgcn_mfma_f32_16x16x32_bf16(av[i], bq[kc][j], accF[i][j], 0, 0, 0);
    }

#pragma unroll
    for (int i = 0; i < 4; ++i)
#pragma unroll
      for (int r = 0; r < 4; ++r) {
        float m = fmaxf(fmaxf(accF[i][0][r], accF[i][1][r]), fmaxf(accF[i][2][r], accF[i][3][r]));
        m = fmaxf(m, __shfl_xor(m, 1, 64));
        m = fmaxf(m, __shfl_xor(m, 2, 64));
        m = fmaxf(m, __shfl_xor(m, 4, 64));
        m = fmaxf(m, __shfl_xor(m, 8, 64));
        if (ln == 0) rmaxL[w][i * 16 + hi * 4 + r] = m;
      }
    {
      int r = tid >> 2, q = tid & 3;
      int b0 = (r * 128 + q * 32) ^ ((r & 7) << 4);
      int b1 = (r * 128 + q * 32 + 16) ^ ((r & 7) << 4);
      u32x4 x0 = *(u32x4*)(Kt[cur] + b0);
      u32x4 x1 = *(u32x4*)(Kt[cur] + b1);
      float s = 0.f;
#pragma unroll
      for (int e = 0; e < 4; ++e) {
        float a0 = bf2f((unsigned short)(x0[e] & 0xffff)), a1 = bf2f((unsigned short)(x0[e] >> 16));
        float a2 = bf2f((unsigned short)(x1[e] & 0xffff)), a3 = bf2f((unsigned short)(x1[e] >> 16));
        s += a0 * a0 + a1 * a1 + a2 * a2 + a3 * a3;
      }
      s += __shfl_xor(s, 1, 64);
      s += __shfl_xor(s, 2, 64);
      if (q == 0) ssqL[r] = s;
    }
    __syncthreads();   // rmax/ssq visible; prev ctx done reading Pt/Vt[cur^1]

    float base[4][4];
#pragma unroll
    for (int i = 0; i < 4; ++i)
#pragma unroll
      for (int r = 0; r < 4; ++r) {
        int row = i * 16 + hi * 4 + r;
        base[i][r] = 0.0625f * ssqL[row] +
                     fmaxf(fmaxf(rmaxL[0][row], rmaxL[1][row]), fmaxf(rmaxL[2][row], rmaxL[3][row]));
      }
#pragma unroll
    for (int i = 0; i < 4; ++i)
#pragma unroll
      for (int j = 0; j < 4; ++j) {
        float v0 = 0.0625f * (expf(accF[i][j][0] - base[i][0]) + 1e-4f);
        float v1 = 0.0625f * (expf(accF[i][j][1] - base[i][1]) + 1e-4f);
        float v2 = 0.0625f * (expf(accF[i][j][2] - base[i][2]) + 1e-4f);
        float v3 = 0.0625f * (expf(accF[i][j][3] - base[i][3]) + 1e-4f);
        cs[j] += v0 + v1 + v2 + v3;
        ushort4 pk;
        pk.x = f2b(v0); pk.y = f2b(v1); pk.z = f2b(v2); pk.w = f2b(v3);
        int m = w * 64 + j * 16 + ln;
        *(ushort4*)(Pt + ((m * 128 + i * 32 + hi * 8) ^ ((m & 7) << 4))) = pk;
      }
    if (t < 7) VWRITE(cur ^ 1);   // write-late: V(t+1) regs -> other buffer
    __syncthreads();   // Pt visible; drains K(t+1) gload16 before next feat

    // ctx MFMA: ctx[m][d] += P^T @ V ; wave w owns m-quarter w*64
#pragma unroll
    for (int kc = 0; kc < 2; ++kc) {
      const int koff = (kc * 64 + hi * 16) ^ rswz;
      bf16x8 am[4], bv[4];
#pragma unroll
      for (int i = 0; i < 4; ++i)
        am[i] = *(bf16x8*)(Pt + (w * 64 + i * 16 + ln) * 128 + koff);
#pragma unroll
      for (int j = 0; j < 4; ++j)
        bv[j] = *(bf16x8*)(Vt[cur] + (j * 16 + ln) * 128 + koff);
#pragma unroll
      for (int i = 0; i < 4; ++i)
#pragma unroll
        for (int j = 0; j < 4; ++j)
          accC[i][j] = __builtin_amdgcn_mfma_f32_16x16x32_bf16(am[i], bv[j], accC[i][j], 0, 0, 0);
    }
  }

  // ksum partial (plain store, deterministic)
#pragma unroll
  for (int j = 0; j < 4; ++j) {
    cs[j] += __shfl_xor(cs[j], 16, 64);
    cs[j] += __shfl_xor(cs[j], 32, 64);
  }
  if (hi == 0) {
#pragma unroll
    for (int j = 0; j < 4; ++j)
      ksumP[((long long)z * 8 + sp) * 256 + w * 64 + j * 16 + ln] = cs[j];
  }

  // ctx partial: stage f32 halves in Pt, coalesced nontemporal store
  float* ctxPs = ctxP + ((long long)z * 8 + sp) * 16384;
#pragma unroll
  for (int dh = 0; dh < 2; ++dh) {
    __syncthreads();
#pragma unroll
    for (int i = 0; i < 4; ++i)
#pragma unroll
      for (int jj = 0; jj < 2; ++jj) {
        int j = dh * 2 + jj;
#pragma unroll
        for (int r = 0; r < 4; ++r) {
          int m = w * 64 + i * 16 + hi * 4 + r;
          int dl = jj * 16 + ln;
          *(float*)(Pt + ((m * 128 + dl * 4) ^ ((m & 7) << 4))) = accC[i][j][r];
        }
      }
    __syncthreads();
#pragma unroll
    for (int p = 0; p < 8; ++p) {
      int idx = p * 256 + tid;
      int row = idx >> 3, seg = idx & 7;
      u32x4 v = *(u32x4*)(Pt + ((row * 128 + seg * 16) ^ ((row & 7) << 4)));
      __builtin_nontemporal_store(v, (u32x4*)(ctxPs + dh * 8192 + row * 32 + seg * 4));
    }
  }
}

// reduce 8 partials (fixed order, deterministic) -> swizzled bf16 ctx^T + ksum
__launch_bounds__(256)
__global__ void ctx_fin(const float* __restrict__ ctxP, const float* __restrict__ ksumP,
                        unsigned short* __restrict__ ctxbf, float* __restrict__ ksumF) {
  __shared__ float acc[16384];   // [dh][m][32]
  const int z = blockIdx.x;
  const int tid = threadIdx.x;
  const float* base = ctxP + (long long)z * 8 * 16384;
  for (int i = tid; i < 16384; i += 256) {
    float s = 0.f;
#pragma unroll
    for (int q = 0; q < 8; ++q) s += base[(long long)q * 16384 + i];
    acc[i] = s;
  }
  {
    const float* kb = ksumP + (long long)z * 8 * 256;
    float s = 0.f;
#pragma unroll
    for (int q = 0; q < 8; ++q) s += kb[q * 256 + tid];
    ksumF[z * 256 + tid] = s;
  }
  __syncthreads();
  unsigned short* dst = ctxbf + (long long)z * 16384;
  for (int cc = tid; cc < 2048; cc += 256) {
    int mh = cc >> 10, rem = cc & 1023, d = rem >> 4, cl = rem & 15;
    int m0 = mh * 128 + cl * 8;
    int dh = d >> 5, dl = d & 31;
    ushort4 o0, o1;
    o0.x = f2b(acc[dh * 8192 + (m0 + 0) * 32 + dl]);
    o0.y = f2b(acc[dh * 8192 + (m0 + 1) * 32 + dl]);
    o0.z = f2b(acc[dh * 8192 + (m0 + 2) * 32 + dl]);
    o0.w = f2b(acc[dh * 8192 + (m0 + 3) * 32 + dl]);
    o1.x = f2b(acc[dh * 8192 + (m0 + 4) * 32 + dl]);
    o1.y = f2b(acc[dh * 8192 + (m0 + 5) * 32 + dl]);
    o1.z = f2b(acc[dh * 8192 + (m0 + 6) * 32 + dl]);
    o1.w = f2b(acc[dh * 8192 + (m0 + 7) * 32 + dl]);
    unsigned short* p = dst + (long long)mh * 8192 + (d * 16 + (cl ^ (d & 7))) * 8;
    *(ushort4*)p = o0;
    *(ushort4*)(p + 4) = o1;
  }
}

// ---------------------------------------------------------------------------
// Fused Q-feature + denom + PV. ctx^T staged up-front (latency hidden under
// Q staging + feat). denom uses bf16-ROUNDED Qp (consistent with numerator).
// ---------------------------------------------------------------------------
__launch_bounds__(256)
__global__ void ao_fused(const unsigned short* __restrict__ QKV,
                         const unsigned short* __restrict__ pjB,
                         const float* __restrict__ ksum,
                         const unsigned short* __restrict__ ctxbf,
                         unsigned short* __restrict__ AO) {
  __shared__ char Qt[8192];
  __shared__ char Ps[32768];
  __shared__ char Ch[32768];     // both ctx^T halves
  __shared__ float rmaxL[4][64];
  __shared__ float ssqL[64];
  __shared__ float dprt[4][64];
  __shared__ float denomS[64];
  const int z = blockIdx.z, b = z >> 4, hh = z & 15;
  const int n0 = blockIdx.x * 64;
  const unsigned short* Qg = QKV + (long long)(b * 4096) * 3072 + hh * 64;
  const int tid = threadIdx.x;
  const int w = tid >> 6, lane = tid & 63;
  const int ln = lane & 15, hi = lane >> 4;
  const int rswz = (ln & 7) << 4;

  // stage ctx^T (32 KB) early — drains at the first barrier
#pragma unroll
  for (int p = 0; p < 8; ++p) {
    int id = p * 256 + tid;
    gload16(ctxbf + (long long)z * 16384 + id * 8, Ch + id * 16);
  }
  // stage Q tile
#pragma unroll
  for (int p = 0; p < 2; ++p) {
    int id = p * 256 + tid;
    int r = id >> 3, c = id & 7;
    gload16(Qg + (long long)(n0 + r) * 3072 + ((c ^ (r & 7)) * 8), Qt + id * 16);
  }
  __syncthreads();

  f32x4 accF[4][4];
#pragma unroll
  for (int i = 0; i < 4; ++i)
#pragma unroll
    for (int j = 0; j < 4; ++j) accF[i][j] = (f32x4){0.f, 0.f, 0.f, 0.f};
#pragma unroll
  for (int kc = 0; kc < 2; ++kc) {
    const int koff = (kc * 64 + hi * 16) ^ rswz;
    bf16x8 av[4], bq[4];
#pragma unroll
    for (int i = 0; i < 4; ++i)
      av[i] = *(bf16x8*)(Qt + (i * 16 + ln) * 128 + koff);
#pragma unroll
    for (int j = 0; j < 4; ++j)
      bq[j] = *(const bf16x8*)(pjB + (w * 64 + j * 16 + ln) * 64 + kc * 32 + hi * 8);
#pragma unroll
    for (int i = 0; i < 4; ++i)
#pragma unroll
      for (int j = 0; j < 4; ++j)
        accF[i][j] = __builtin_amdgcn_mfma_f32_16x16x32_bf16(av[i], bq[j], accF[i][j], 0, 0, 0);
  }

#pragma unroll
  for (int i = 0; i < 4; ++i)
#pragma unroll
    for (int r = 0; r < 4; ++r) {
      float m = fmaxf(fmaxf(accF[i][0][r], accF[i][1][r]), fmaxf(accF[i][2][r], accF[i][3][r]));
      m = fmaxf(m, __shfl_xor(m, 1, 64));
      m = fmaxf(m, __shfl_xor(m, 2, 64));
      m = fmaxf(m, __shfl_xor(m, 4, 64));
      m = fmaxf(m, __shfl_xor(m, 8, 64));
      if (ln == 0) rmaxL[w][i * 16 + hi * 4 + r] = m;
    }
  {
    int r = tid >> 2, q = tid & 3;
    int b0 = (r * 128 + q * 32) ^ ((r & 7) << 4);
    int b1 = (r * 128 + q * 32 + 16) ^ ((r & 7) << 4);
    u32x4 x0 = *(u32x4*)(Qt + b0);
    u32x4 x1 = *(u32x4*)(Qt + b1);
    float s = 0.f;
#pragma unroll
    for (int e = 0; e < 4; ++e) {
      float a0 = bf2f((unsigned short)(x0[e] & 0xffff)), a1 = bf2f((unsigned short)(x0[e] >> 16));
      float a2 = bf2f((unsigned short)(x1[e] & 0xffff)), a3 = bf2f((unsigned short)(x1[e] >> 16));
      s += a0 * a0 + a1 * a1 + a2 * a2 + a3 * a3;
    }
    s += __shfl_xor(s, 1, 64);
    s += __shfl_xor(s, 2, 64);
    if (q == 0) ssqL[r] = s;
  }
  __syncthreads();

  float ks[4];
#pragma unroll
  for (int j = 0; j < 4; ++j) ks[j] = ksum[z * 256 + w * 64 + j * 16 + ln];
#pragma unroll
  for (int i = 0; i < 4; ++i)
#pragma unroll
    for (int r = 0; r < 4; ++r) {
      int n = i * 16 + hi * 4 + r;
      float base = 0.0625f * ssqL[n] +
                   fmaxf(fmaxf(rmaxL[0][n], rmaxL[1][n]), fmaxf(rmaxL[2][n], rmaxL[3][n]));
      float dp = 0.f;
#pragma unroll
      for (int j = 0; j < 4; ++j) {
        float v = 0.0625f * (expf(accF[i][j][r] - base) + 1e-4f);
        unsigned short vb = f2b(v);
        int m = w * 64 + j * 16 + ln;
        *(unsigned short*)(Ps + n * 512 + ((m * 2) ^ ((n & 7) << 4))) = vb;
        dp += bf2f(vb) * ks[j];    // consistent with the rounded numerator
      }
      dp += __shfl_xor(dp, 1, 64);
      dp += __shfl_xor(dp, 2, 64);
      dp += __shfl_xor(dp, 4, 64);
      dp += __shfl_xor(dp, 8, 64);
      if (ln == 0) dprt[w][n] = dp;
    }
  __syncthreads();
  if (tid < 64) denomS[tid] = dprt[0][tid] + dprt[1][tid] + dprt[2][tid] + dprt[3][tid];

  // PV from pre-staged Ch (no mid-loop staging)
  f32x4 accO[4];
#pragma unroll
  for (int j = 0; j < 4; ++j) accO[j] = (f32x4){0.f, 0.f, 0.f, 0.f};
#pragma unroll
  for (int mh = 0; mh < 2; ++mh) {
#pragma unroll
    for (int ms = 0; ms < 4; ++ms) {
      const int koff = (ms * 64 + hi * 16);
      bf16x8 ap = *(bf16x8*)(Ps + (w * 16 + ln) * 512 + ((mh * 256 + koff) ^ rswz));
      bf16x8 bc[4];
#pragma unroll
      for (int j = 0; j < 4; ++j)
        bc[j] = *(bf16x8*)(Ch + mh * 16384 + (j * 16 + ln) * 256 + (koff ^ rswz));
#pragma unroll
      for (int j = 0; j < 4; ++j)
        accO[j] = __builtin_amdgcn_mfma_f32_16x16x32_bf16(ap, bc[j], accO[j], 0, 0, 0);
    }
  }
  __syncthreads();   // denomS visible; Qt safe to reuse

  float inv[4];
#pragma unroll
  for (int r = 0; r < 4; ++r) inv[r] = 1.0f / denomS[w * 16 + hi * 4 + r];
  char* Ct = Qt;
#pragma unroll
  for (int j = 0; j < 4; ++j)
#pragma unroll
    for (int r = 0; r < 4; ++r) {
      int n = w * 16 + hi * 4 + r;
      int d = j * 16 + ln;
      *(unsigned short*)(Ct + ((n * 128 + d * 2) ^ ((n & 7) << 4))) = f2b(accO[j][r] * inv[r]);
    }
  __syncthreads();
#pragma unroll
  for (int p = 0; p < 2; ++p) {
    int idx = p * 256 + tid;
    int row = idx >> 3, seg = idx & 7;
    u32x4 v = *(u32x4*)(Ct + ((row * 128 + seg * 16) ^ ((row & 7) << 4)));
    *(u32x4*)(AO + (long long)(b * 4096 + n0 + row) * 1024 + hh * 64 + seg * 8) = v;
  }
}

// weight transpose+convert: out[n*K+k] = bf16(in[k*N+n])
__launch_bounds__(256)
__global__ void wt_cvt(const float* __restrict__ in, unsigned short* __restrict__ out,
                       int K, int N) {
  __shared__ float t[32][33];
  int k0 = blockIdx.y * 32, n0 = blockIdx.x * 32;
  int tx = threadIdx.x & 31, ty = threadIdx.x >> 5;
  for (int r = ty; r < 32; r += 8) t[r][tx] = in[(long long)(k0 + r) * N + n0 + tx];
  __syncthreads();
  for (int r = ty; r < 32; r += 8) out[(long long)(n0 + r) * K + k0 + tx] = f2b(t[tx][r]);
}

// pjB[m][d] = bf16(dn * proj[m][d])
__launch_bounds__(256)
__global__ void projB_cvt(const float* __restrict__ proj, unsigned short* __restrict__ out) {
  int i = blockIdx.x * 256 + threadIdx.x;
  out[i] = f2b(0.35355339059327373f * proj[i]);
}

// bias concat
__launch_bounds__(256)
__global__ void bias_cat(const float* __restrict__ b0, const float* __restrict__ b1,
                         const float* __restrict__ b2, float* __restrict__ out) {
  int i = blockIdx.x * 256 + threadIdx.x;
  float v;
  if (i < 1024) v = b0[i];
  else if (i < 2048) v = b1[i - 1024];
  else v = b2[i - 2048];
  out[i] = v;
}

__launch_bounds__(256)
__global__ void cvt_bf16(const float* __restrict__ in, unsigned short* __restrict__ out,
                         long long n) {
  long long stride = (long long)gridDim.x * 1024;
  for (long long i = ((long long)blockIdx.x * 256 + threadIdx.x) * 4; i < n; i += stride) {
    float4 v = *(const float4*)&in[i];
    ushort4 o;
    o.x = f2b(v.x); o.y = f2b(v.y); o.z = f2b(v.z); o.w = f2b(v.w);
    *(ushort4*)&out[i] = o;
  }
}

// out = LN(res + po) * g + beta, rows of 1024.
__launch_bounds__(256)
__global__ void ln_k(const float* __restrict__ resf, const unsigned short* __restrict__ resb,
                     const unsigned short* __restrict__ po,
                     const float* __restrict__ g, const float* __restrict__ be,
                     float* __restrict__ outf, unsigned short* __restrict__ outb) {
  long long row = blockIdx.x;
  int t = threadIdx.x;
  float x0, x1, x2, x3;
  if (resf) {
    float4 va = ((const float4*)(resf + row * H_))[t];
    x0 = va.x; x1 = va.y; x2 = va.z; x3 = va.w;
  } else {
    ushort4 va = ((const ushort4*)(resb + row * H_))[t];
    x0 = bf2f(va.x); x1 = bf2f(va.y); x2 = bf2f(va.z); x3 = bf2f(va.w);
  }
  {
    ushort4 vp = ((const ushort4*)(po + row * H_))[t];
    x0 += bf2f(vp.x); x1 += bf2f(vp.y); x2 += bf2f(vp.z); x3 += bf2f(vp.w);
  }
  float s = x0 + x1 + x2 + x3;
  float q = x0 * x0 + x1 * x1 + x2 * x2 + x3 * x3;
#pragma unroll
  for (int m = 1; m < 64; m <<= 1) { s += __shfl_xor(s, m, 64); q += __shfl_xor(q, m, 64); }
  __shared__ float ssum[4], ssq[4];
  int w = t >> 6, lane = t & 63;
  if (lane == 0) { ssum[w] = s; ssq[w] = q; }
  __syncthreads();
  s = ssum[0] + ssum[1] + ssum[2] + ssum[3];
  q = ssq[0] + ssq[1] + ssq[2] + ssq[3];
  float mean = s * (1.0f / H_);
  float var = q * (1.0f / H_) - mean * mean;
  float rstd = rsqrtf(var + 1e-5f);
  float4 vg = ((const float4*)g)[t];
  float4 vbe = ((const float4*)be)[t];
  float o0 = (x0 - mean) * rstd * vg.x + vbe.x;
  float o1 = (x1 - mean) * rstd * vg.y + vbe.y;
  float o2 = (x2 - mean) * rstd * vg.z + vbe.z;
  float o3 = (x3 - mean) * rstd * vg.w + vbe.w;
  if (outf) {
    float4 o; o.x = o0; o.y = o1; o.z = o2; o.w = o3;
    ((float4*)(outf + row * H_))[t] = o;
  }
  if (outb) {
    ushort4 ob; ob.x = f2b(o0); ob.y = f2b(o1); ob.z = f2b(o2); ob.w = f2b(o3);
    ((ushort4*)(outb + row * H_))[t] = ob;
  }
}

extern "C" void kernel_launch(void* const* d_in, const int* in_sizes, int n_in,
                              void* d_out, int out_size, void* d_ws, size_t ws_size,
                              hipStream_t stream) {
  (void)in_sizes; (void)n_in; (void)out_size; (void)ws_size;
  const float* x      = (const float*)d_in[0];
  const float* enc    = (const float*)d_in[1];
  const float* sa_w[4] = {(const float*)d_in[2], (const float*)d_in[4], (const float*)d_in[6], (const float*)d_in[8]};
  const float* sa_b[4] = {(const float*)d_in[3], (const float*)d_in[5], (const float*)d_in[7], (const float*)d_in[9]};
  const float* sa_pj  = (const float*)d_in[10];
  const float* ca_w[4] = {(const float*)d_in[11], (const float*)d_in[13], (const float*)d_in[15], (const float*)d_in[17]};
  const float* ca_b[4] = {(const float*)d_in[12], (const float*)d_in[14], (const float*)d_in[16], (const float*)d_in[18]};
  const float* ca_pj  = (const float*)d_in[19];
  const float* ff_w1  = (const float*)d_in[20];
  const float* ff_b1  = (const float*)d_in[21];
  const float* ff_w2  = (const float*)d_in[22];
  const float* ff_b2  = (const float*)d_in[23];
  const float* ln1_g  = (const float*)d_in[24];
  const float* ln1_b  = (const float*)d_in[25];
  const float* ln2_g  = (const float*)d_in[26];
  const float* ln2_b  = (const float*)d_in[27];
  const float* ln3_g  = (const float*)d_in[28];
  const float* ln3_b  = (const float*)d_in[29];

  float* ws = (float*)d_ws;
  // Offsets in f32 elements. Peak ~224.6 MB (<235 proven good).
  unsigned short* XB = (unsigned short*)(ws);                 // [16384][1024] bf16
  unsigned short* EB = (unsigned short*)(ws + 8388608LL);     // enc bf16 / AO / ffT
  unsigned short* QKVb = (unsigned short*)(ws + 16777216LL);  // [16384][3072] bf16
  unsigned short* PO = (unsigned short*)(ws + 41943040LL);    // [16384][1024] bf16
  float* ctxP = ws + 41943040LL;                               // ALIAS of PO: [512][16384] f32
  unsigned short* MIDB = PO;                                   // FFN mid chunk
  unsigned short* FO = (unsigned short*)(ws + 50331648LL);
  unsigned short* WTph = (unsigned short*)(ws + 52428800LL);  // 4 x [1024][1024] bf16
  unsigned short* pjB = (unsigned short*)(ws + 54525952LL);   // 2 x [256][64] bf16
  float* ksumP = ws + 54542336LL;                              // [64][8][256] f32
  float* ksumF = ws + 54673408LL;                              // [64][256] f32
  unsigned short* ctxbf = (unsigned short*)(ws + 55607296LL); // [64][16384] bf16
  float* biasC = ws + 56131584LL;                              // [3072] f32

  unsigned short* ff1T = EB;
  unsigned short* ff2T = EB + 4194304LL;
  unsigned short* pjB_sa = pjB, *pjB_ca = pjB + 16384;

  dim3 blk(256, 1, 1);
  const int LDQ = 3072;

  projB_cvt<<<dim3(64), blk, 0, stream>>>(sa_pj, pjB_sa);
  projB_cvt<<<dim3(64), blk, 0, stream>>>(ca_pj, pjB_ca);
  cvt_bf16<<<dim3(2048), blk, 0, stream>>>(x, XB, 16777216LL);

  auto attn_core = [&](const unsigned short* pj, const float* wo_bias) {
    ctxksum_mfma<<<dim3(8, 1, 64), blk, 0, stream>>>(QKVb, pj, ksumP, ctxP);
    ctx_fin<<<dim3(64), blk, 0, stream>>>(ctxP, ksumP, ctxbf, ksumF);
    ao_fused<<<dim3(64, 1, 64), blk, 0, stream>>>(QKVb, pj, ksumF, ctxbf, EB);
    gemm_mfma<0><<<dim3(8, 128), blk, 0, stream>>>(EB, H_, WTph + 3145728, wo_bias, PO, H_, H_);
  };

  // ---- self-attention ----
  for (int i = 0; i < 4; ++i)
    wt_cvt<<<dim3(32, 32), blk, 0, stream>>>(sa_w[i], WTph + (long long)i * 1048576, H_, H_);
  bias_cat<<<dim3(12), blk, 0, stream>>>(sa_b[0], sa_b[1], sa_b[2], biasC);
  gemm_mfma<0><<<dim3(24, 128), blk, 0, stream>>>(XB, H_, WTph, biasC, QKVb, LDQ, H_);
  attn_core(pjB_sa, sa_b[3]);
  ln_k<<<dim3(16384), blk, 0, stream>>>(x, nullptr, PO, ln1_g, ln1_b, nullptr, XB);

  // ---- cross-attention ----
  cvt_bf16<<<dim3(2048), blk, 0, stream>>>(enc, EB, 16777216LL);
  for (int i = 0; i < 4; ++i)
    wt_cvt<<<dim3(32, 32), blk, 0, stream>>>(ca_w[i], WTph + (long long)i * 1048576, H_, H_);
  bias_cat<<<dim3(8), blk, 0, stream>>>(ca_b[1], ca_b[2], nullptr, biasC);
  gemm_mfma<0><<<dim3(8, 128), blk, 0, stream>>>(XB, H_, WTph, ca_b[0], QKVb, LDQ, H_);
  gemm_mfma<0><<<dim3(16, 128), blk, 0, stream>>>(EB, H_, WTph + 1048576, biasC, QKVb + 1024, LDQ, H_);
  attn_core(pjB_ca, ca_b[3]);
  ln_k<<<dim3(16384), blk, 0, stream>>>(nullptr, XB, PO, ln2_g, ln2_b, nullptr, XB);

  // ---- FFN ----
  wt_cvt<<<dim3(128, 32), blk, 0, stream>>>(ff_w1, ff1T, H_, 4096);
  wt_cvt<<<dim3(32, 128), blk, 0, stream>>>(ff_w2, ff2T, 4096, H_);
  for (int c = 0; c < 4; ++c) {
    const long long co = (long long)c * 4096 * H_;
    gemm_mfma<1><<<dim3(32, 32), blk, 0, stream>>>(XB + co, H_, ff1T, ff_b1, MIDB, 4096, H_);
    gemm_mfma<0><<<dim3(8, 32), blk, 0, stream>>>(MIDB, 4096, ff2T, ff_b2, FO, H_, 4096);
    ln_k<<<dim3(4096), blk, 0, stream>>>(nullptr, XB + co, FO, ln3_g, ln3_b,
                                         (float*)d_out + co, nullptr);
  }
}